// Round 2
// baseline (382.799 us; speedup 1.0000x reference)
//
#include <hip/hip_runtime.h>

typedef __attribute__((ext_vector_type(8))) short short8;
typedef __attribute__((ext_vector_type(4))) short short4v;
typedef __attribute__((ext_vector_type(4))) float float4a;
typedef __attribute__((ext_vector_type(16))) float float16a;
typedef __attribute__((ext_vector_type(4))) unsigned int uint4v;

#define MFMA16(a, b, c) __builtin_amdgcn_mfma_f32_16x16x32_bf16(a, b, c, 0, 0, 0)
#define MFMA32(a, b, c) __builtin_amdgcn_mfma_f32_32x32x16_bf16(a, b, c, 0, 0, 0)

static __device__ __forceinline__ short f2bf(float f) {
  unsigned u = __builtin_bit_cast(unsigned, f);
  u += 0x7fff + ((u >> 16) & 1);   // RNE
  return (short)(u >> 16);
}
static __device__ __forceinline__ float bf2f(short s) {
  unsigned u = ((unsigned)(unsigned short)s) << 16;
  return __builtin_bit_cast(float, u);
}

// async global->LDS, 16 B per lane. LDS dest = wave-uniform base + lane*16.
static __device__ __forceinline__ void gl2lds(const short* g, short* l) {
  __builtin_amdgcn_global_load_lds(
      (const __attribute__((address_space(1))) void*)g,
      (__attribute__((address_space(3))) void*)l,
      16, 0, 0);
}

// ---- fused f32->bf16 conversion for all 8 tensors ----
struct Cvt8 { const float* in[8]; short* out[8]; };
__global__ __launch_bounds__(256) void cvt8_k(Cvt8 a) {
  int b = blockIdx.x, seg, rb;
  if (b < 12288)      { seg = b >> 12;                 rb = b & 4095; }
  else if (b < 16384) { seg = 3 + ((b - 12288) >> 10); rb = (b - 12288) & 1023; }
  else                { seg = 7;                       rb = b - 16384; }
  int i = rb * 256 + threadIdx.x;
  float4a v = ((const float4a*)a.in[seg])[i];
  short4v o;
  o.x = f2bf(v.x); o.y = f2bf(v.y); o.z = f2bf(v.z); o.w = f2bf(v.w);
  ((short4v*)a.out[seg])[i] = o;
}

// ---- tiled GEMM, BK=64 rows (128 B = all 32 banks) + XOR swizzle ----
// Fused Q/K/V projections; 128x128 tile; 2x2 waves of 64x64.
// Q output is pre-scaled by (1/sqrt(128))*log2(e) so attention can use exp2.
__global__ __launch_bounds__(256) void gemm_qkv(
    const short* __restrict__ Qb, const short* __restrict__ Kb, const short* __restrict__ Vb,
    const short* __restrict__ Wq, const short* __restrict__ Wk, const short* __restrict__ Wv,
    short* __restrict__ Qp, short* __restrict__ Kp, short* __restrict__ Vt) {
  __shared__ short pool[16384];        // As=pool[0:8192), Bs=pool[8192:16384)
  short* As = pool;
  short* Bs = pool + 8192;
  int seg = blockIdx.x >> 8, bid = blockIdx.x & 255;
  const short* A = seg == 0 ? Qb : (seg == 1 ? Kb : Vb);
  const short* W = seg == 0 ? Wq : (seg == 1 ? Wk : Wv);
  int mt = bid >> 3, nt = bid & 7;
  int m0 = mt * 128, n0 = nt * 128;
  int tid = threadIdx.x;
  int lane = tid & 63, wid = tid >> 6;
  int l15 = lane & 15, quad = lane >> 4;
  int wm = wid & 1, wn = wid >> 1;

  int srow = lane >> 3, sunit = (lane & 7) ^ (lane >> 3);
  const short* gA = A + (m0 + wid * 32 + srow) * 1024 + sunit * 8;
  const short* gB = W + (n0 + wid * 32 + srow) * 1024 + sunit * 8;
  short* lA = As + (wid * 32) * 64;
  short* lB = Bs + (wid * 32) * 64;
  int sw = l15 & 7;

  float4a acc[4][4];
#pragma unroll
  for (int i = 0; i < 4; ++i)
#pragma unroll
    for (int j = 0; j < 4; ++j) acc[i][j] = (float4a){0, 0, 0, 0};

  for (int kc = 0; kc < 1024; kc += 64) {
    __syncthreads();
#pragma unroll
    for (int t = 0; t < 4; ++t) {
      gl2lds(gA + kc + t * 8192, lA + t * 512);
      gl2lds(gB + kc + t * 8192, lB + t * 512);
    }
    __syncthreads();
#pragma unroll
    for (int ks = 0; ks < 2; ++ks) {
      short8 af[4], bfr[4];
#pragma unroll
      for (int i = 0; i < 4; ++i)
        af[i] = *(const short8*)&As[(wm * 64 + i * 16 + l15) * 64 +
                                    (((ks * 4 + quad) ^ sw) * 8)];
#pragma unroll
      for (int j = 0; j < 4; ++j)
        bfr[j] = *(const short8*)&Bs[(wn * 64 + j * 16 + l15) * 64 +
                                     (((ks * 4 + quad) ^ sw) * 8)];
#pragma unroll
      for (int i = 0; i < 4; ++i)
#pragma unroll
        for (int j = 0; j < 4; ++j) acc[i][j] = MFMA16(af[i], bfr[j], acc[i][j]);
    }
  }

  if (seg < 2) {
    // Qp/Kp: n = h*128+d, d consecutive across lanes -> direct stores
    float scl = (seg == 0) ? 0.12752745707470575f : 1.0f;  // sc * log2(e) for Q
#pragma unroll
    for (int i = 0; i < 4; ++i)
#pragma unroll
      for (int j = 0; j < 4; ++j)
#pragma unroll
        for (int r = 0; r < 4; ++r) {
          int m = m0 + wm * 64 + i * 16 + quad * 4 + r;
          int n = n0 + wn * 64 + j * 16 + l15;
          int bb = m >> 10, s = m & 1023, hh = n >> 7, d = n & 127;
          short v = f2bf(acc[i][j][r] * scl);
          if (seg == 0) Qp[(((bb * 8 + hh) * 1024) + s) * 128 + d] = v;
          else          Kp[(((bb * 8 + hh) * 1024) + s) * 128 + d] = v;
        }
  } else {
    // Vt: transpose through LDS, then coalesced 256B-row stores.
    short* T = pool;                   // 64 x 132 shorts
    int b2 = m0 >> 10, s0 = m0 & 1023;
    long vb2 = (long)(b2 * 8 + nt) * 131072;
#pragma unroll
    for (int hd = 0; hd < 2; ++hd) {
      __syncthreads();
      if (wn == hd) {
#pragma unroll
        for (int j = 0; j < 4; ++j)
#pragma unroll
          for (int i = 0; i < 4; ++i)
#pragma unroll
            for (int r = 0; r < 4; ++r)
              T[(j * 16 + l15) * 132 + wm * 64 + i * 16 + quad * 4 + r] =
                  f2bf(acc[i][j][r]);
      }
      __syncthreads();
#pragma unroll
      for (int rr = 0; rr < 4; ++rr) {
        int d = rr * 16 + (tid >> 4);
        short8 v = *(const short8*)&T[d * 132 + (tid & 15) * 8];
        *(short8*)&Vt[vb2 + (hd * 64 + d) * 1024 + s0 + (tid & 15) * 8] = v;
      }
    }
  }
}

// ---- output projection: out(f32) = O2 @ Wo^T. 128x64 tiles, BK=64 swizzled. ----
__global__ __launch_bounds__(256) void gemm_o(const short* __restrict__ A,
                                              const short* __restrict__ W,
                                              float* __restrict__ C) {
  __shared__ short As[128 * 64];
  __shared__ short Bs[64 * 64];
  int bid = blockIdx.x;
  int mt = bid >> 4, nt = bid & 15;
  int m0 = mt * 128, n0 = nt * 64;
  int lane = threadIdx.x & 63, wid = threadIdx.x >> 6;
  int l15 = lane & 15, quad = lane >> 4;
  int wm = wid & 1, wn = wid >> 1;

  int srow = lane >> 3, sunit = (lane & 7) ^ (lane >> 3);
  const short* gA = A + (m0 + wid * 32 + srow) * 1024 + sunit * 8;
  const short* gB = W + (n0 + wid * 16 + srow) * 1024 + sunit * 8;
  short* lA = As + (wid * 32) * 64;
  short* lB = Bs + (wid * 16) * 64;
  int sw = l15 & 7;

  float4a acc[4][2];
#pragma unroll
  for (int i = 0; i < 4; ++i)
#pragma unroll
    for (int j = 0; j < 2; ++j) acc[i][j] = (float4a){0, 0, 0, 0};

  for (int kc = 0; kc < 1024; kc += 64) {
    __syncthreads();
#pragma unroll
    for (int t = 0; t < 4; ++t) gl2lds(gA + kc + t * 8192, lA + t * 512);
#pragma unroll
    for (int t = 0; t < 2; ++t) gl2lds(gB + kc + t * 8192, lB + t * 512);
    __syncthreads();
#pragma unroll
    for (int ks = 0; ks < 2; ++ks) {
      short8 af[4], bfr[2];
#pragma unroll
      for (int i = 0; i < 4; ++i)
        af[i] = *(const short8*)&As[(wm * 64 + i * 16 + l15) * 64 +
                                    (((ks * 4 + quad) ^ sw) * 8)];
#pragma unroll
      for (int j = 0; j < 2; ++j)
        bfr[j] = *(const short8*)&Bs[(wn * 32 + j * 16 + l15) * 64 +
                                     (((ks * 4 + quad) ^ sw) * 8)];
#pragma unroll
      for (int i = 0; i < 4; ++i)
#pragma unroll
        for (int j = 0; j < 2; ++j) acc[i][j] = MFMA16(af[i], bfr[j], acc[i][j]);
    }
  }

#pragma unroll
  for (int i = 0; i < 4; ++i)
#pragma unroll
    for (int j = 0; j < 2; ++j)
#pragma unroll
      for (int r = 0; r < 4; ++r) {
        int m = m0 + wm * 64 + i * 16 + quad * 4 + r;
        int n = n0 + wn * 32 + j * 16 + l15;
        C[m * 1024 + n] = acc[i][j][r];
      }
}

// Qrel[bh, q, r] = sum_d Qp[bh,q,d] * rel[h,r,d]   (bf16 out, 258-padded rows)
__global__ __launch_bounds__(256) void qrel_k(const short* __restrict__ Qp,
                                              const short* __restrict__ rel,
                                              short* __restrict__ Qrel) {
  int lane = threadIdx.x & 63, wid = threadIdx.x >> 6;
  int gw = blockIdx.x * 4 + wid;
  int bh = gw / 1088;
  int rem = gw - bh * 1088;
  int mt = rem / 17;
  int nt = rem - mt * 17;
  int l15 = lane & 15, quad = lane >> 4;
  int h = bh & 7;

  const short* arow = Qp + bh * 131072 + (mt * 16 + l15) * 128 + quad * 8;
  int col = nt * 16 + l15;
  int colc = col > 256 ? 256 : col;
  const short* brow = rel + (h * 257 + colc) * 128 + quad * 8;

  float4a acc = {0, 0, 0, 0};
#pragma unroll
  for (int kc = 0; kc < 128; kc += 32) {
    short8 a = *(const short8*)(arow + kc);
    short8 b = *(const short8*)(brow + kc);
    acc = MFMA16(a, b, acc);
  }
  if (col < 257) {
#pragma unroll
    for (int r = 0; r < 4; ++r) {
      int q = mt * 16 + quad * 4 + r;
      Qrel[bh * 264192 + q * 258 + col] = f2bf(acc[r]);
    }
  }
}

// Banded attention v5: 32-query blocks, 4 band-quarter waves, swapped QK^T
// (P lane-local per q-row), cvt_pk+permlane32_swap in-register P->A fragments,
// exp2-folded scaling. NATURAL dispatch order (bid = bh*32 + qsb): bid%8 is
// independent of h, so the 8 head-blocks writing each O2 cache line share an
// XCD and their 2B-scatter stores merge in that XCD's L2 (WRITE_SIZE ~= O2
// size). The round-1 XCD remap scattered head-writers across L2s -> 9.5x
// write amplification; reverted.
__global__ __launch_bounds__(256, 3) void attn_k(const short* __restrict__ Qp,
                                                 const short* __restrict__ Kp,
                                                 const short* __restrict__ Vt,
                                                 const short* __restrict__ Qrel,
                                                 const unsigned char* __restrict__ kpm,
                                                 short* __restrict__ O2) {
  __shared__ __align__(16) short qlds[32 * 258];   // 16512 B, 258-stride rows
  __shared__ float obuf[32][128];                  // 16384 B
  __shared__ float lbuf[32];
  int tid = threadIdx.x;
  int lane = tid & 63, wid = tid >> 6;             // wid = band quarter
  int bid = blockIdx.x;
  int bh = bid >> 5;                               // natural order
  int qsb = bid & 31;
  int q0 = qsb * 32;
  int l31 = lane & 31, hl = lane >> 5;
  int b = bh >> 3, h = bh & 7;

  {
    float* ob = &obuf[0][0];
#pragma unroll
    for (int i = 0; i < 16; ++i) ob[tid + i * 256] = 0.f;
    if (tid < 32) lbuf[tid] = 0.f;
  }
  {
    const unsigned long long* src =
        (const unsigned long long*)(Qrel + bh * 264192 + q0 * 258);
    unsigned long long* dst = (unsigned long long*)qlds;
    for (int i = tid; i < 2064; i += 256) dst[i] = src[i];
  }

  short8 aq[8];
  const short* qrow = Qp + bh * 131072 + (q0 + l31) * 128 + hl * 8;
#pragma unroll
  for (int s = 0; s < 8; ++s) aq[s] = *(const short8*)(qrow + s * 16);
  __syncthreads();

  float16a O[4];
#pragma unroll
  for (int d = 0; d < 4; ++d)
#pragma unroll
    for (int i = 0; i < 16; ++i) O[d][i] = 0.f;
  float lsum = 0.f;

  int klo = q0 - 256; if (klo < 0) klo = 0;        // 32-aligned
  int khi = q0 + 288; if (khi > 1024) khi = 1024;

  const short* kbase = Kp + bh * 131072 + hl * 8;
  const short* vbase = Vt + bh * 131072 + hl * 8;
  const unsigned char* pmrow = kpm + b * 1024;
  int qv = q0 + l31;                // this lane's q-row
  int rowb = l31 * 258;

  int k0 = klo + wid * 32;
  short8 kb[8];
  unsigned pm32 = 0;
  if (k0 < khi) {
    const short* krow = kbase + (k0 + l31) * 128;
#pragma unroll
    for (int s = 0; s < 8; ++s) kb[s] = *(const short8*)(krow + s * 16);
    pm32 = (unsigned)__ballot(pmrow[k0 + l31] != 0);
  }

  for (; k0 < khi; k0 += 128) {
    unsigned pmc = pm32;
    // S = K^T-as-A x Q-as-B : C col(lane)=q, row(reg,hl)=key offset
    float16a S;
#pragma unroll
    for (int i = 0; i < 16; ++i) S[i] = 0.f;
#pragma unroll
    for (int s = 0; s < 8; ++s) S = MFMA32(kb[s], aq[s], S);

    // V fragments (B-operand: lane = d)
    short8 vb0[4], vb1[4];
#pragma unroll
    for (int dblk = 0; dblk < 4; ++dblk) {
      const short* vrow = vbase + (dblk * 32 + l31) * 1024 + k0;
      vb0[dblk] = *(const short8*)(vrow);
      vb1[dblk] = *(const short8*)(vrow + 16);
    }

    // softmax epilogue: per-lane q-row, 16 key-offsets in regs
    int dq = k0 - qv;
    bool edge = (k0 - q0 < -224) | (k0 - q0 > 224) | (pmc != 0);
    if (!edge) {
      int rb = dq + 4 * hl + 128;
#pragma unroll
      for (int i = 0; i < 16; ++i) {
        int rr = rb + (i & 3) + 8 * (i >> 2);
        rr = rr < 0 ? 0 : (rr > 256 ? 256 : rr);
        float pe = __builtin_amdgcn_exp2f(S[i] + bf2f(qlds[rowb + rr]));
        S[i] = pe;
        lsum += pe;
      }
    } else {
#pragma unroll
      for (int i = 0; i < 16; ++i) {
        int koff = (i & 3) + 8 * (i >> 2) + 4 * hl;
        int dd = dq + koff;
        int rr = dd < -128 ? 0 : (dd > 128 ? 256 : dd + 128);
        float rel = bf2f(qlds[rowb + rr]);
        int msk = (dd < -256) | (dd > 256) | (int)((pmc >> koff) & 1u);
        float pe = msk ? 0.f : __builtin_amdgcn_exp2f(S[i] + rel);
        S[i] = pe;
        lsum += pe;
      }
    }

    // P (f32 C-layout) -> bf16 A-fragments: 8 cvt_pk + 4 permlane32_swap
    short8 ap0, ap1;
    {
      unsigned x0, y0, z0, w0;
      asm("v_cvt_pk_bf16_f32 %0, %1, %2" : "=v"(x0) : "v"(S[0]), "v"(S[1]));
      asm("v_cvt_pk_bf16_f32 %0, %1, %2" : "=v"(y0) : "v"(S[2]), "v"(S[3]));
      asm("v_cvt_pk_bf16_f32 %0, %1, %2" : "=v"(z0) : "v"(S[4]), "v"(S[5]));
      asm("v_cvt_pk_bf16_f32 %0, %1, %2" : "=v"(w0) : "v"(S[6]), "v"(S[7]));
      asm("v_permlane32_swap_b32 %0, %1" : "+v"(x0), "+v"(z0));
      asm("v_permlane32_swap_b32 %0, %1" : "+v"(y0), "+v"(w0));
      uint4v u0 = {x0, y0, z0, w0};
      ap0 = __builtin_bit_cast(short8, u0);
      unsigned x1, y1, z1, w1;
      asm("v_cvt_pk_bf16_f32 %0, %1, %2" : "=v"(x1) : "v"(S[8]), "v"(S[9]));
      asm("v_cvt_pk_bf16_f32 %0, %1, %2" : "=v"(y1) : "v"(S[10]), "v"(S[11]));
      asm("v_cvt_pk_bf16_f32 %0, %1, %2" : "=v"(z1) : "v"(S[12]), "v"(S[13]));
      asm("v_cvt_pk_bf16_f32 %0, %1, %2" : "=v"(w1) : "v"(S[14]), "v"(S[15]));
      asm("v_permlane32_swap_b32 %0, %1" : "+v"(x1), "+v"(z1));
      asm("v_permlane32_swap_b32 %0, %1" : "+v"(y1), "+v"(w1));
      uint4v u1 = {x1, y1, z1, w1};
      ap1 = __builtin_bit_cast(short8, u1);
    }

    // prefetch next K tile + padding bits (hides under PV)
    int kn = k0 + 128;
    if (kn < khi) {
      const short* krow = kbase + (kn + l31) * 128;
#pragma unroll
      for (int s = 0; s < 8; ++s) kb[s] = *(const short8*)(krow + s * 16);
      pm32 = (unsigned)__ballot(pmrow[kn + l31] != 0);
    }

#pragma unroll
    for (int dblk = 0; dblk < 4; ++dblk) {
      O[dblk] = MFMA32(ap0, vb0[dblk], O[dblk]);
      O[dblk] = MFMA32(ap1, vb1[dblk], O[dblk]);
    }
  }

  // combine the 4 band-quarters
  lsum += __shfl_xor(lsum, 32);
  if (hl == 0) atomicAdd(&lbuf[l31], lsum);
#pragma unroll
  for (int dblk = 0; dblk < 4; ++dblk)
#pragma unroll
    for (int i = 0; i < 16; ++i) {
      int qoff = (i & 3) + 8 * (i >> 2) + 4 * hl;
      atomicAdd(&obuf[qoff][dblk * 32 + l31], O[dblk][i]);
    }
  __syncthreads();

#pragma unroll
  for (int i = 0; i < 16; ++i) {
    int idx = tid + i * 256;
    int q = idx >> 7, d = idx & 127;
    float inv = __builtin_amdgcn_rcpf(lbuf[q]);
    O2[(b * 1024 + q0 + q) * 1024 + d * 8 + h] = f2bf(obuf[q][d] * inv);
  }
}

extern "C" void kernel_launch(void* const* d_in, const int* in_sizes, int n_in,
                              void* d_out, int out_size, void* d_ws, size_t ws_size,
                              hipStream_t stream) {
  const float* Q   = (const float*)d_in[0];
  const float* K   = (const float*)d_in[1];
  const float* V   = (const float*)d_in[2];
  const unsigned char* kpm = (const unsigned char*)d_in[4];
  const float* Wq  = (const float*)d_in[5];
  const float* Wk  = (const float*)d_in[6];
  const float* Wv  = (const float*)d_in[7];
  const float* Wo  = (const float*)d_in[8];
  const float* rel = (const float*)d_in[9];
  float* out = (float*)d_out;

  short* ws = (short*)d_ws;
  short* Qb   = ws;
  short* Kb   = Qb + 4194304;
  short* Vb   = Kb + 4194304;
  short* Wqb  = Vb + 4194304;
  short* Wkb  = Wqb + 1048576;
  short* Wvb  = Wkb + 1048576;
  short* Wob  = Wvb + 1048576;
  short* relb = Wob + 1048576;
  short* Qp   = relb + 263168;
  short* Kp   = Qp + 4194304;
  short* Vt   = Kp + 4194304;
  short* O2   = Vt + 4194304;
  // Qrel (32*1024*258 shorts) aliases Qb/Kb/Vb head: those are dead once
  // gemm_qkv has run, and qrel_k/attn_k are stream-ordered after it.
  short* Qrel = Qb;

  Cvt8 ca;
  ca.in[0] = Q;  ca.out[0] = Qb;
  ca.in[1] = K;  ca.out[1] = Kb;
  ca.in[2] = V;  ca.out[2] = Vb;
  ca.in[3] = Wq; ca.out[3] = Wqb;
  ca.in[4] = Wk; ca.out[4] = Wkb;
  ca.in[5] = Wv; ca.out[5] = Wvb;
  ca.in[6] = Wo; ca.out[6] = Wob;
  ca.in[7] = rel; ca.out[7] = relb;
  cvt8_k<<<dim3(16641), dim3(256), 0, stream>>>(ca);

  gemm_qkv<<<dim3(768), dim3(256), 0, stream>>>(Qb, Kb, Vb, Wqb, Wkb, Wvb, Qp, Kp, Vt);
  qrel_k<<<dim3(8704), dim3(256), 0, stream>>>(Qp, relb, Qrel);
  attn_k<<<dim3(1024), dim3(256), 0, stream>>>(Qp, Kp, Vt, Qrel, kpm, O2);
  gemm_o<<<dim3(512), dim3(256), 0, stream>>>(O2, Wob, out);
}

// Round 3
// 373.222 us; speedup vs baseline: 1.0257x; 1.0257x over previous
//
#include <hip/hip_runtime.h>

typedef __attribute__((ext_vector_type(8))) short short8;
typedef __attribute__((ext_vector_type(4))) short short4v;
typedef __attribute__((ext_vector_type(4))) float float4a;
typedef __attribute__((ext_vector_type(16))) float float16a;
typedef __attribute__((ext_vector_type(4))) unsigned int uint4v;

#define MFMA16(a, b, c) __builtin_amdgcn_mfma_f32_16x16x32_bf16(a, b, c, 0, 0, 0)
#define MFMA32(a, b, c) __builtin_amdgcn_mfma_f32_32x32x16_bf16(a, b, c, 0, 0, 0)

static __device__ __forceinline__ short f2bf(float f) {
  unsigned u = __builtin_bit_cast(unsigned, f);
  u += 0x7fff + ((u >> 16) & 1);   // RNE
  return (short)(u >> 16);
}
static __device__ __forceinline__ float bf2f(short s) {
  unsigned u = ((unsigned)(unsigned short)s) << 16;
  return __builtin_bit_cast(float, u);
}

// async global->LDS, 16 B per lane. LDS dest = wave-uniform base + lane*16.
static __device__ __forceinline__ void gl2lds(const short* g, short* l) {
  __builtin_amdgcn_global_load_lds(
      (const __attribute__((address_space(1))) void*)g,
      (__attribute__((address_space(3))) void*)l,
      16, 0, 0);
}

// ---- fused f32->bf16 conversion for all 8 tensors ----
// seg 6 (Wo) additionally permutes columns: WoP[n][h*128+d] = Wo[n][d*8+h],
// so gemm_o can consume head-major O2 with contiguous rows.
struct Cvt8 { const float* in[8]; short* out[8]; };
__global__ __launch_bounds__(256) void cvt8_k(Cvt8 a) {
  int b = blockIdx.x, seg, rb;
  if (b < 12288)      { seg = b >> 12;                 rb = b & 4095; }
  else if (b < 16384) { seg = 3 + ((b - 12288) >> 10); rb = (b - 12288) & 1023; }
  else                { seg = 7;                       rb = b - 16384; }
  int i = rb * 256 + threadIdx.x;
  if (seg == 6) {
    int o = i * 4;                       // 4 consecutive permuted outputs
    int n = o >> 10, kp = o & 1023;
    int h = kp >> 7, d0 = kp & 127;      // d0 multiple of 4, h fixed for all 4
    const float* src = a.in[6] + n * 1024 + h;
    short4v s;
    s.x = f2bf(src[d0 * 8]);
    s.y = f2bf(src[d0 * 8 + 8]);
    s.z = f2bf(src[d0 * 8 + 16]);
    s.w = f2bf(src[d0 * 8 + 24]);
    ((short4v*)a.out[6])[i] = s;
    return;
  }
  float4a v = ((const float4a*)a.in[seg])[i];
  short4v o;
  o.x = f2bf(v.x); o.y = f2bf(v.y); o.z = f2bf(v.z); o.w = f2bf(v.w);
  ((short4v*)a.out[seg])[i] = o;
}

// ---- tiled GEMM, BK=64 rows (128 B = all 32 banks) + XOR swizzle ----
// Fused Q/K/V projections; 128x128 tile; 2x2 waves of 64x64.
// Q output is pre-scaled by (1/sqrt(128))*log2(e) so attention can use exp2.
__global__ __launch_bounds__(256) void gemm_qkv(
    const short* __restrict__ Qb, const short* __restrict__ Kb, const short* __restrict__ Vb,
    const short* __restrict__ Wq, const short* __restrict__ Wk, const short* __restrict__ Wv,
    short* __restrict__ Qp, short* __restrict__ Kp, short* __restrict__ Vt) {
  __shared__ short pool[16384];        // As=pool[0:8192), Bs=pool[8192:16384)
  short* As = pool;
  short* Bs = pool + 8192;
  int seg = blockIdx.x >> 8, bid = blockIdx.x & 255;
  const short* A = seg == 0 ? Qb : (seg == 1 ? Kb : Vb);
  const short* W = seg == 0 ? Wq : (seg == 1 ? Wk : Wv);
  int mt = bid >> 3, nt = bid & 7;
  int m0 = mt * 128, n0 = nt * 128;
  int tid = threadIdx.x;
  int lane = tid & 63, wid = tid >> 6;
  int l15 = lane & 15, quad = lane >> 4;
  int wm = wid & 1, wn = wid >> 1;

  int srow = lane >> 3, sunit = (lane & 7) ^ (lane >> 3);
  const short* gA = A + (m0 + wid * 32 + srow) * 1024 + sunit * 8;
  const short* gB = W + (n0 + wid * 32 + srow) * 1024 + sunit * 8;
  short* lA = As + (wid * 32) * 64;
  short* lB = Bs + (wid * 32) * 64;
  int sw = l15 & 7;

  float4a acc[4][4];
#pragma unroll
  for (int i = 0; i < 4; ++i)
#pragma unroll
    for (int j = 0; j < 4; ++j) acc[i][j] = (float4a){0, 0, 0, 0};

  for (int kc = 0; kc < 1024; kc += 64) {
    __syncthreads();
#pragma unroll
    for (int t = 0; t < 4; ++t) {
      gl2lds(gA + kc + t * 8192, lA + t * 512);
      gl2lds(gB + kc + t * 8192, lB + t * 512);
    }
    __syncthreads();
#pragma unroll
    for (int ks = 0; ks < 2; ++ks) {
      short8 af[4], bfr[4];
#pragma unroll
      for (int i = 0; i < 4; ++i)
        af[i] = *(const short8*)&As[(wm * 64 + i * 16 + l15) * 64 +
                                    (((ks * 4 + quad) ^ sw) * 8)];
#pragma unroll
      for (int j = 0; j < 4; ++j)
        bfr[j] = *(const short8*)&Bs[(wn * 64 + j * 16 + l15) * 64 +
                                     (((ks * 4 + quad) ^ sw) * 8)];
#pragma unroll
      for (int i = 0; i < 4; ++i)
#pragma unroll
        for (int j = 0; j < 4; ++j) acc[i][j] = MFMA16(af[i], bfr[j], acc[i][j]);
    }
  }

  if (seg < 2) {
    // Qp/Kp: n = h*128+d, d consecutive across lanes -> direct stores
    float scl = (seg == 0) ? 0.12752745707470575f : 1.0f;  // sc * log2(e) for Q
#pragma unroll
    for (int i = 0; i < 4; ++i)
#pragma unroll
      for (int j = 0; j < 4; ++j)
#pragma unroll
        for (int r = 0; r < 4; ++r) {
          int m = m0 + wm * 64 + i * 16 + quad * 4 + r;
          int n = n0 + wn * 64 + j * 16 + l15;
          int bb = m >> 10, s = m & 1023, hh = n >> 7, d = n & 127;
          short v = f2bf(acc[i][j][r] * scl);
          if (seg == 0) Qp[(((bb * 8 + hh) * 1024) + s) * 128 + d] = v;
          else          Kp[(((bb * 8 + hh) * 1024) + s) * 128 + d] = v;
        }
  } else {
    // Vt: transpose through LDS, then coalesced 256B-row stores.
    short* T = pool;                   // 64 x 132 shorts
    int b2 = m0 >> 10, s0 = m0 & 1023;
    long vb2 = (long)(b2 * 8 + nt) * 131072;
#pragma unroll
    for (int hd = 0; hd < 2; ++hd) {
      __syncthreads();
      if (wn == hd) {
#pragma unroll
        for (int j = 0; j < 4; ++j)
#pragma unroll
          for (int i = 0; i < 4; ++i)
#pragma unroll
            for (int r = 0; r < 4; ++r)
              T[(j * 16 + l15) * 132 + wm * 64 + i * 16 + quad * 4 + r] =
                  f2bf(acc[i][j][r]);
      }
      __syncthreads();
#pragma unroll
      for (int rr = 0; rr < 4; ++rr) {
        int d = rr * 16 + (tid >> 4);
        short8 v = *(const short8*)&T[d * 132 + (tid & 15) * 8];
        *(short8*)&Vt[vb2 + (hd * 64 + d) * 1024 + s0 + (tid & 15) * 8] = v;
      }
    }
  }
}

// ---- output projection: out(f32) = O2h @ WoP^T. A is head-major:
// A[m=(b,q)][k'=h*128+d] = O2h[(b*8+h)*131072 + q*128 + d]. ----
__global__ __launch_bounds__(256) void gemm_o(const short* __restrict__ A,
                                              const short* __restrict__ W,
                                              float* __restrict__ C) {
  __shared__ short As[128 * 64];
  __shared__ short Bs[64 * 64];
  int bid = blockIdx.x;
  int mt = bid >> 4, nt = bid & 15;
  int m0 = mt * 128, n0 = nt * 64;
  int lane = threadIdx.x & 63, wid = threadIdx.x >> 6;
  int l15 = lane & 15, quad = lane >> 4;
  int wm = wid & 1, wn = wid >> 1;

  int srow = lane >> 3, sunit = (lane & 7) ^ (lane >> 3);
  int bb = m0 >> 10, q0t = m0 & 1023;
  const short* gA = A + bb * 1048576 + (q0t + wid * 32 + srow) * 128 + sunit * 8;
  const short* gB = W + (n0 + wid * 16 + srow) * 1024 + sunit * 8;
  short* lA = As + (wid * 32) * 64;
  short* lB = Bs + (wid * 16) * 64;
  int sw = l15 & 7;

  float4a acc[4][2];
#pragma unroll
  for (int i = 0; i < 4; ++i)
#pragma unroll
    for (int j = 0; j < 2; ++j) acc[i][j] = (float4a){0, 0, 0, 0};

  for (int kc = 0; kc < 1024; kc += 64) {
    int koff = (kc >> 7) * 131072 + (kc & 64);   // head block + half-row
    __syncthreads();
#pragma unroll
    for (int t = 0; t < 4; ++t) gl2lds(gA + koff + t * 1024, lA + t * 512);
#pragma unroll
    for (int t = 0; t < 2; ++t) gl2lds(gB + kc + t * 8192, lB + t * 512);
    __syncthreads();
#pragma unroll
    for (int ks = 0; ks < 2; ++ks) {
      short8 af[4], bfr[2];
#pragma unroll
      for (int i = 0; i < 4; ++i)
        af[i] = *(const short8*)&As[(wm * 64 + i * 16 + l15) * 64 +
                                    (((ks * 4 + quad) ^ sw) * 8)];
#pragma unroll
      for (int j = 0; j < 2; ++j)
        bfr[j] = *(const short8*)&Bs[(wn * 32 + j * 16 + l15) * 64 +
                                     (((ks * 4 + quad) ^ sw) * 8)];
#pragma unroll
      for (int i = 0; i < 4; ++i)
#pragma unroll
        for (int j = 0; j < 2; ++j) acc[i][j] = MFMA16(af[i], bfr[j], acc[i][j]);
    }
  }

#pragma unroll
  for (int i = 0; i < 4; ++i)
#pragma unroll
    for (int j = 0; j < 2; ++j)
#pragma unroll
      for (int r = 0; r < 4; ++r) {
        int m = m0 + wm * 64 + i * 16 + quad * 4 + r;
        int n = n0 + wn * 32 + j * 16 + l15;
        C[m * 1024 + n] = acc[i][j][r];
      }
}

// Qrel[bh, q, r] = sum_d Qp[bh,q,d] * rel[h,r,d]   (bf16 out, 258-padded rows)
__global__ __launch_bounds__(256) void qrel_k(const short* __restrict__ Qp,
                                              const short* __restrict__ rel,
                                              short* __restrict__ Qrel) {
  int lane = threadIdx.x & 63, wid = threadIdx.x >> 6;
  int gw = blockIdx.x * 4 + wid;
  int bh = gw / 1088;
  int rem = gw - bh * 1088;
  int mt = rem / 17;
  int nt = rem - mt * 17;
  int l15 = lane & 15, quad = lane >> 4;
  int h = bh & 7;

  const short* arow = Qp + bh * 131072 + (mt * 16 + l15) * 128 + quad * 8;
  int col = nt * 16 + l15;
  int colc = col > 256 ? 256 : col;
  const short* brow = rel + (h * 257 + colc) * 128 + quad * 8;

  float4a acc = {0, 0, 0, 0};
#pragma unroll
  for (int kc = 0; kc < 128; kc += 32) {
    short8 a = *(const short8*)(arow + kc);
    short8 b = *(const short8*)(brow + kc);
    acc = MFMA16(a, b, acc);
  }
  if (col < 257) {
#pragma unroll
    for (int r = 0; r < 4; ++r) {
      int q = mt * 16 + quad * 4 + r;
      Qrel[bh * 264192 + q * 258 + col] = f2bf(acc[r]);
    }
  }
}

// Banded attention v6: 32-query blocks, 4 band-quarter waves, swapped QK^T,
// in-register softmax, exp2 folding. O2 is HEAD-MAJOR [bh][q][d]: each block
// writes one contiguous line-aligned 8 KB run -> WRITE == |O2|, no L2
// write-merge dependency, no RMW fetches. With writes decoupled, the XCD
// remap (bh grouped per XCD: bid%8 -> bh[4:2]) keeps K/V (2 MB/XCD)
// L2-resident for the read side.
__global__ __launch_bounds__(256, 3) void attn_k(const short* __restrict__ Qp,
                                                 const short* __restrict__ Kp,
                                                 const short* __restrict__ Vt,
                                                 const short* __restrict__ Qrel,
                                                 const unsigned char* __restrict__ kpm,
                                                 short* __restrict__ O2) {
  __shared__ __align__(16) short qlds[32 * 258];   // 16512 B, 258-stride rows
  __shared__ float obuf[32][128];                  // 16384 B
  __shared__ float lbuf[32];
  int tid = threadIdx.x;
  int lane = tid & 63, wid = tid >> 6;             // wid = band quarter
  int bid = blockIdx.x;
  // XCD-grouping: bid%8 selects a group of 4 bh; all 32 q-blocks of those
  // bh run on one XCD -> K+V working set 2 MB, L2-resident.
  int bh = ((bid & 7) << 2) | ((bid >> 3) & 3);
  int qsb = bid >> 5;
  int q0 = qsb * 32;
  int l31 = lane & 31, hl = lane >> 5;
  int b = bh >> 3;

  {
    float* ob = &obuf[0][0];
#pragma unroll
    for (int i = 0; i < 16; ++i) ob[tid + i * 256] = 0.f;
    if (tid < 32) lbuf[tid] = 0.f;
  }
  {
    const unsigned long long* src =
        (const unsigned long long*)(Qrel + bh * 264192 + q0 * 258);
    unsigned long long* dst = (unsigned long long*)qlds;
    for (int i = tid; i < 2064; i += 256) dst[i] = src[i];
  }

  short8 aq[8];
  const short* qrow = Qp + bh * 131072 + (q0 + l31) * 128 + hl * 8;
#pragma unroll
  for (int s = 0; s < 8; ++s) aq[s] = *(const short8*)(qrow + s * 16);
  __syncthreads();

  float16a O[4];
#pragma unroll
  for (int d = 0; d < 4; ++d)
#pragma unroll
    for (int i = 0; i < 16; ++i) O[d][i] = 0.f;
  float lsum = 0.f;

  int klo = q0 - 256; if (klo < 0) klo = 0;        // 32-aligned
  int khi = q0 + 288; if (khi > 1024) khi = 1024;

  const short* kbase = Kp + bh * 131072 + hl * 8;
  const short* vbase = Vt + bh * 131072 + hl * 8;
  const unsigned char* pmrow = kpm + b * 1024;
  int qv = q0 + l31;                // this lane's q-row
  int rowb = l31 * 258;

  int k0 = klo + wid * 32;
  short8 kb[8];
  unsigned pm32 = 0;
  if (k0 < khi) {
    const short* krow = kbase + (k0 + l31) * 128;
#pragma unroll
    for (int s = 0; s < 8; ++s) kb[s] = *(const short8*)(krow + s * 16);
    pm32 = (unsigned)__ballot(pmrow[k0 + l31] != 0);
  }

  for (; k0 < khi; k0 += 128) {
    unsigned pmc = pm32;
    // S = K^T-as-A x Q-as-B : C col(lane)=q, row(reg,hl)=key offset
    float16a S;
#pragma unroll
    for (int i = 0; i < 16; ++i) S[i] = 0.f;
#pragma unroll
    for (int s = 0; s < 8; ++s) S = MFMA32(kb[s], aq[s], S);

    // V fragments (B-operand: lane = d)
    short8 vb0[4], vb1[4];
#pragma unroll
    for (int dblk = 0; dblk < 4; ++dblk) {
      const short* vrow = vbase + (dblk * 32 + l31) * 1024 + k0;
      vb0[dblk] = *(const short8*)(vrow);
      vb1[dblk] = *(const short8*)(vrow + 16);
    }

    // softmax epilogue: per-lane q-row, 16 key-offsets in regs
    int dq = k0 - qv;
    bool edge = (k0 - q0 < -224) | (k0 - q0 > 224) | (pmc != 0);
    if (!edge) {
      int rb = dq + 4 * hl + 128;
#pragma unroll
      for (int i = 0; i < 16; ++i) {
        int rr = rb + (i & 3) + 8 * (i >> 2);
        rr = rr < 0 ? 0 : (rr > 256 ? 256 : rr);
        float pe = __builtin_amdgcn_exp2f(S[i] + bf2f(qlds[rowb + rr]));
        S[i] = pe;
        lsum += pe;
      }
    } else {
#pragma unroll
      for (int i = 0; i < 16; ++i) {
        int koff = (i & 3) + 8 * (i >> 2) + 4 * hl;
        int dd = dq + koff;
        int rr = dd < -128 ? 0 : (dd > 128 ? 256 : dd + 128);
        float rel = bf2f(qlds[rowb + rr]);
        int msk = (dd < -256) | (dd > 256) | (int)((pmc >> koff) & 1u);
        float pe = msk ? 0.f : __builtin_amdgcn_exp2f(S[i] + rel);
        S[i] = pe;
        lsum += pe;
      }
    }

    // P (f32 C-layout) -> bf16 A-fragments: 8 cvt_pk + 4 permlane32_swap
    short8 ap0, ap1;
    {
      unsigned x0, y0, z0, w0;
      asm("v_cvt_pk_bf16_f32 %0, %1, %2" : "=v"(x0) : "v"(S[0]), "v"(S[1]));
      asm("v_cvt_pk_bf16_f32 %0, %1, %2" : "=v"(y0) : "v"(S[2]), "v"(S[3]));
      asm("v_cvt_pk_bf16_f32 %0, %1, %2" : "=v"(z0) : "v"(S[4]), "v"(S[5]));
      asm("v_cvt_pk_bf16_f32 %0, %1, %2" : "=v"(w0) : "v"(S[6]), "v"(S[7]));
      asm("v_permlane32_swap_b32 %0, %1" : "+v"(x0), "+v"(z0));
      asm("v_permlane32_swap_b32 %0, %1" : "+v"(y0), "+v"(w0));
      uint4v u0 = {x0, y0, z0, w0};
      ap0 = __builtin_bit_cast(short8, u0);
      unsigned x1, y1, z1, w1;
      asm("v_cvt_pk_bf16_f32 %0, %1, %2" : "=v"(x1) : "v"(S[8]), "v"(S[9]));
      asm("v_cvt_pk_bf16_f32 %0, %1, %2" : "=v"(y1) : "v"(S[10]), "v"(S[11]));
      asm("v_cvt_pk_bf16_f32 %0, %1, %2" : "=v"(z1) : "v"(S[12]), "v"(S[13]));
      asm("v_cvt_pk_bf16_f32 %0, %1, %2" : "=v"(w1) : "v"(S[14]), "v"(S[15]));
      asm("v_permlane32_swap_b32 %0, %1" : "+v"(x1), "+v"(z1));
      asm("v_permlane32_swap_b32 %0, %1" : "+v"(y1), "+v"(w1));
      uint4v u1 = {x1, y1, z1, w1};
      ap1 = __builtin_bit_cast(short8, u1);
    }

    // prefetch next K tile + padding bits (hides under PV)
    int kn = k0 + 128;
    if (kn < khi) {
      const short* krow = kbase + (kn + l31) * 128;
#pragma unroll
      for (int s = 0; s < 8; ++s) kb[s] = *(const short8*)(krow + s * 16);
      pm32 = (unsigned)__ballot(pmrow[kn + l31] != 0);
    }

#pragma unroll
    for (int dblk = 0; dblk < 4; ++dblk) {
      O[dblk] = MFMA32(ap0, vb0[dblk], O[dblk]);
      O[dblk] = MFMA32(ap1, vb1[dblk], O[dblk]);
    }
  }

  // combine the 4 band-quarters
  lsum += __shfl_xor(lsum, 32);
  if (hl == 0) atomicAdd(&lbuf[l31], lsum);
#pragma unroll
  for (int dblk = 0; dblk < 4; ++dblk)
#pragma unroll
    for (int i = 0; i < 16; ++i) {
      int qoff = (i & 3) + 8 * (i >> 2) + 4 * hl;
      atomicAdd(&obuf[qoff][dblk * 32 + l31], O[dblk][i]);
    }
  __syncthreads();

  // head-major contiguous epilogue: 8 KB line-aligned run per block
#pragma unroll
  for (int it = 0; it < 2; ++it) {
    int idx = (tid + it * 256) * 8;
    int q = idx >> 7, d = idx & 127;
    float inv = __builtin_amdgcn_rcpf(lbuf[q]);
    const float* ob = &obuf[q][d];
    short8 v;
#pragma unroll
    for (int j = 0; j < 8; ++j) v[j] = f2bf(ob[j] * inv);
    *(short8*)&O2[(long)bh * 131072 + (long)(q0 + q) * 128 + d] = v;
  }
}

extern "C" void kernel_launch(void* const* d_in, const int* in_sizes, int n_in,
                              void* d_out, int out_size, void* d_ws, size_t ws_size,
                              hipStream_t stream) {
  const float* Q   = (const float*)d_in[0];
  const float* K   = (const float*)d_in[1];
  const float* V   = (const float*)d_in[2];
  const unsigned char* kpm = (const unsigned char*)d_in[4];
  const float* Wq  = (const float*)d_in[5];
  const float* Wk  = (const float*)d_in[6];
  const float* Wv  = (const float*)d_in[7];
  const float* Wo  = (const float*)d_in[8];
  const float* rel = (const float*)d_in[9];
  float* out = (float*)d_out;

  short* ws = (short*)d_ws;
  short* Qb   = ws;
  short* Kb   = Qb + 4194304;
  short* Vb   = Kb + 4194304;
  short* Wqb  = Vb + 4194304;
  short* Wkb  = Wqb + 1048576;
  short* Wvb  = Wkb + 1048576;
  short* Wob  = Wvb + 1048576;
  short* relb = Wob + 1048576;
  short* Qp   = relb + 263168;
  short* Kp   = Qp + 4194304;
  short* Vt   = Kp + 4194304;
  short* O2   = Vt + 4194304;
  // Qrel (32*1024*258 shorts) aliases Qb/Kb/Vb head: those are dead once
  // gemm_qkv has run, and qrel_k/attn_k are stream-ordered after it.
  short* Qrel = Qb;

  Cvt8 ca;
  ca.in[0] = Q;  ca.out[0] = Qb;
  ca.in[1] = K;  ca.out[1] = Kb;
  ca.in[2] = V;  ca.out[2] = Vb;
  ca.in[3] = Wq; ca.out[3] = Wqb;
  ca.in[4] = Wk; ca.out[4] = Wkb;
  ca.in[5] = Wv; ca.out[5] = Wvb;
  ca.in[6] = Wo; ca.out[6] = Wob;
  ca.in[7] = rel; ca.out[7] = relb;
  cvt8_k<<<dim3(16641), dim3(256), 0, stream>>>(ca);

  gemm_qkv<<<dim3(768), dim3(256), 0, stream>>>(Qb, Kb, Vb, Wqb, Wkb, Wvb, Qp, Kp, Vt);
  qrel_k<<<dim3(8704), dim3(256), 0, stream>>>(Qp, relb, Qrel);
  attn_k<<<dim3(1024), dim3(256), 0, stream>>>(Qp, Kp, Vt, Qrel, kpm, O2);
  gemm_o<<<dim3(512), dim3(256), 0, stream>>>(O2, Wob, out);
}

// Round 4
// 337.488 us; speedup vs baseline: 1.1343x; 1.1059x over previous
//
#include <hip/hip_runtime.h>

typedef __attribute__((ext_vector_type(8))) short short8;
typedef __attribute__((ext_vector_type(4))) short short4v;
typedef __attribute__((ext_vector_type(4))) float float4a;
typedef __attribute__((ext_vector_type(16))) float float16a;
typedef __attribute__((ext_vector_type(4))) unsigned int uint4v;

#define MFMA16(a, b, c) __builtin_amdgcn_mfma_f32_16x16x32_bf16(a, b, c, 0, 0, 0)
#define MFMA32(a, b, c) __builtin_amdgcn_mfma_f32_32x32x16_bf16(a, b, c, 0, 0, 0)

static __device__ __forceinline__ short f2bf(float f) {
  unsigned u = __builtin_bit_cast(unsigned, f);
  u += 0x7fff + ((u >> 16) & 1);   // RNE
  return (short)(u >> 16);
}
static __device__ __forceinline__ float bf2f(short s) {
  unsigned u = ((unsigned)(unsigned short)s) << 16;
  return __builtin_bit_cast(float, u);
}

// async global->LDS, 16 B per lane. LDS dest = wave-uniform base + lane*16.
static __device__ __forceinline__ void gl2lds(const short* g, short* l) {
  __builtin_amdgcn_global_load_lds(
      (const __attribute__((address_space(1))) void*)g,
      (__attribute__((address_space(3))) void*)l,
      16, 0, 0);
}

// ---- fused f32->bf16 conversion for all 8 tensors ----
// seg 6 (Wo) additionally permutes columns: WoP[n][h*128+d] = Wo[n][d*8+h],
// so gemm_o can consume head-major O2 with contiguous rows.
struct Cvt8 { const float* in[8]; short* out[8]; };
__global__ __launch_bounds__(256) void cvt8_k(Cvt8 a) {
  int b = blockIdx.x, seg, rb;
  if (b < 12288)      { seg = b >> 12;                 rb = b & 4095; }
  else if (b < 16384) { seg = 3 + ((b - 12288) >> 10); rb = (b - 12288) & 1023; }
  else                { seg = 7;                       rb = b - 16384; }
  int i = rb * 256 + threadIdx.x;
  if (seg == 6) {
    int o = i * 4;                       // 4 consecutive permuted outputs
    int n = o >> 10, kp = o & 1023;
    int h = kp >> 7, d0 = kp & 127;      // d0 multiple of 4, h fixed for all 4
    const float* src = a.in[6] + n * 1024 + h;
    short4v s;
    s.x = f2bf(src[d0 * 8]);
    s.y = f2bf(src[d0 * 8 + 8]);
    s.z = f2bf(src[d0 * 8 + 16]);
    s.w = f2bf(src[d0 * 8 + 24]);
    ((short4v*)a.out[6])[i] = s;
    return;
  }
  float4a v = ((const float4a*)a.in[seg])[i];
  short4v o;
  o.x = f2bf(v.x); o.y = f2bf(v.y); o.z = f2bf(v.z); o.w = f2bf(v.w);
  ((short4v*)a.out[seg])[i] = o;
}

// ---- tiled GEMM, BK=64 rows (128 B = all 32 banks) + XOR swizzle ----
// Fused Q/K/V projections; 128x128 tile; 2x2 waves of 64x64.
// Q output is pre-scaled by (1/sqrt(128))*log2(e) so attention can use exp2.
__global__ __launch_bounds__(256) void gemm_qkv(
    const short* __restrict__ Qb, const short* __restrict__ Kb, const short* __restrict__ Vb,
    const short* __restrict__ Wq, const short* __restrict__ Wk, const short* __restrict__ Wv,
    short* __restrict__ Qp, short* __restrict__ Kp, short* __restrict__ Vt) {
  __shared__ short pool[16384];        // As=pool[0:8192), Bs=pool[8192:16384)
  short* As = pool;
  short* Bs = pool + 8192;
  int seg = blockIdx.x >> 8, bid = blockIdx.x & 255;
  const short* A = seg == 0 ? Qb : (seg == 1 ? Kb : Vb);
  const short* W = seg == 0 ? Wq : (seg == 1 ? Wk : Wv);
  int mt = bid >> 3, nt = bid & 7;
  int m0 = mt * 128, n0 = nt * 128;
  int tid = threadIdx.x;
  int lane = tid & 63, wid = tid >> 6;
  int l15 = lane & 15, quad = lane >> 4;
  int wm = wid & 1, wn = wid >> 1;

  int srow = lane >> 3, sunit = (lane & 7) ^ (lane >> 3);
  const short* gA = A + (m0 + wid * 32 + srow) * 1024 + sunit * 8;
  const short* gB = W + (n0 + wid * 32 + srow) * 1024 + sunit * 8;
  short* lA = As + (wid * 32) * 64;
  short* lB = Bs + (wid * 32) * 64;
  int sw = l15 & 7;

  float4a acc[4][4];
#pragma unroll
  for (int i = 0; i < 4; ++i)
#pragma unroll
    for (int j = 0; j < 4; ++j) acc[i][j] = (float4a){0, 0, 0, 0};

  for (int kc = 0; kc < 1024; kc += 64) {
    __syncthreads();
#pragma unroll
    for (int t = 0; t < 4; ++t) {
      gl2lds(gA + kc + t * 8192, lA + t * 512);
      gl2lds(gB + kc + t * 8192, lB + t * 512);
    }
    __syncthreads();
#pragma unroll
    for (int ks = 0; ks < 2; ++ks) {
      short8 af[4], bfr[4];
#pragma unroll
      for (int i = 0; i < 4; ++i)
        af[i] = *(const short8*)&As[(wm * 64 + i * 16 + l15) * 64 +
                                    (((ks * 4 + quad) ^ sw) * 8)];
#pragma unroll
      for (int j = 0; j < 4; ++j)
        bfr[j] = *(const short8*)&Bs[(wn * 64 + j * 16 + l15) * 64 +
                                     (((ks * 4 + quad) ^ sw) * 8)];
#pragma unroll
      for (int i = 0; i < 4; ++i)
#pragma unroll
        for (int j = 0; j < 4; ++j) acc[i][j] = MFMA16(af[i], bfr[j], acc[i][j]);
    }
  }

  if (seg < 2) {
    // Qp/Kp: n = h*128+d, d consecutive across lanes -> direct stores
    float scl = (seg == 0) ? 0.12752745707470575f : 1.0f;  // sc * log2(e) for Q
#pragma unroll
    for (int i = 0; i < 4; ++i)
#pragma unroll
      for (int j = 0; j < 4; ++j)
#pragma unroll
        for (int r = 0; r < 4; ++r) {
          int m = m0 + wm * 64 + i * 16 + quad * 4 + r;
          int n = n0 + wn * 64 + j * 16 + l15;
          int bb = m >> 10, s = m & 1023, hh = n >> 7, d = n & 127;
          short v = f2bf(acc[i][j][r] * scl);
          if (seg == 0) Qp[(((bb * 8 + hh) * 1024) + s) * 128 + d] = v;
          else          Kp[(((bb * 8 + hh) * 1024) + s) * 128 + d] = v;
        }
  } else {
    // Vt: transpose through LDS, then coalesced 256B-row stores.
    short* T = pool;                   // 64 x 132 shorts
    int b2 = m0 >> 10, s0 = m0 & 1023;
    long vb2 = (long)(b2 * 8 + nt) * 131072;
#pragma unroll
    for (int hd = 0; hd < 2; ++hd) {
      __syncthreads();
      if (wn == hd) {
#pragma unroll
        for (int j = 0; j < 4; ++j)
#pragma unroll
          for (int i = 0; i < 4; ++i)
#pragma unroll
            for (int r = 0; r < 4; ++r)
              T[(j * 16 + l15) * 132 + wm * 64 + i * 16 + quad * 4 + r] =
                  f2bf(acc[i][j][r]);
      }
      __syncthreads();
#pragma unroll
      for (int rr = 0; rr < 4; ++rr) {
        int d = rr * 16 + (tid >> 4);
        short8 v = *(const short8*)&T[d * 132 + (tid & 15) * 8];
        *(short8*)&Vt[vb2 + (hd * 64 + d) * 1024 + s0 + (tid & 15) * 8] = v;
      }
    }
  }
}

// ---- output projection: out(f32) = O2h @ WoP^T. A is head-major:
// A[m=(b,q)][k'=h*128+d] = O2h[(b*8+h)*131072 + q*128 + d]. ----
__global__ __launch_bounds__(256) void gemm_o(const short* __restrict__ A,
                                              const short* __restrict__ W,
                                              float* __restrict__ C) {
  __shared__ short As[128 * 64];
  __shared__ short Bs[64 * 64];
  int bid = blockIdx.x;
  int mt = bid >> 4, nt = bid & 15;
  int m0 = mt * 128, n0 = nt * 64;
  int lane = threadIdx.x & 63, wid = threadIdx.x >> 6;
  int l15 = lane & 15, quad = lane >> 4;
  int wm = wid & 1, wn = wid >> 1;

  int srow = lane >> 3, sunit = (lane & 7) ^ (lane >> 3);
  int bb = m0 >> 10, q0t = m0 & 1023;
  const short* gA = A + bb * 1048576 + (q0t + wid * 32 + srow) * 128 + sunit * 8;
  const short* gB = W + (n0 + wid * 16 + srow) * 1024 + sunit * 8;
  short* lA = As + (wid * 32) * 64;
  short* lB = Bs + (wid * 16) * 64;
  int sw = l15 & 7;

  float4a acc[4][2];
#pragma unroll
  for (int i = 0; i < 4; ++i)
#pragma unroll
    for (int j = 0; j < 2; ++j) acc[i][j] = (float4a){0, 0, 0, 0};

  for (int kc = 0; kc < 1024; kc += 64) {
    int koff = (kc >> 7) * 131072 + (kc & 64);   // head block + half-row
    __syncthreads();
#pragma unroll
    for (int t = 0; t < 4; ++t) gl2lds(gA + koff + t * 1024, lA + t * 512);
#pragma unroll
    for (int t = 0; t < 2; ++t) gl2lds(gB + kc + t * 8192, lB + t * 512);
    __syncthreads();
#pragma unroll
    for (int ks = 0; ks < 2; ++ks) {
      short8 af[4], bfr[2];
#pragma unroll
      for (int i = 0; i < 4; ++i)
        af[i] = *(const short8*)&As[(wm * 64 + i * 16 + l15) * 64 +
                                    (((ks * 4 + quad) ^ sw) * 8)];
#pragma unroll
      for (int j = 0; j < 2; ++j)
        bfr[j] = *(const short8*)&Bs[(wn * 32 + j * 16 + l15) * 64 +
                                     (((ks * 4 + quad) ^ sw) * 8)];
#pragma unroll
      for (int i = 0; i < 4; ++i)
#pragma unroll
        for (int j = 0; j < 2; ++j) acc[i][j] = MFMA16(af[i], bfr[j], acc[i][j]);
    }
  }

#pragma unroll
  for (int i = 0; i < 4; ++i)
#pragma unroll
    for (int j = 0; j < 2; ++j)
#pragma unroll
      for (int r = 0; r < 4; ++r) {
        int m = m0 + wm * 64 + i * 16 + quad * 4 + r;
        int n = n0 + wn * 32 + j * 16 + l15;
        C[m * 1024 + n] = acc[i][j][r];
      }
}

// Qrel[bh, q, r] = sum_d Qp[bh,q,d] * rel[h,r,d]   (bf16 out, 258-padded rows)
__global__ __launch_bounds__(256) void qrel_k(const short* __restrict__ Qp,
                                              const short* __restrict__ rel,
                                              short* __restrict__ Qrel) {
  int lane = threadIdx.x & 63, wid = threadIdx.x >> 6;
  int gw = blockIdx.x * 4 + wid;
  int bh = gw / 1088;
  int rem = gw - bh * 1088;
  int mt = rem / 17;
  int nt = rem - mt * 17;
  int l15 = lane & 15, quad = lane >> 4;
  int h = bh & 7;

  const short* arow = Qp + bh * 131072 + (mt * 16 + l15) * 128 + quad * 8;
  int col = nt * 16 + l15;
  int colc = col > 256 ? 256 : col;
  const short* brow = rel + (h * 257 + colc) * 128 + quad * 8;

  float4a acc = {0, 0, 0, 0};
#pragma unroll
  for (int kc = 0; kc < 128; kc += 32) {
    short8 a = *(const short8*)(arow + kc);
    short8 b = *(const short8*)(brow + kc);
    acc = MFMA16(a, b, acc);
  }
  if (col < 257) {
#pragma unroll
    for (int r = 0; r < 4; ++r) {
      int q = mt * 16 + quad * 4 + r;
      Qrel[bh * 264192 + q * 258 + col] = f2bf(acc[r]);
    }
  }
}

// Banded attention v7: v6 structure with __launch_bounds__(256, 2).
// The (256,3) bound capped the unified reg file at ~170/wave against a
// ~200-reg demand -> spill-to-scratch inside the k-loop, ~63 MB of scratch
// writes + ~64 MB scratch reads per dispatch (the constant WRITE_SIZE excess
// across v4-v6). (256,2) gives 256 regs/wave headroom (v3 proved ~224 used,
// zero spill). Occupancy is unchanged (~8 waves/CU measured either way).
__global__ __launch_bounds__(256, 2) void attn_k(const short* __restrict__ Qp,
                                                 const short* __restrict__ Kp,
                                                 const short* __restrict__ Vt,
                                                 const short* __restrict__ Qrel,
                                                 const unsigned char* __restrict__ kpm,
                                                 short* __restrict__ O2) {
  __shared__ __align__(16) short qlds[32 * 258];   // 16512 B, 258-stride rows
  __shared__ float obuf[32][128];                  // 16384 B
  __shared__ float lbuf[32];
  int tid = threadIdx.x;
  int lane = tid & 63, wid = tid >> 6;             // wid = band quarter
  int bid = blockIdx.x;
  // XCD-grouping: bid%8 selects a group of 4 bh; all 32 q-blocks of those
  // bh run on one XCD -> K+V working set 2 MB, L2-resident.
  int bh = ((bid & 7) << 2) | ((bid >> 3) & 3);
  int qsb = bid >> 5;
  int q0 = qsb * 32;
  int l31 = lane & 31, hl = lane >> 5;
  int b = bh >> 3;

  {
    float* ob = &obuf[0][0];
#pragma unroll
    for (int i = 0; i < 16; ++i) ob[tid + i * 256] = 0.f;
    if (tid < 32) lbuf[tid] = 0.f;
  }
  {
    const unsigned long long* src =
        (const unsigned long long*)(Qrel + bh * 264192 + q0 * 258);
    unsigned long long* dst = (unsigned long long*)qlds;
    for (int i = tid; i < 2064; i += 256) dst[i] = src[i];
  }

  short8 aq[8];
  const short* qrow = Qp + bh * 131072 + (q0 + l31) * 128 + hl * 8;
#pragma unroll
  for (int s = 0; s < 8; ++s) aq[s] = *(const short8*)(qrow + s * 16);
  __syncthreads();

  float16a O[4];
#pragma unroll
  for (int d = 0; d < 4; ++d)
#pragma unroll
    for (int i = 0; i < 16; ++i) O[d][i] = 0.f;
  float lsum = 0.f;

  int klo = q0 - 256; if (klo < 0) klo = 0;        // 32-aligned
  int khi = q0 + 288; if (khi > 1024) khi = 1024;

  const short* kbase = Kp + bh * 131072 + hl * 8;
  const short* vbase = Vt + bh * 131072 + hl * 8;
  const unsigned char* pmrow = kpm + b * 1024;
  int qv = q0 + l31;                // this lane's q-row
  int rowb = l31 * 258;

  int k0 = klo + wid * 32;
  short8 kb[8];
  unsigned pm32 = 0;
  if (k0 < khi) {
    const short* krow = kbase + (k0 + l31) * 128;
#pragma unroll
    for (int s = 0; s < 8; ++s) kb[s] = *(const short8*)(krow + s * 16);
    pm32 = (unsigned)__ballot(pmrow[k0 + l31] != 0);
  }

  for (; k0 < khi; k0 += 128) {
    unsigned pmc = pm32;
    // S = K^T-as-A x Q-as-B : C col(lane)=q, row(reg,hl)=key offset
    float16a S;
#pragma unroll
    for (int i = 0; i < 16; ++i) S[i] = 0.f;
#pragma unroll
    for (int s = 0; s < 8; ++s) S = MFMA32(kb[s], aq[s], S);

    // V fragments (B-operand: lane = d)
    short8 vb0[4], vb1[4];
#pragma unroll
    for (int dblk = 0; dblk < 4; ++dblk) {
      const short* vrow = vbase + (dblk * 32 + l31) * 1024 + k0;
      vb0[dblk] = *(const short8*)(vrow);
      vb1[dblk] = *(const short8*)(vrow + 16);
    }

    // softmax epilogue: per-lane q-row, 16 key-offsets in regs
    int dq = k0 - qv;
    bool edge = (k0 - q0 < -224) | (k0 - q0 > 224) | (pmc != 0);
    if (!edge) {
      int rb = dq + 4 * hl + 128;
#pragma unroll
      for (int i = 0; i < 16; ++i) {
        int rr = rb + (i & 3) + 8 * (i >> 2);
        rr = rr < 0 ? 0 : (rr > 256 ? 256 : rr);
        float pe = __builtin_amdgcn_exp2f(S[i] + bf2f(qlds[rowb + rr]));
        S[i] = pe;
        lsum += pe;
      }
    } else {
#pragma unroll
      for (int i = 0; i < 16; ++i) {
        int koff = (i & 3) + 8 * (i >> 2) + 4 * hl;
        int dd = dq + koff;
        int rr = dd < -128 ? 0 : (dd > 128 ? 256 : dd + 128);
        float rel = bf2f(qlds[rowb + rr]);
        int msk = (dd < -256) | (dd > 256) | (int)((pmc >> koff) & 1u);
        float pe = msk ? 0.f : __builtin_amdgcn_exp2f(S[i] + rel);
        S[i] = pe;
        lsum += pe;
      }
    }

    // P (f32 C-layout) -> bf16 A-fragments: 8 cvt_pk + 4 permlane32_swap
    short8 ap0, ap1;
    {
      unsigned x0, y0, z0, w0;
      asm("v_cvt_pk_bf16_f32 %0, %1, %2" : "=v"(x0) : "v"(S[0]), "v"(S[1]));
      asm("v_cvt_pk_bf16_f32 %0, %1, %2" : "=v"(y0) : "v"(S[2]), "v"(S[3]));
      asm("v_cvt_pk_bf16_f32 %0, %1, %2" : "=v"(z0) : "v"(S[4]), "v"(S[5]));
      asm("v_cvt_pk_bf16_f32 %0, %1, %2" : "=v"(w0) : "v"(S[6]), "v"(S[7]));
      asm("v_permlane32_swap_b32 %0, %1" : "+v"(x0), "+v"(z0));
      asm("v_permlane32_swap_b32 %0, %1" : "+v"(y0), "+v"(w0));
      uint4v u0 = {x0, y0, z0, w0};
      ap0 = __builtin_bit_cast(short8, u0);
      unsigned x1, y1, z1, w1;
      asm("v_cvt_pk_bf16_f32 %0, %1, %2" : "=v"(x1) : "v"(S[8]), "v"(S[9]));
      asm("v_cvt_pk_bf16_f32 %0, %1, %2" : "=v"(y1) : "v"(S[10]), "v"(S[11]));
      asm("v_cvt_pk_bf16_f32 %0, %1, %2" : "=v"(z1) : "v"(S[12]), "v"(S[13]));
      asm("v_cvt_pk_bf16_f32 %0, %1, %2" : "=v"(w1) : "v"(S[14]), "v"(S[15]));
      asm("v_permlane32_swap_b32 %0, %1" : "+v"(x1), "+v"(z1));
      asm("v_permlane32_swap_b32 %0, %1" : "+v"(y1), "+v"(w1));
      uint4v u1 = {x1, y1, z1, w1};
      ap1 = __builtin_bit_cast(short8, u1);
    }

    // prefetch next K tile + padding bits (hides under PV)
    int kn = k0 + 128;
    if (kn < khi) {
      const short* krow = kbase + (kn + l31) * 128;
#pragma unroll
      for (int s = 0; s < 8; ++s) kb[s] = *(const short8*)(krow + s * 16);
      pm32 = (unsigned)__ballot(pmrow[kn + l31] != 0);
    }

#pragma unroll
    for (int dblk = 0; dblk < 4; ++dblk) {
      O[dblk] = MFMA32(ap0, vb0[dblk], O[dblk]);
      O[dblk] = MFMA32(ap1, vb1[dblk], O[dblk]);
    }
  }

  // combine the 4 band-quarters
  lsum += __shfl_xor(lsum, 32);
  if (hl == 0) atomicAdd(&lbuf[l31], lsum);
#pragma unroll
  for (int dblk = 0; dblk < 4; ++dblk)
#pragma unroll
    for (int i = 0; i < 16; ++i) {
      int qoff = (i & 3) + 8 * (i >> 2) + 4 * hl;
      atomicAdd(&obuf[qoff][dblk * 32 + l31], O[dblk][i]);
    }
  __syncthreads();

  // head-major contiguous epilogue: 8 KB line-aligned run per block
#pragma unroll
  for (int it = 0; it < 2; ++it) {
    int idx = (tid + it * 256) * 8;
    int q = idx >> 7, d = idx & 127;
    float inv = __builtin_amdgcn_rcpf(lbuf[q]);
    const float* ob = &obuf[q][d];
    short8 v;
#pragma unroll
    for (int j = 0; j < 8; ++j) v[j] = f2bf(ob[j] * inv);
    *(short8*)&O2[(long)bh * 131072 + (long)(q0 + q) * 128 + d] = v;
  }
}

extern "C" void kernel_launch(void* const* d_in, const int* in_sizes, int n_in,
                              void* d_out, int out_size, void* d_ws, size_t ws_size,
                              hipStream_t stream) {
  const float* Q   = (const float*)d_in[0];
  const float* K   = (const float*)d_in[1];
  const float* V   = (const float*)d_in[2];
  const unsigned char* kpm = (const unsigned char*)d_in[4];
  const float* Wq  = (const float*)d_in[5];
  const float* Wk  = (const float*)d_in[6];
  const float* Wv  = (const float*)d_in[7];
  const float* Wo  = (const float*)d_in[8];
  const float* rel = (const float*)d_in[9];
  float* out = (float*)d_out;

  short* ws = (short*)d_ws;
  short* Qb   = ws;
  short* Kb   = Qb + 4194304;
  short* Vb   = Kb + 4194304;
  short* Wqb  = Vb + 4194304;
  short* Wkb  = Wqb + 1048576;
  short* Wvb  = Wkb + 1048576;
  short* Wob  = Wvb + 1048576;
  short* relb = Wob + 1048576;
  short* Qp   = relb + 263168;
  short* Kp   = Qp + 4194304;
  short* Vt   = Kp + 4194304;
  short* O2   = Vt + 4194304;
  // Qrel (32*1024*258 shorts) aliases Qb/Kb/Vb head: those are dead once
  // gemm_qkv has run, and qrel_k/attn_k are stream-ordered after it.
  short* Qrel = Qb;

  Cvt8 ca;
  ca.in[0] = Q;  ca.out[0] = Qb;
  ca.in[1] = K;  ca.out[1] = Kb;
  ca.in[2] = V;  ca.out[2] = Vb;
  ca.in[3] = Wq; ca.out[3] = Wqb;
  ca.in[4] = Wk; ca.out[4] = Wkb;
  ca.in[5] = Wv; ca.out[5] = Wvb;
  ca.in[6] = Wo; ca.out[6] = Wob;
  ca.in[7] = rel; ca.out[7] = relb;
  cvt8_k<<<dim3(16641), dim3(256), 0, stream>>>(ca);

  gemm_qkv<<<dim3(768), dim3(256), 0, stream>>>(Qb, Kb, Vb, Wqb, Wkb, Wvb, Qp, Kp, Vt);
  qrel_k<<<dim3(8704), dim3(256), 0, stream>>>(Qp, relb, Qrel);
  attn_k<<<dim3(1024), dim3(256), 0, stream>>>(Qp, Kp, Vt, Qrel, kpm, O2);
  gemm_o<<<dim3(512), dim3(256), 0, stream>>>(O2, Wob, out);
}

// Round 5
// 263.730 us; speedup vs baseline: 1.4515x; 1.2797x over previous
//
#include <hip/hip_runtime.h>

typedef __attribute__((ext_vector_type(8))) short short8;
typedef __attribute__((ext_vector_type(4))) short short4v;
typedef __attribute__((ext_vector_type(4))) float float4a;
typedef __attribute__((ext_vector_type(16))) float float16a;
typedef __attribute__((ext_vector_type(4))) unsigned int uint4v;

#define MFMA16(a, b, c) __builtin_amdgcn_mfma_f32_16x16x32_bf16(a, b, c, 0, 0, 0)
#define MFMA32(a, b, c) __builtin_amdgcn_mfma_f32_32x32x16_bf16(a, b, c, 0, 0, 0)

static __device__ __forceinline__ short f2bf(float f) {
  unsigned u = __builtin_bit_cast(unsigned, f);
  u += 0x7fff + ((u >> 16) & 1);   // RNE
  return (short)(u >> 16);
}
static __device__ __forceinline__ float bf2f(short s) {
  unsigned u = ((unsigned)(unsigned short)s) << 16;
  return __builtin_bit_cast(float, u);
}

// async global->LDS, 16 B per lane. LDS dest = wave-uniform base + lane*16.
static __device__ __forceinline__ void gl2lds(const short* g, short* l) {
  __builtin_amdgcn_global_load_lds(
      (const __attribute__((address_space(1))) void*)g,
      (__attribute__((address_space(3))) void*)l,
      16, 0, 0);
}

// ---- fused f32->bf16 conversion for all 8 tensors ----
// seg 6 (Wo) additionally permutes columns: WoP[n][h*128+d] = Wo[n][d*8+h],
// so gemm_o can consume head-major O2 with contiguous rows.
struct Cvt8 { const float* in[8]; short* out[8]; };
__global__ __launch_bounds__(256) void cvt8_k(Cvt8 a) {
  int b = blockIdx.x, seg, rb;
  if (b < 12288)      { seg = b >> 12;                 rb = b & 4095; }
  else if (b < 16384) { seg = 3 + ((b - 12288) >> 10); rb = (b - 12288) & 1023; }
  else                { seg = 7;                       rb = b - 16384; }
  int i = rb * 256 + threadIdx.x;
  if (seg == 6) {
    int o = i * 4;                       // 4 consecutive permuted outputs
    int n = o >> 10, kp = o & 1023;
    int h = kp >> 7, d0 = kp & 127;      // d0 multiple of 4, h fixed for all 4
    const float* src = a.in[6] + n * 1024 + h;
    short4v s;
    s.x = f2bf(src[d0 * 8]);
    s.y = f2bf(src[d0 * 8 + 8]);
    s.z = f2bf(src[d0 * 8 + 16]);
    s.w = f2bf(src[d0 * 8 + 24]);
    ((short4v*)a.out[6])[i] = s;
    return;
  }
  float4a v = ((const float4a*)a.in[seg])[i];
  short4v o;
  o.x = f2bf(v.x); o.y = f2bf(v.y); o.z = f2bf(v.z); o.w = f2bf(v.w);
  ((short4v*)a.out[seg])[i] = o;
}

// ---- tiled GEMM, BK=64 rows (128 B = all 32 banks) + XOR swizzle ----
// Fused Q/K/V projections; 128x128 tile; 2x2 waves of 64x64.
// Q output is pre-scaled by (1/sqrt(128))*log2(e) so attention can use exp2.
__global__ __launch_bounds__(256) void gemm_qkv(
    const short* __restrict__ Qb, const short* __restrict__ Kb, const short* __restrict__ Vb,
    const short* __restrict__ Wq, const short* __restrict__ Wk, const short* __restrict__ Wv,
    short* __restrict__ Qp, short* __restrict__ Kp, short* __restrict__ Vt) {
  __shared__ short pool[16384];        // As=pool[0:8192), Bs=pool[8192:16384)
  short* As = pool;
  short* Bs = pool + 8192;
  int seg = blockIdx.x >> 8, bid = blockIdx.x & 255;
  const short* A = seg == 0 ? Qb : (seg == 1 ? Kb : Vb);
  const short* W = seg == 0 ? Wq : (seg == 1 ? Wk : Wv);
  int mt = bid >> 3, nt = bid & 7;
  int m0 = mt * 128, n0 = nt * 128;
  int tid = threadIdx.x;
  int lane = tid & 63, wid = tid >> 6;
  int l15 = lane & 15, quad = lane >> 4;
  int wm = wid & 1, wn = wid >> 1;

  int srow = lane >> 3, sunit = (lane & 7) ^ (lane >> 3);
  const short* gA = A + (m0 + wid * 32 + srow) * 1024 + sunit * 8;
  const short* gB = W + (n0 + wid * 32 + srow) * 1024 + sunit * 8;
  short* lA = As + (wid * 32) * 64;
  short* lB = Bs + (wid * 32) * 64;
  int sw = l15 & 7;

  float4a acc[4][4];
#pragma unroll
  for (int i = 0; i < 4; ++i)
#pragma unroll
    for (int j = 0; j < 4; ++j) acc[i][j] = (float4a){0, 0, 0, 0};

  for (int kc = 0; kc < 1024; kc += 64) {
    __syncthreads();
#pragma unroll
    for (int t = 0; t < 4; ++t) {
      gl2lds(gA + kc + t * 8192, lA + t * 512);
      gl2lds(gB + kc + t * 8192, lB + t * 512);
    }
    __syncthreads();
#pragma unroll
    for (int ks = 0; ks < 2; ++ks) {
      short8 af[4], bfr[4];
#pragma unroll
      for (int i = 0; i < 4; ++i)
        af[i] = *(const short8*)&As[(wm * 64 + i * 16 + l15) * 64 +
                                    (((ks * 4 + quad) ^ sw) * 8)];
#pragma unroll
      for (int j = 0; j < 4; ++j)
        bfr[j] = *(const short8*)&Bs[(wn * 64 + j * 16 + l15) * 64 +
                                     (((ks * 4 + quad) ^ sw) * 8)];
#pragma unroll
      for (int i = 0; i < 4; ++i)
#pragma unroll
        for (int j = 0; j < 4; ++j) acc[i][j] = MFMA16(af[i], bfr[j], acc[i][j]);
    }
  }

  if (seg < 2) {
    // Qp/Kp: n = h*128+d, d consecutive across lanes -> direct stores
    float scl = (seg == 0) ? 0.12752745707470575f : 1.0f;  // sc * log2(e) for Q
#pragma unroll
    for (int i = 0; i < 4; ++i)
#pragma unroll
      for (int j = 0; j < 4; ++j)
#pragma unroll
        for (int r = 0; r < 4; ++r) {
          int m = m0 + wm * 64 + i * 16 + quad * 4 + r;
          int n = n0 + wn * 64 + j * 16 + l15;
          int bb = m >> 10, s = m & 1023, hh = n >> 7, d = n & 127;
          short v = f2bf(acc[i][j][r] * scl);
          if (seg == 0) Qp[(((bb * 8 + hh) * 1024) + s) * 128 + d] = v;
          else          Kp[(((bb * 8 + hh) * 1024) + s) * 128 + d] = v;
        }
  } else {
    // Vt: transpose through LDS, then coalesced 256B-row stores.
    short* T = pool;                   // 64 x 132 shorts
    int b2 = m0 >> 10, s0 = m0 & 1023;
    long vb2 = (long)(b2 * 8 + nt) * 131072;
#pragma unroll
    for (int hd = 0; hd < 2; ++hd) {
      __syncthreads();
      if (wn == hd) {
#pragma unroll
        for (int j = 0; j < 4; ++j)
#pragma unroll
          for (int i = 0; i < 4; ++i)
#pragma unroll
            for (int r = 0; r < 4; ++r)
              T[(j * 16 + l15) * 132 + wm * 64 + i * 16 + quad * 4 + r] =
                  f2bf(acc[i][j][r]);
      }
      __syncthreads();
#pragma unroll
      for (int rr = 0; rr < 4; ++rr) {
        int d = rr * 16 + (tid >> 4);
        short8 v = *(const short8*)&T[d * 132 + (tid & 15) * 8];
        *(short8*)&Vt[vb2 + (hd * 64 + d) * 1024 + s0 + (tid & 15) * 8] = v;
      }
    }
  }
}

// ---- output projection: out(f32) = O2h @ WoP^T. A is head-major:
// A[m=(b,q)][k'=h*128+d] = O2h[(b*8+h)*131072 + q*128 + d]. ----
__global__ __launch_bounds__(256) void gemm_o(const short* __restrict__ A,
                                              const short* __restrict__ W,
                                              float* __restrict__ C) {
  __shared__ short As[128 * 64];
  __shared__ short Bs[64 * 64];
  int bid = blockIdx.x;
  int mt = bid >> 4, nt = bid & 15;
  int m0 = mt * 128, n0 = nt * 64;
  int lane = threadIdx.x & 63, wid = threadIdx.x >> 6;
  int l15 = lane & 15, quad = lane >> 4;
  int wm = wid & 1, wn = wid >> 1;

  int srow = lane >> 3, sunit = (lane & 7) ^ (lane >> 3);
  int bb = m0 >> 10, q0t = m0 & 1023;
  const short* gA = A + bb * 1048576 + (q0t + wid * 32 + srow) * 128 + sunit * 8;
  const short* gB = W + (n0 + wid * 16 + srow) * 1024 + sunit * 8;
  short* lA = As + (wid * 32) * 64;
  short* lB = Bs + (wid * 16) * 64;
  int sw = l15 & 7;

  float4a acc[4][2];
#pragma unroll
  for (int i = 0; i < 4; ++i)
#pragma unroll
    for (int j = 0; j < 2; ++j) acc[i][j] = (float4a){0, 0, 0, 0};

  for (int kc = 0; kc < 1024; kc += 64) {
    int koff = (kc >> 7) * 131072 + (kc & 64);   // head block + half-row
    __syncthreads();
#pragma unroll
    for (int t = 0; t < 4; ++t) gl2lds(gA + koff + t * 1024, lA + t * 512);
#pragma unroll
    for (int t = 0; t < 2; ++t) gl2lds(gB + kc + t * 8192, lB + t * 512);
    __syncthreads();
#pragma unroll
    for (int ks = 0; ks < 2; ++ks) {
      short8 af[4], bfr[2];
#pragma unroll
      for (int i = 0; i < 4; ++i)
        af[i] = *(const short8*)&As[(wm * 64 + i * 16 + l15) * 64 +
                                    (((ks * 4 + quad) ^ sw) * 8)];
#pragma unroll
      for (int j = 0; j < 2; ++j)
        bfr[j] = *(const short8*)&Bs[(wn * 32 + j * 16 + l15) * 64 +
                                     (((ks * 4 + quad) ^ sw) * 8)];
#pragma unroll
      for (int i = 0; i < 4; ++i)
#pragma unroll
        for (int j = 0; j < 2; ++j) acc[i][j] = MFMA16(af[i], bfr[j], acc[i][j]);
    }
  }

#pragma unroll
  for (int i = 0; i < 4; ++i)
#pragma unroll
    for (int j = 0; j < 2; ++j)
#pragma unroll
      for (int r = 0; r < 4; ++r) {
        int m = m0 + wm * 64 + i * 16 + quad * 4 + r;
        int n = n0 + wn * 32 + j * 16 + l15;
        C[m * 1024 + n] = acc[i][j][r];
      }
}

// Qrel[bh, q, r] = sum_d Qp[bh,q,d] * rel[h,r,d]   (bf16 out, 258-padded rows)
__global__ __launch_bounds__(256) void qrel_k(const short* __restrict__ Qp,
                                              const short* __restrict__ rel,
                                              short* __restrict__ Qrel) {
  int lane = threadIdx.x & 63, wid = threadIdx.x >> 6;
  int gw = blockIdx.x * 4 + wid;
  int bh = gw / 1088;
  int rem = gw - bh * 1088;
  int mt = rem / 17;
  int nt = rem - mt * 17;
  int l15 = lane & 15, quad = lane >> 4;
  int h = bh & 7;

  const short* arow = Qp + bh * 131072 + (mt * 16 + l15) * 128 + quad * 8;
  int col = nt * 16 + l15;
  int colc = col > 256 ? 256 : col;
  const short* brow = rel + (h * 257 + colc) * 128 + quad * 8;

  float4a acc = {0, 0, 0, 0};
#pragma unroll
  for (int kc = 0; kc < 128; kc += 32) {
    short8 a = *(const short8*)(arow + kc);
    short8 b = *(const short8*)(brow + kc);
    acc = MFMA16(a, b, acc);
  }
  if (col < 257) {
#pragma unroll
    for (int r = 0; r < 4; ++r) {
      int q = mt * 16 + quad * 4 + r;
      Qrel[bh * 264192 + q * 258 + col] = f2bf(acc[r]);
    }
  }
}

// Banded attention v8: 64-query blocks, grid 512 (= 2 blocks/CU assigned ==
// 2 resident at ~200 unified regs/wave: no sequential rounds). 4 waves =
// 2 q-tiles x 2 band-halves, 32-key tiles step 64 per wave. In-register
// softmax (swapped QK^T), exp2 folding, head-major O2, XCD-grouped bh.
// Latency fixes vs v7: K prefetch issued right after S-MFMA (full-iter
// cover), V issued before softmax (~450cyc cover), pad-mask byte loaded at
// issue-time and __ballot'ed only at loop bottom (the v7 ballot stalled a
// full load-to-use latency mid-loop). Atomic-free two-phase epilogue;
// qlds/obuf share one 33 KB LDS pool (obuf only live after the k-loop).
__global__ __launch_bounds__(256, 2) void attn_k(const short* __restrict__ Qp,
                                                 const short* __restrict__ Kp,
                                                 const short* __restrict__ Vt,
                                                 const short* __restrict__ Qrel,
                                                 const unsigned char* __restrict__ kpm,
                                                 short* __restrict__ O2) {
  __shared__ __align__(16) short pool[16512];      // 33024 B union
  short* qlds = pool;                              // 64 x 258 shorts (k-loop)
  float* obuf = (float*)pool;                      // 64 x 128 f32 (epilogue)
  float* lbuf = (float*)pool + 8192;               // 64 f32     (epilogue)
  int tid = threadIdx.x;
  int lane = tid & 63, wid = tid >> 6;
  int qt = wid & 1, half = wid >> 1;
  int bid = blockIdx.x;
  // XCD-grouping: bid%8 fixes a group of 4 bh; all 16 q-blocks of those bh
  // run on one XCD -> K+V working set 2 MB, L2-resident.
  int bh = ((bid & 7) << 2) | ((bid >> 3) & 3);
  int qsb = bid >> 5;                              // 0..15
  int Q0 = qsb * 64;
  int q0 = Q0 + qt * 32;
  int l31 = lane & 31, hl = lane >> 5;
  int b = bh >> 3;

  {
    const short8* src = (const short8*)(Qrel + bh * 264192 + Q0 * 258);
    short8* dst = (short8*)qlds;
    for (int i = tid; i < 2064; i += 256) dst[i] = src[i];
  }

  short8 aq[8];
  const short* qrow = Qp + bh * 131072 + (q0 + l31) * 128 + hl * 8;
#pragma unroll
  for (int s = 0; s < 8; ++s) aq[s] = *(const short8*)(qrow + s * 16);
  __syncthreads();

  float16a O[4];
#pragma unroll
  for (int d = 0; d < 4; ++d)
#pragma unroll
    for (int i = 0; i < 16; ++i) O[d][i] = 0.f;
  float lsum = 0.f;

  int klo = Q0 - 256; if (klo < 0) klo = 0;        // 32-aligned
  int khi = Q0 + 320; if (khi > 1024) khi = 1024;

  const short* kbase = Kp + bh * 131072 + hl * 8;
  const short* vbase = Vt + bh * 131072 + hl * 8;
  const unsigned char* pmrow = kpm + b * 1024;
  int qv = q0 + l31;                // this lane's q-row
  int rowb = (qt * 32 + l31) * 258;

  int k0 = klo + half * 32;
  short8 kb[8];
  unsigned pm32 = 0;
  {
    const short* krow = kbase + (k0 + l31) * 128;
#pragma unroll
    for (int s = 0; s < 8; ++s) kb[s] = *(const short8*)(krow + s * 16);
    pm32 = (unsigned)__ballot(pmrow[k0 + l31] != 0);
  }

  for (; k0 < khi; k0 += 64) {
    unsigned pmc = pm32;
    // S = K^T-as-A x Q-as-B : C col(lane)=q, row(reg,hl)=key offset
    float16a S;
#pragma unroll
    for (int i = 0; i < 16; ++i) S[i] = 0.f;
#pragma unroll
    for (int s = 0; s < 8; ++s) S = MFMA32(kb[s], aq[s], S);

    // prefetch next K tile NOW (full iteration of cover before next S-MFMA);
    // load next pad-mask byte, defer the ballot to loop bottom.
    int kn = k0 + 64;
    unsigned char pmb = 0;
    if (kn < khi) {
      const short* krow = kbase + (kn + l31) * 128;
#pragma unroll
      for (int s = 0; s < 8; ++s) kb[s] = *(const short8*)(krow + s * 16);
      pmb = pmrow[kn + l31];
    }

    // V fragments for the current tile (cover: softmax + cvt before PV)
    short8 vb0[4], vb1[4];
#pragma unroll
    for (int dblk = 0; dblk < 4; ++dblk) {
      const short* vrow = vbase + (dblk * 32 + l31) * 1024 + k0;
      vb0[dblk] = *(const short8*)(vrow);
      vb1[dblk] = *(const short8*)(vrow + 16);
    }

    // softmax epilogue: per-lane q-row, 16 key-offsets in regs
    int dq = k0 - qv;
    bool edge = (k0 - q0 < -224) | (k0 - q0 > 224) | (pmc != 0);
    if (!edge) {
      int rb = dq + 4 * hl + 128;
#pragma unroll
      for (int i = 0; i < 16; ++i) {
        int rr = rb + (i & 3) + 8 * (i >> 2);
        rr = rr < 0 ? 0 : (rr > 256 ? 256 : rr);
        float pe = __builtin_amdgcn_exp2f(S[i] + bf2f(qlds[rowb + rr]));
        S[i] = pe;
        lsum += pe;
      }
    } else {
#pragma unroll
      for (int i = 0; i < 16; ++i) {
        int koff = (i & 3) + 8 * (i >> 2) + 4 * hl;
        int dd = dq + koff;
        int rr = dd < -128 ? 0 : (dd > 128 ? 256 : dd + 128);
        float rel = bf2f(qlds[rowb + rr]);
        int msk = (dd < -256) | (dd > 256) | (int)((pmc >> koff) & 1u);
        float pe = msk ? 0.f : __builtin_amdgcn_exp2f(S[i] + rel);
        S[i] = pe;
        lsum += pe;
      }
    }

    // P (f32 C-layout) -> bf16 A-fragments: 8 cvt_pk + 4 permlane32_swap
    short8 ap0, ap1;
    {
      unsigned x0, y0, z0, w0;
      asm("v_cvt_pk_bf16_f32 %0, %1, %2" : "=v"(x0) : "v"(S[0]), "v"(S[1]));
      asm("v_cvt_pk_bf16_f32 %0, %1, %2" : "=v"(y0) : "v"(S[2]), "v"(S[3]));
      asm("v_cvt_pk_bf16_f32 %0, %1, %2" : "=v"(z0) : "v"(S[4]), "v"(S[5]));
      asm("v_cvt_pk_bf16_f32 %0, %1, %2" : "=v"(w0) : "v"(S[6]), "v"(S[7]));
      asm("v_permlane32_swap_b32 %0, %1" : "+v"(x0), "+v"(z0));
      asm("v_permlane32_swap_b32 %0, %1" : "+v"(y0), "+v"(w0));
      uint4v u0 = {x0, y0, z0, w0};
      ap0 = __builtin_bit_cast(short8, u0);
      unsigned x1, y1, z1, w1;
      asm("v_cvt_pk_bf16_f32 %0, %1, %2" : "=v"(x1) : "v"(S[8]), "v"(S[9]));
      asm("v_cvt_pk_bf16_f32 %0, %1, %2" : "=v"(y1) : "v"(S[10]), "v"(S[11]));
      asm("v_cvt_pk_bf16_f32 %0, %1, %2" : "=v"(z1) : "v"(S[12]), "v"(S[13]));
      asm("v_cvt_pk_bf16_f32 %0, %1, %2" : "=v"(w1) : "v"(S[14]), "v"(S[15]));
      asm("v_permlane32_swap_b32 %0, %1" : "+v"(x1), "+v"(z1));
      asm("v_permlane32_swap_b32 %0, %1" : "+v"(y1), "+v"(w1));
      uint4v u1 = {x1, y1, z1, w1};
      ap1 = __builtin_bit_cast(short8, u1);
    }

#pragma unroll
    for (int dblk = 0; dblk < 4; ++dblk) {
      O[dblk] = MFMA32(ap0, vb0[dblk], O[dblk]);
      O[dblk] = MFMA32(ap1, vb1[dblk], O[dblk]);
    }

    pm32 = (unsigned)__ballot(pmb != 0);   // byte load covered by sm+cvt+PV
  }

  // ---- two-phase combine across the 2 band-halves (no atomics) ----
  lsum += __shfl_xor(lsum, 32);            // hl-pair partial denominators
  __syncthreads();                         // qlds dead; obuf may now alias
  if (half == 1) {
    if (hl == 0) lbuf[qt * 32 + l31] = lsum;
#pragma unroll
    for (int dblk = 0; dblk < 4; ++dblk)
#pragma unroll
      for (int i = 0; i < 16; ++i) {
        int qoff = (i & 3) + 8 * (i >> 2) + 4 * hl;
        obuf[(qt * 32 + qoff) * 128 + dblk * 32 + l31] = O[dblk][i];
      }
  }
  __syncthreads();
  if (half == 0) {
    if (hl == 0) {
      float inv = __builtin_amdgcn_rcpf(lsum + lbuf[qt * 32 + l31]);
      lbuf[qt * 32 + l31] = inv;
    }
#pragma unroll
    for (int dblk = 0; dblk < 4; ++dblk)
#pragma unroll
      for (int i = 0; i < 16; ++i) {
        int qoff = (i & 3) + 8 * (i >> 2) + 4 * hl;
        obuf[(qt * 32 + qoff) * 128 + dblk * 32 + l31] += O[dblk][i];
      }
  }
  __syncthreads();

  // head-major contiguous epilogue: 16 KB line-aligned run per block
#pragma unroll
  for (int it = 0; it < 4; ++it) {
    int idx = tid + it * 256;
    int q = idx >> 4, d = (idx & 15) * 8;
    float inv = lbuf[q];
    const float* ob = &obuf[q * 128 + d];
    short8 v;
#pragma unroll
    for (int j = 0; j < 8; ++j) v[j] = f2bf(ob[j] * inv);
    *(short8*)&O2[(long)bh * 131072 + (long)(Q0 + q) * 128 + d] = v;
  }
}

extern "C" void kernel_launch(void* const* d_in, const int* in_sizes, int n_in,
                              void* d_out, int out_size, void* d_ws, size_t ws_size,
                              hipStream_t stream) {
  const float* Q   = (const float*)d_in[0];
  const float* K   = (const float*)d_in[1];
  const float* V   = (const float*)d_in[2];
  const unsigned char* kpm = (const unsigned char*)d_in[4];
  const float* Wq  = (const float*)d_in[5];
  const float* Wk  = (const float*)d_in[6];
  const float* Wv  = (const float*)d_in[7];
  const float* Wo  = (const float*)d_in[8];
  const float* rel = (const float*)d_in[9];
  float* out = (float*)d_out;

  short* ws = (short*)d_ws;
  short* Qb   = ws;
  short* Kb   = Qb + 4194304;
  short* Vb   = Kb + 4194304;
  short* Wqb  = Vb + 4194304;
  short* Wkb  = Wqb + 1048576;
  short* Wvb  = Wkb + 1048576;
  short* Wob  = Wvb + 1048576;
  short* relb = Wob + 1048576;
  short* Qp   = relb + 263168;
  short* Kp   = Qp + 4194304;
  short* Vt   = Kp + 4194304;
  short* O2   = Vt + 4194304;
  // Qrel (32*1024*258 shorts) aliases Qb/Kb/Vb head: those are dead once
  // gemm_qkv has run, and qrel_k/attn_k are stream-ordered after it.
  short* Qrel = Qb;

  Cvt8 ca;
  ca.in[0] = Q;  ca.out[0] = Qb;
  ca.in[1] = K;  ca.out[1] = Kb;
  ca.in[2] = V;  ca.out[2] = Vb;
  ca.in[3] = Wq; ca.out[3] = Wqb;
  ca.in[4] = Wk; ca.out[4] = Wkb;
  ca.in[5] = Wv; ca.out[5] = Wvb;
  ca.in[6] = Wo; ca.out[6] = Wob;
  ca.in[7] = rel; ca.out[7] = relb;
  cvt8_k<<<dim3(16641), dim3(256), 0, stream>>>(ca);

  gemm_qkv<<<dim3(768), dim3(256), 0, stream>>>(Qb, Kb, Vb, Wqb, Wkb, Wvb, Qp, Kp, Vt);
  qrel_k<<<dim3(8704), dim3(256), 0, stream>>>(Qp, relb, Qrel);
  attn_k<<<dim3(512), dim3(256), 0, stream>>>(Qp, Kp, Vt, Qrel, kpm, O2);
  gemm_o<<<dim3(512), dim3(256), 0, stream>>>(O2, Wob, out);
}

// Round 6
// 239.711 us; speedup vs baseline: 1.5969x; 1.1002x over previous
//
#include <hip/hip_runtime.h>

typedef __attribute__((ext_vector_type(8))) short short8;
typedef __attribute__((ext_vector_type(4))) short short4v;
typedef __attribute__((ext_vector_type(4))) float float4a;
typedef __attribute__((ext_vector_type(16))) float float16a;
typedef __attribute__((ext_vector_type(4))) unsigned int uint4v;

#define MFMA16(a, b, c) __builtin_amdgcn_mfma_f32_16x16x32_bf16(a, b, c, 0, 0, 0)
#define MFMA32(a, b, c) __builtin_amdgcn_mfma_f32_32x32x16_bf16(a, b, c, 0, 0, 0)

static __device__ __forceinline__ short f2bf(float f) {
  unsigned u = __builtin_bit_cast(unsigned, f);
  u += 0x7fff + ((u >> 16) & 1);   // RNE
  return (short)(u >> 16);
}
static __device__ __forceinline__ float bf2f(short s) {
  unsigned u = ((unsigned)(unsigned short)s) << 16;
  return __builtin_bit_cast(float, u);
}

// async global->LDS, 16 B per lane. LDS dest = wave-uniform base + lane*16.
static __device__ __forceinline__ void gl2lds(const short* g, short* l) {
  __builtin_amdgcn_global_load_lds(
      (const __attribute__((address_space(1))) void*)g,
      (__attribute__((address_space(3))) void*)l,
      16, 0, 0);
}

// ---- fused f32->bf16 conversion for all 8 tensors ----
// seg 6 (Wo) additionally permutes columns: WoP[n][h*128+d] = Wo[n][d*8+h],
// so gemm_o can consume head-major O2 with contiguous rows.
struct Cvt8 { const float* in[8]; short* out[8]; };
__global__ __launch_bounds__(256) void cvt8_k(Cvt8 a) {
  int b = blockIdx.x, seg, rb;
  if (b < 12288)      { seg = b >> 12;                 rb = b & 4095; }
  else if (b < 16384) { seg = 3 + ((b - 12288) >> 10); rb = (b - 12288) & 1023; }
  else                { seg = 7;                       rb = b - 16384; }
  int i = rb * 256 + threadIdx.x;
  if (seg == 6) {
    int o = i * 4;                       // 4 consecutive permuted outputs
    int n = o >> 10, kp = o & 1023;
    int h = kp >> 7, d0 = kp & 127;      // d0 multiple of 4, h fixed for all 4
    const float* src = a.in[6] + n * 1024 + h;
    short4v s;
    s.x = f2bf(src[d0 * 8]);
    s.y = f2bf(src[d0 * 8 + 8]);
    s.z = f2bf(src[d0 * 8 + 16]);
    s.w = f2bf(src[d0 * 8 + 24]);
    ((short4v*)a.out[6])[i] = s;
    return;
  }
  float4a v = ((const float4a*)a.in[seg])[i];
  short4v o;
  o.x = f2bf(v.x); o.y = f2bf(v.y); o.z = f2bf(v.z); o.w = f2bf(v.w);
  ((short4v*)a.out[seg])[i] = o;
}

// ---- fused Q/K/V projection GEMM, v2: 2-phase LDS double-buffer + 2D XCD
// swizzle. xcd = bid%8 (round-robin dispatch) decodes to an (mt-group x
// nt-group) region: each XCD owns 8 mt x 4 nt for all 3 segs -> A panels
// (2 MB) + B panels (1 MB) are L2-resident per XCD (was: A re-fetched by
// all 8 XCDs, ~200 MB at L2-miss level). K-loop: STAGE(next tile) issued
// BEFORE compute(cur) with one vmcnt-drain barrier per step, so load
// latency hides under the 32-MFMA compute phase (was: fully serial
// stage->drain->compute). Q output pre-scaled by (1/sqrt(128))*log2(e).
__global__ __launch_bounds__(256) void gemm_qkv(
    const short* __restrict__ Qb, const short* __restrict__ Kb, const short* __restrict__ Vb,
    const short* __restrict__ Wq, const short* __restrict__ Wk, const short* __restrict__ Wv,
    short* __restrict__ Qp, short* __restrict__ Kp, short* __restrict__ Vt) {
  __shared__ short pool[32768];        // 2 stages x (As 8192 | Bs 8192)
  int bid = blockIdx.x;
  int xcd = bid & 7, slot = bid >> 3;  // 768 = 8 XCD x 96
  int seg = slot >> 5, r = slot & 31;
  int mt = ((xcd >> 1) << 3) | (r >> 2);   // 32 mt in 4 groups of 8
  int nt = ((xcd & 1) << 2) | (r & 3);     // 8 nt in 2 groups of 4
  const short* A = seg == 0 ? Qb : (seg == 1 ? Kb : Vb);
  const short* W = seg == 0 ? Wq : (seg == 1 ? Wk : Wv);
  int m0 = mt * 128, n0 = nt * 128;
  int tid = threadIdx.x;
  int lane = tid & 63, wid = tid >> 6;
  int l15 = lane & 15, quad = lane >> 4;
  int wm = wid & 1, wn = wid >> 1;

  int srow = lane >> 3, sunit = (lane & 7) ^ (lane >> 3);
  const short* gA = A + (m0 + wid * 32 + srow) * 1024 + sunit * 8;
  const short* gB = W + (n0 + wid * 32 + srow) * 1024 + sunit * 8;
  int stoff = (wid * 32) * 64;         // per-wave stage offset
  int sw = l15 & 7;

  float4a acc[4][4];
#pragma unroll
  for (int i = 0; i < 4; ++i)
#pragma unroll
    for (int j = 0; j < 4; ++j) acc[i][j] = (float4a){0, 0, 0, 0};

  // prologue: stage tile 0 into buffer 0
#pragma unroll
  for (int t = 0; t < 4; ++t) {
    gl2lds(gA + t * 8192, pool + stoff + t * 512);
    gl2lds(gB + t * 8192, pool + 8192 + stoff + t * 512);
  }
  __syncthreads();                     // implicit vmcnt(0) drains the stage

  int cur = 0;
  for (int kc = 0; kc < 1024; kc += 64) {
    if (kc < 960) {                    // stage next tile into other buffer
      short* nxt = pool + ((cur ^ 1) << 14);
#pragma unroll
      for (int t = 0; t < 4; ++t) {
        gl2lds(gA + kc + 64 + t * 8192, nxt + stoff + t * 512);
        gl2lds(gB + kc + 64 + t * 8192, nxt + 8192 + stoff + t * 512);
      }
    }
    const short* As = pool + (cur << 14);
    const short* Bs = As + 8192;
#pragma unroll
    for (int ks = 0; ks < 2; ++ks) {
      short8 af[4], bfr[4];
#pragma unroll
      for (int i = 0; i < 4; ++i)
        af[i] = *(const short8*)&As[(wm * 64 + i * 16 + l15) * 64 +
                                    (((ks * 4 + quad) ^ sw) * 8)];
#pragma unroll
      for (int j = 0; j < 4; ++j)
        bfr[j] = *(const short8*)&Bs[(wn * 64 + j * 16 + l15) * 64 +
                                     (((ks * 4 + quad) ^ sw) * 8)];
#pragma unroll
      for (int i = 0; i < 4; ++i)
#pragma unroll
        for (int j = 0; j < 4; ++j) acc[i][j] = MFMA16(af[i], bfr[j], acc[i][j]);
    }
    __syncthreads();                   // drains next-stage loads (covered)
    cur ^= 1;
  }

  if (seg < 2) {
    // Qp/Kp: n = h*128+d, d consecutive across lanes -> direct stores
    float scl = (seg == 0) ? 0.12752745707470575f : 1.0f;  // sc * log2(e) for Q
#pragma unroll
    for (int i = 0; i < 4; ++i)
#pragma unroll
      for (int j = 0; j < 4; ++j)
#pragma unroll
        for (int r2 = 0; r2 < 4; ++r2) {
          int m = m0 + wm * 64 + i * 16 + quad * 4 + r2;
          int n = n0 + wn * 64 + j * 16 + l15;
          int bb = m >> 10, s = m & 1023, hh = n >> 7, d = n & 127;
          short v = f2bf(acc[i][j][r2] * scl);
          if (seg == 0) Qp[(((bb * 8 + hh) * 1024) + s) * 128 + d] = v;
          else          Kp[(((bb * 8 + hh) * 1024) + s) * 128 + d] = v;
        }
  } else {
    // Vt: transpose through LDS, then coalesced 256B-row stores.
    short* T = pool;                   // 64 x 132 shorts (reuses stage pool)
    int b2 = m0 >> 10, s0 = m0 & 1023;
    long vb2 = (long)(b2 * 8 + nt) * 131072;
#pragma unroll
    for (int hd = 0; hd < 2; ++hd) {
      __syncthreads();
      if (wn == hd) {
#pragma unroll
        for (int j = 0; j < 4; ++j)
#pragma unroll
          for (int i = 0; i < 4; ++i)
#pragma unroll
            for (int r2 = 0; r2 < 4; ++r2)
              T[(j * 16 + l15) * 132 + wm * 64 + i * 16 + quad * 4 + r2] =
                  f2bf(acc[i][j][r2]);
      }
      __syncthreads();
#pragma unroll
      for (int rr = 0; rr < 4; ++rr) {
        int d = rr * 16 + (tid >> 4);
        short8 v = *(const short8*)&T[d * 132 + (tid & 15) * 8];
        *(short8*)&Vt[vb2 + (hd * 64 + d) * 1024 + s0 + (tid & 15) * 8] = v;
      }
    }
  }
}

// ---- output projection v2: out(f32) = O2h @ WoP^T, head-major A.
// Same 2-phase dbuf + 2D XCD swizzle: each XCD owns 8 mt x 8 nt ->
// A (2 MB) + B (1 MB) L2-resident. ----
__global__ __launch_bounds__(256) void gemm_o(const short* __restrict__ A,
                                              const short* __restrict__ W,
                                              float* __restrict__ C) {
  __shared__ short pool[24576];        // 2 stages x (As 8192 | Bs 4096)
  int bid = blockIdx.x;
  int xcd = bid & 7, slot = bid >> 3;  // 512 = 8 XCD x 64
  int mt = ((xcd >> 1) << 3) | (slot >> 3);  // 32 mt in 4 groups of 8
  int nt = ((xcd & 1) << 3) | (slot & 7);    // 16 nt in 2 groups of 8
  int m0 = mt * 128, n0 = nt * 64;
  int lane = threadIdx.x & 63, wid = threadIdx.x >> 6;
  int l15 = lane & 15, quad = lane >> 4;
  int wm = wid & 1, wn = wid >> 1;

  int srow = lane >> 3, sunit = (lane & 7) ^ (lane >> 3);
  int bb = m0 >> 10, q0t = m0 & 1023;
  const short* gA = A + bb * 1048576 + (q0t + wid * 32 + srow) * 128 + sunit * 8;
  const short* gB = W + (n0 + wid * 16 + srow) * 1024 + sunit * 8;
  int saoff = (wid * 32) * 64;
  int sboff = (wid * 16) * 64;
  int sw = l15 & 7;

  float4a acc[4][2];
#pragma unroll
  for (int i = 0; i < 4; ++i)
#pragma unroll
    for (int j = 0; j < 2; ++j) acc[i][j] = (float4a){0, 0, 0, 0};

  // prologue: stage tile 0 (kc=0 -> koff=0)
#pragma unroll
  for (int t = 0; t < 4; ++t) gl2lds(gA + t * 1024, pool + saoff + t * 512);
#pragma unroll
  for (int t = 0; t < 2; ++t) gl2lds(gB + t * 8192, pool + 8192 + sboff + t * 512);
  __syncthreads();

  int cur = 0;
  for (int kc = 0; kc < 1024; kc += 64) {
    if (kc < 960) {
      int kn = kc + 64;
      int koff = (kn >> 7) * 131072 + (kn & 64);   // head block + half-row
      short* nxt = pool + ((cur ^ 1) * 12288);
#pragma unroll
      for (int t = 0; t < 4; ++t) gl2lds(gA + koff + t * 1024, nxt + saoff + t * 512);
#pragma unroll
      for (int t = 0; t < 2; ++t) gl2lds(gB + kn + t * 8192, nxt + 8192 + sboff + t * 512);
    }
    const short* As = pool + cur * 12288;
    const short* Bs = As + 8192;
#pragma unroll
    for (int ks = 0; ks < 2; ++ks) {
      short8 af[4], bfr[2];
#pragma unroll
      for (int i = 0; i < 4; ++i)
        af[i] = *(const short8*)&As[(wm * 64 + i * 16 + l15) * 64 +
                                    (((ks * 4 + quad) ^ sw) * 8)];
#pragma unroll
      for (int j = 0; j < 2; ++j)
        bfr[j] = *(const short8*)&Bs[(wn * 32 + j * 16 + l15) * 64 +
                                     (((ks * 4 + quad) ^ sw) * 8)];
#pragma unroll
      for (int i = 0; i < 4; ++i)
#pragma unroll
        for (int j = 0; j < 2; ++j) acc[i][j] = MFMA16(af[i], bfr[j], acc[i][j]);
    }
    __syncthreads();
    cur ^= 1;
  }

#pragma unroll
  for (int i = 0; i < 4; ++i)
#pragma unroll
    for (int j = 0; j < 2; ++j)
#pragma unroll
      for (int r2 = 0; r2 < 4; ++r2) {
        int m = m0 + wm * 64 + i * 16 + quad * 4 + r2;
        int n = n0 + wn * 32 + j * 16 + l15;
        C[m * 1024 + n] = acc[i][j][r2];
      }
}

// Qrel[bh, q, r] = sum_d Qp[bh,q,d] * rel[h,r,d]   (bf16 out, 258-padded rows)
__global__ __launch_bounds__(256) void qrel_k(const short* __restrict__ Qp,
                                              const short* __restrict__ rel,
                                              short* __restrict__ Qrel) {
  int lane = threadIdx.x & 63, wid = threadIdx.x >> 6;
  int gw = blockIdx.x * 4 + wid;
  int bh = gw / 1088;
  int rem = gw - bh * 1088;
  int mt = rem / 17;
  int nt = rem - mt * 17;
  int l15 = lane & 15, quad = lane >> 4;
  int h = bh & 7;

  const short* arow = Qp + bh * 131072 + (mt * 16 + l15) * 128 + quad * 8;
  int col = nt * 16 + l15;
  int colc = col > 256 ? 256 : col;
  const short* brow = rel + (h * 257 + colc) * 128 + quad * 8;

  float4a acc = {0, 0, 0, 0};
#pragma unroll
  for (int kc = 0; kc < 128; kc += 32) {
    short8 a = *(const short8*)(arow + kc);
    short8 b = *(const short8*)(brow + kc);
    acc = MFMA16(a, b, acc);
  }
  if (col < 257) {
#pragma unroll
    for (int r = 0; r < 4; ++r) {
      int q = mt * 16 + quad * 4 + r;
      Qrel[bh * 264192 + q * 258 + col] = f2bf(acc[r]);
    }
  }
}

// Banded attention v8: 64-query blocks, grid 512 (= 2 blocks/CU assigned ==
// 2 resident at ~200 unified regs/wave: no sequential rounds). 4 waves =
// 2 q-tiles x 2 band-halves, 32-key tiles step 64 per wave. In-register
// softmax (swapped QK^T), exp2 folding, head-major O2, XCD-grouped bh.
__global__ __launch_bounds__(256, 2) void attn_k(const short* __restrict__ Qp,
                                                 const short* __restrict__ Kp,
                                                 const short* __restrict__ Vt,
                                                 const short* __restrict__ Qrel,
                                                 const unsigned char* __restrict__ kpm,
                                                 short* __restrict__ O2) {
  __shared__ __align__(16) short pool[16512];      // 33024 B union
  short* qlds = pool;                              // 64 x 258 shorts (k-loop)
  float* obuf = (float*)pool;                      // 64 x 128 f32 (epilogue)
  float* lbuf = (float*)pool + 8192;               // 64 f32     (epilogue)
  int tid = threadIdx.x;
  int lane = tid & 63, wid = tid >> 6;
  int qt = wid & 1, half = wid >> 1;
  int bid = blockIdx.x;
  // XCD-grouping: bid%8 fixes a group of 4 bh; all 16 q-blocks of those bh
  // run on one XCD -> K+V working set 2 MB, L2-resident.
  int bh = ((bid & 7) << 2) | ((bid >> 3) & 3);
  int qsb = bid >> 5;                              // 0..15
  int Q0 = qsb * 64;
  int q0 = Q0 + qt * 32;
  int l31 = lane & 31, hl = lane >> 5;
  int b = bh >> 3;

  {
    const short8* src = (const short8*)(Qrel + bh * 264192 + Q0 * 258);
    short8* dst = (short8*)qlds;
    for (int i = tid; i < 2064; i += 256) dst[i] = src[i];
  }

  short8 aq[8];
  const short* qrow = Qp + bh * 131072 + (q0 + l31) * 128 + hl * 8;
#pragma unroll
  for (int s = 0; s < 8; ++s) aq[s] = *(const short8*)(qrow + s * 16);
  __syncthreads();

  float16a O[4];
#pragma unroll
  for (int d = 0; d < 4; ++d)
#pragma unroll
    for (int i = 0; i < 16; ++i) O[d][i] = 0.f;
  float lsum = 0.f;

  int klo = Q0 - 256; if (klo < 0) klo = 0;        // 32-aligned
  int khi = Q0 + 320; if (khi > 1024) khi = 1024;

  const short* kbase = Kp + bh * 131072 + hl * 8;
  const short* vbase = Vt + bh * 131072 + hl * 8;
  const unsigned char* pmrow = kpm + b * 1024;
  int qv = q0 + l31;                // this lane's q-row
  int rowb = (qt * 32 + l31) * 258;

  int k0 = klo + half * 32;
  short8 kb[8];
  unsigned pm32 = 0;
  {
    const short* krow = kbase + (k0 + l31) * 128;
#pragma unroll
    for (int s = 0; s < 8; ++s) kb[s] = *(const short8*)(krow + s * 16);
    pm32 = (unsigned)__ballot(pmrow[k0 + l31] != 0);
  }

  for (; k0 < khi; k0 += 64) {
    unsigned pmc = pm32;
    // S = K^T-as-A x Q-as-B : C col(lane)=q, row(reg,hl)=key offset
    float16a S;
#pragma unroll
    for (int i = 0; i < 16; ++i) S[i] = 0.f;
#pragma unroll
    for (int s = 0; s < 8; ++s) S = MFMA32(kb[s], aq[s], S);

    // prefetch next K tile NOW (full iteration of cover before next S-MFMA);
    // load next pad-mask byte, defer the ballot to loop bottom.
    int kn = k0 + 64;
    unsigned char pmb = 0;
    if (kn < khi) {
      const short* krow = kbase + (kn + l31) * 128;
#pragma unroll
      for (int s = 0; s < 8; ++s) kb[s] = *(const short8*)(krow + s * 16);
      pmb = pmrow[kn + l31];
    }

    // V fragments for the current tile (cover: softmax + cvt before PV)
    short8 vb0[4], vb1[4];
#pragma unroll
    for (int dblk = 0; dblk < 4; ++dblk) {
      const short* vrow = vbase + (dblk * 32 + l31) * 1024 + k0;
      vb0[dblk] = *(const short8*)(vrow);
      vb1[dblk] = *(const short8*)(vrow + 16);
    }

    // softmax epilogue: per-lane q-row, 16 key-offsets in regs
    int dq = k0 - qv;
    bool edge = (k0 - q0 < -224) | (k0 - q0 > 224) | (pmc != 0);
    if (!edge) {
      int rb = dq + 4 * hl + 128;
#pragma unroll
      for (int i = 0; i < 16; ++i) {
        int rr = rb + (i & 3) + 8 * (i >> 2);
        rr = rr < 0 ? 0 : (rr > 256 ? 256 : rr);
        float pe = __builtin_amdgcn_exp2f(S[i] + bf2f(qlds[rowb + rr]));
        S[i] = pe;
        lsum += pe;
      }
    } else {
#pragma unroll
      for (int i = 0; i < 16; ++i) {
        int koff = (i & 3) + 8 * (i >> 2) + 4 * hl;
        int dd = dq + koff;
        int rr = dd < -128 ? 0 : (dd > 128 ? 256 : dd + 128);
        float rel = bf2f(qlds[rowb + rr]);
        int msk = (dd < -256) | (dd > 256) | (int)((pmc >> koff) & 1u);
        float pe = msk ? 0.f : __builtin_amdgcn_exp2f(S[i] + rel);
        S[i] = pe;
        lsum += pe;
      }
    }

    // P (f32 C-layout) -> bf16 A-fragments: 8 cvt_pk + 4 permlane32_swap
    short8 ap0, ap1;
    {
      unsigned x0, y0, z0, w0;
      asm("v_cvt_pk_bf16_f32 %0, %1, %2" : "=v"(x0) : "v"(S[0]), "v"(S[1]));
      asm("v_cvt_pk_bf16_f32 %0, %1, %2" : "=v"(y0) : "v"(S[2]), "v"(S[3]));
      asm("v_cvt_pk_bf16_f32 %0, %1, %2" : "=v"(z0) : "v"(S[4]), "v"(S[5]));
      asm("v_cvt_pk_bf16_f32 %0, %1, %2" : "=v"(w0) : "v"(S[6]), "v"(S[7]));
      asm("v_permlane32_swap_b32 %0, %1" : "+v"(x0), "+v"(z0));
      asm("v_permlane32_swap_b32 %0, %1" : "+v"(y0), "+v"(w0));
      uint4v u0 = {x0, y0, z0, w0};
      ap0 = __builtin_bit_cast(short8, u0);
      unsigned x1, y1, z1, w1;
      asm("v_cvt_pk_bf16_f32 %0, %1, %2" : "=v"(x1) : "v"(S[8]), "v"(S[9]));
      asm("v_cvt_pk_bf16_f32 %0, %1, %2" : "=v"(y1) : "v"(S[10]), "v"(S[11]));
      asm("v_cvt_pk_bf16_f32 %0, %1, %2" : "=v"(z1) : "v"(S[12]), "v"(S[13]));
      asm("v_cvt_pk_bf16_f32 %0, %1, %2" : "=v"(w1) : "v"(S[14]), "v"(S[15]));
      asm("v_permlane32_swap_b32 %0, %1" : "+v"(x1), "+v"(z1));
      asm("v_permlane32_swap_b32 %0, %1" : "+v"(y1), "+v"(w1));
      uint4v u1 = {x1, y1, z1, w1};
      ap1 = __builtin_bit_cast(short8, u1);
    }

#pragma unroll
    for (int dblk = 0; dblk < 4; ++dblk) {
      O[dblk] = MFMA32(ap0, vb0[dblk], O[dblk]);
      O[dblk] = MFMA32(ap1, vb1[dblk], O[dblk]);
    }

    pm32 = (unsigned)__ballot(pmb != 0);   // byte load covered by sm+cvt+PV
  }

  // ---- two-phase combine across the 2 band-halves (no atomics) ----
  lsum += __shfl_xor(lsum, 32);            // hl-pair partial denominators
  __syncthreads();                         // qlds dead; obuf may now alias
  if (half == 1) {
    if (hl == 0) lbuf[qt * 32 + l31] = lsum;
#pragma unroll
    for (int dblk = 0; dblk < 4; ++dblk)
#pragma unroll
      for (int i = 0; i < 16; ++i) {
        int qoff = (i & 3) + 8 * (i >> 2) + 4 * hl;
        obuf[(qt * 32 + qoff) * 128 + dblk * 32 + l31] = O[dblk][i];
      }
  }
  __syncthreads();
  if (half == 0) {
    if (hl == 0) {
      float inv = __builtin_amdgcn_rcpf(lsum + lbuf[qt * 32 + l31]);
      lbuf[qt * 32 + l31] = inv;
    }
#pragma unroll
    for (int dblk = 0; dblk < 4; ++dblk)
#pragma unroll
      for (int i = 0; i < 16; ++i) {
        int qoff = (i & 3) + 8 * (i >> 2) + 4 * hl;
        obuf[(qt * 32 + qoff) * 128 + dblk * 32 + l31] += O[dblk][i];
      }
  }
  __syncthreads();

  // head-major contiguous epilogue: 16 KB line-aligned run per block
#pragma unroll
  for (int it = 0; it < 4; ++it) {
    int idx = tid + it * 256;
    int q = idx >> 4, d = (idx & 15) * 8;
    float inv = lbuf[q];
    const float* ob = &obuf[q * 128 + d];
    short8 v;
#pragma unroll
    for (int j = 0; j < 8; ++j) v[j] = f2bf(ob[j] * inv);
    *(short8*)&O2[(long)bh * 131072 + (long)(Q0 + q) * 128 + d] = v;
  }
}

extern "C" void kernel_launch(void* const* d_in, const int* in_sizes, int n_in,
                              void* d_out, int out_size, void* d_ws, size_t ws_size,
                              hipStream_t stream) {
  const float* Q   = (const float*)d_in[0];
  const float* K   = (const float*)d_in[1];
  const float* V   = (const float*)d_in[2];
  const unsigned char* kpm = (const unsigned char*)d_in[4];
  const float* Wq  = (const float*)d_in[5];
  const float* Wk  = (const float*)d_in[6];
  const float* Wv  = (const float*)d_in[7];
  const float* Wo  = (const float*)d_in[8];
  const float* rel = (const float*)d_in[9];
  float* out = (float*)d_out;

  short* ws = (short*)d_ws;
  short* Qb   = ws;
  short* Kb   = Qb + 4194304;
  short* Vb   = Kb + 4194304;
  short* Wqb  = Vb + 4194304;
  short* Wkb  = Wqb + 1048576;
  short* Wvb  = Wkb + 1048576;
  short* Wob  = Wvb + 1048576;
  short* relb = Wob + 1048576;
  short* Qp   = relb + 263168;
  short* Kp   = Qp + 4194304;
  short* Vt   = Kp + 4194304;
  short* O2   = Vt + 4194304;
  // Qrel (32*1024*258 shorts) aliases Qb/Kb/Vb head: those are dead once
  // gemm_qkv has run, and qrel_k/attn_k are stream-ordered after it.
  short* Qrel = Qb;

  Cvt8 ca;
  ca.in[0] = Q;  ca.out[0] = Qb;
  ca.in[1] = K;  ca.out[1] = Kb;
  ca.in[2] = V;  ca.out[2] = Vb;
  ca.in[3] = Wq; ca.out[3] = Wqb;
  ca.in[4] = Wk; ca.out[4] = Wkb;
  ca.in[5] = Wv; ca.out[5] = Wvb;
  ca.in[6] = Wo; ca.out[6] = Wob;
  ca.in[7] = rel; ca.out[7] = relb;
  cvt8_k<<<dim3(16641), dim3(256), 0, stream>>>(ca);

  gemm_qkv<<<dim3(768), dim3(256), 0, stream>>>(Qb, Kb, Vb, Wqb, Wkb, Wvb, Qp, Kp, Vt);
  qrel_k<<<dim3(8704), dim3(256), 0, stream>>>(Qp, relb, Qrel);
  attn_k<<<dim3(512), dim3(256), 0, stream>>>(Qp, Kp, Vt, Qrel, kpm, O2);
  gemm_o<<<dim3(512), dim3(256), 0, stream>>>(O2, Wob, out);
}

// Round 9
// 220.494 us; speedup vs baseline: 1.7361x; 1.0872x over previous
//
#include <hip/hip_runtime.h>

typedef __attribute__((ext_vector_type(8))) short short8;
typedef __attribute__((ext_vector_type(4))) short short4v;
typedef __attribute__((ext_vector_type(4))) float float4a;
typedef __attribute__((ext_vector_type(16))) float float16a;
typedef __attribute__((ext_vector_type(4))) unsigned int uint4v;

#define MFMA16(a, b, c) __builtin_amdgcn_mfma_f32_16x16x32_bf16(a, b, c, 0, 0, 0)
#define MFMA32(a, b, c) __builtin_amdgcn_mfma_f32_32x32x16_bf16(a, b, c, 0, 0, 0)

static __device__ __forceinline__ short f2bf(float f) {
  unsigned u = __builtin_bit_cast(unsigned, f);
  u += 0x7fff + ((u >> 16) & 1);   // RNE
  return (short)(u >> 16);
}
static __device__ __forceinline__ float bf2f(short s) {
  unsigned u = ((unsigned)(unsigned short)s) << 16;
  return __builtin_bit_cast(float, u);
}

// async global->LDS, 16 B per lane. LDS dest = wave-uniform base + lane*16.
static __device__ __forceinline__ void gl2lds(const short* g, short* l) {
  __builtin_amdgcn_global_load_lds(
      (const __attribute__((address_space(1))) void*)g,
      (__attribute__((address_space(3))) void*)l,
      16, 0, 0);
}

// ---- fused f32->bf16 conversion for all 8 tensors ----
// seg 6 (Wo) additionally permutes columns: WoP[n][h*128+d] = Wo[n][d*8+h],
// so gemm_o can consume head-major O2 with contiguous rows.
struct Cvt8 { const float* in[8]; short* out[8]; };
__global__ __launch_bounds__(256) void cvt8_k(Cvt8 a) {
  int b = blockIdx.x, seg, rb;
  if (b < 12288)      { seg = b >> 12;                 rb = b & 4095; }
  else if (b < 16384) { seg = 3 + ((b - 12288) >> 10); rb = (b - 12288) & 1023; }
  else                { seg = 7;                       rb = b - 16384; }
  int i = rb * 256 + threadIdx.x;
  if (seg == 6) {
    int o = i * 4;                       // 4 consecutive permuted outputs
    int n = o >> 10, kp = o & 1023;
    int h = kp >> 7, d0 = kp & 127;      // d0 multiple of 4, h fixed for all 4
    const float* src = a.in[6] + n * 1024 + h;
    short4v s;
    s.x = f2bf(src[d0 * 8]);
    s.y = f2bf(src[d0 * 8 + 8]);
    s.z = f2bf(src[d0 * 8 + 16]);
    s.w = f2bf(src[d0 * 8 + 24]);
    ((short4v*)a.out[6])[i] = s;
    return;
  }
  float4a v = ((const float4a*)a.in[seg])[i];
  short4v o;
  o.x = f2bf(v.x); o.y = f2bf(v.y); o.z = f2bf(v.z); o.w = f2bf(v.w);
  ((short4v*)a.out[seg])[i] = o;
}

// ---- fused Q/K/V projection GEMM: 2-phase LDS double-buffer + 2D XCD
// swizzle (verified round 6: 62 -> <42 us). ----
__global__ __launch_bounds__(256) void gemm_qkv(
    const short* __restrict__ Qb, const short* __restrict__ Kb, const short* __restrict__ Vb,
    const short* __restrict__ Wq, const short* __restrict__ Wk, const short* __restrict__ Wv,
    short* __restrict__ Qp, short* __restrict__ Kp, short* __restrict__ Vt) {
  __shared__ short pool[32768];        // 2 stages x (As 8192 | Bs 8192)
  int bid = blockIdx.x;
  int xcd = bid & 7, slot = bid >> 3;  // 768 = 8 XCD x 96
  int seg = slot >> 5, r = slot & 31;
  int mt = ((xcd >> 1) << 3) | (r >> 2);   // 32 mt in 4 groups of 8
  int nt = ((xcd & 1) << 2) | (r & 3);     // 8 nt in 2 groups of 4
  const short* A = seg == 0 ? Qb : (seg == 1 ? Kb : Vb);
  const short* W = seg == 0 ? Wq : (seg == 1 ? Wk : Wv);
  int m0 = mt * 128, n0 = nt * 128;
  int tid = threadIdx.x;
  int lane = tid & 63, wid = tid >> 6;
  int l15 = lane & 15, quad = lane >> 4;
  int wm = wid & 1, wn = wid >> 1;

  int srow = lane >> 3, sunit = (lane & 7) ^ (lane >> 3);
  const short* gA = A + (m0 + wid * 32 + srow) * 1024 + sunit * 8;
  const short* gB = W + (n0 + wid * 32 + srow) * 1024 + sunit * 8;
  int stoff = (wid * 32) * 64;         // per-wave stage offset
  int sw = l15 & 7;

  float4a acc[4][4];
#pragma unroll
  for (int i = 0; i < 4; ++i)
#pragma unroll
    for (int j = 0; j < 4; ++j) acc[i][j] = (float4a){0, 0, 0, 0};

  // prologue: stage tile 0 into buffer 0
#pragma unroll
  for (int t = 0; t < 4; ++t) {
    gl2lds(gA + t * 8192, pool + stoff + t * 512);
    gl2lds(gB + t * 8192, pool + 8192 + stoff + t * 512);
  }
  __syncthreads();                     // implicit vmcnt(0) drains the stage

  int cur = 0;
  for (int kc = 0; kc < 1024; kc += 64) {
    if (kc < 960) {                    // stage next tile into other buffer
      short* nxt = pool + ((cur ^ 1) << 14);
#pragma unroll
      for (int t = 0; t < 4; ++t) {
        gl2lds(gA + kc + 64 + t * 8192, nxt + stoff + t * 512);
        gl2lds(gB + kc + 64 + t * 8192, nxt + 8192 + stoff + t * 512);
      }
    }
    const short* As = pool + (cur << 14);
    const short* Bs = As + 8192;
#pragma unroll
    for (int ks = 0; ks < 2; ++ks) {
      short8 af[4], bfr[4];
#pragma unroll
      for (int i = 0; i < 4; ++i)
        af[i] = *(const short8*)&As[(wm * 64 + i * 16 + l15) * 64 +
                                    (((ks * 4 + quad) ^ sw) * 8)];
#pragma unroll
      for (int j = 0; j < 4; ++j)
        bfr[j] = *(const short8*)&Bs[(wn * 64 + j * 16 + l15) * 64 +
                                     (((ks * 4 + quad) ^ sw) * 8)];
#pragma unroll
      for (int i = 0; i < 4; ++i)
#pragma unroll
        for (int j = 0; j < 4; ++j) acc[i][j] = MFMA16(af[i], bfr[j], acc[i][j]);
    }
    __syncthreads();                   // drains next-stage loads (covered)
    cur ^= 1;
  }

  if (seg < 2) {
    // Qp/Kp: n = h*128+d, d consecutive across lanes -> direct stores
    float scl = (seg == 0) ? 0.12752745707470575f : 1.0f;  // sc * log2(e) for Q
#pragma unroll
    for (int i = 0; i < 4; ++i)
#pragma unroll
      for (int j = 0; j < 4; ++j)
#pragma unroll
        for (int r2 = 0; r2 < 4; ++r2) {
          int m = m0 + wm * 64 + i * 16 + quad * 4 + r2;
          int n = n0 + wn * 64 + j * 16 + l15;
          int bb = m >> 10, s = m & 1023, hh = n >> 7, d = n & 127;
          short v = f2bf(acc[i][j][r2] * scl);
          if (seg == 0) Qp[(((bb * 8 + hh) * 1024) + s) * 128 + d] = v;
          else          Kp[(((bb * 8 + hh) * 1024) + s) * 128 + d] = v;
        }
  } else {
    // Vt: transpose through LDS, then coalesced 256B-row stores.
    short* T = pool;                   // 64 x 132 shorts (reuses stage pool)
    int b2 = m0 >> 10, s0 = m0 & 1023;
    long vb2 = (long)(b2 * 8 + nt) * 131072;
#pragma unroll
    for (int hd = 0; hd < 2; ++hd) {
      __syncthreads();
      if (wn == hd) {
#pragma unroll
        for (int j = 0; j < 4; ++j)
#pragma unroll
          for (int i = 0; i < 4; ++i)
#pragma unroll
            for (int r2 = 0; r2 < 4; ++r2)
              T[(j * 16 + l15) * 132 + wm * 64 + i * 16 + quad * 4 + r2] =
                  f2bf(acc[i][j][r2]);
      }
      __syncthreads();
#pragma unroll
      for (int rr = 0; rr < 4; ++rr) {
        int d = rr * 16 + (tid >> 4);
        short8 v = *(const short8*)&T[d * 132 + (tid & 15) * 8];
        *(short8*)&Vt[vb2 + (hd * 64 + d) * 1024 + s0 + (tid & 15) * 8] = v;
      }
    }
  }
}

// ---- output projection: out(f32) = O2h @ WoP^T, head-major A. 2-phase dbuf
// + 2D XCD swizzle (verified round 6). ----
__global__ __launch_bounds__(256) void gemm_o(const short* __restrict__ A,
                                              const short* __restrict__ W,
                                              float* __restrict__ C) {
  __shared__ short pool[24576];        // 2 stages x (As 8192 | Bs 4096)
  int bid = blockIdx.x;
  int xcd = bid & 7, slot = bid >> 3;  // 512 = 8 XCD x 64
  int mt = ((xcd >> 1) << 3) | (slot >> 3);  // 32 mt in 4 groups of 8
  int nt = ((xcd & 1) << 3) | (slot & 7);    // 16 nt in 2 groups of 8
  int m0 = mt * 128, n0 = nt * 64;
  int lane = threadIdx.x & 63, wid = threadIdx.x >> 6;
  int l15 = lane & 15, quad = lane >> 4;
  int wm = wid & 1, wn = wid >> 1;

  int srow = lane >> 3, sunit = (lane & 7) ^ (lane >> 3);
  int bb = m0 >> 10, q0t = m0 & 1023;
  const short* gA = A + bb * 1048576 + (q0t + wid * 32 + srow) * 128 + sunit * 8;
  const short* gB = W + (n0 + wid * 16 + srow) * 1024 + sunit * 8;
  int saoff = (wid * 32) * 64;
  int sboff = (wid * 16) * 64;
  int sw = l15 & 7;

  float4a acc[4][2];
#pragma unroll
  for (int i = 0; i < 4; ++i)
#pragma unroll
    for (int j = 0; j < 2; ++j) acc[i][j] = (float4a){0, 0, 0, 0};

  // prologue: stage tile 0 (kc=0 -> koff=0)
#pragma unroll
  for (int t = 0; t < 4; ++t) gl2lds(gA + t * 1024, pool + saoff + t * 512);
#pragma unroll
  for (int t = 0; t < 2; ++t) gl2lds(gB + t * 8192, pool + 8192 + sboff + t * 512);
  __syncthreads();

  int cur = 0;
  for (int kc = 0; kc < 1024; kc += 64) {
    if (kc < 960) {
      int kn = kc + 64;
      int koff = (kn >> 7) * 131072 + (kn & 64);   // head block + half-row
      short* nxt = pool + ((cur ^ 1) * 12288);
#pragma unroll
      for (int t = 0; t < 4; ++t) gl2lds(gA + koff + t * 1024, nxt + saoff + t * 512);
#pragma unroll
      for (int t = 0; t < 2; ++t) gl2lds(gB + kn + t * 8192, nxt + 8192 + sboff + t * 512);
    }
    const short* As = pool + cur * 12288;
    const short* Bs = As + 8192;
#pragma unroll
    for (int ks = 0; ks < 2; ++ks) {
      short8 af[4], bfr[2];
#pragma unroll
      for (int i = 0; i < 4; ++i)
        af[i] = *(const short8*)&As[(wm * 64 + i * 16 + l15) * 64 +
                                    (((ks * 4 + quad) ^ sw) * 8)];
#pragma unroll
      for (int j = 0; j < 2; ++j)
        bfr[j] = *(const short8*)&Bs[(wn * 32 + j * 16 + l15) * 64 +
                                     (((ks * 4 + quad) ^ sw) * 8)];
#pragma unroll
      for (int i = 0; i < 4; ++i)
#pragma unroll
        for (int j = 0; j < 2; ++j) acc[i][j] = MFMA16(af[i], bfr[j], acc[i][j]);
    }
    __syncthreads();
    cur ^= 1;
  }

#pragma unroll
  for (int i = 0; i < 4; ++i)
#pragma unroll
    for (int j = 0; j < 2; ++j)
#pragma unroll
      for (int r2 = 0; r2 < 4; ++r2) {
        int m = m0 + wm * 64 + i * 16 + quad * 4 + r2;
        int n = n0 + wn * 32 + j * 16 + l15;
        C[m * 1024 + n] = acc[i][j][r2];
      }
}

// Qrel[bh, q, r] = sum_d Qp[bh,q,d] * rel[h,r,d]   (bf16 out, 258-padded rows)
__global__ __launch_bounds__(256) void qrel_k(const short* __restrict__ Qp,
                                              const short* __restrict__ rel,
                                              short* __restrict__ Qrel) {
  int lane = threadIdx.x & 63, wid = threadIdx.x >> 6;
  int gw = blockIdx.x * 4 + wid;
  int bh = gw / 1088;
  int rem = gw - bh * 1088;
  int mt = rem / 17;
  int nt = rem - mt * 17;
  int l15 = lane & 15, quad = lane >> 4;
  int h = bh & 7;

  const short* arow = Qp + bh * 131072 + (mt * 16 + l15) * 128 + quad * 8;
  int col = nt * 16 + l15;
  int colc = col > 256 ? 256 : col;
  const short* brow = rel + (h * 257 + colc) * 128 + quad * 8;

  float4a acc = {0, 0, 0, 0};
#pragma unroll
  for (int kc = 0; kc < 128; kc += 32) {
    short8 a = *(const short8*)(arow + kc);
    short8 b = *(const short8*)(brow + kc);
    acc = MFMA16(a, b, acc);
  }
  if (col < 257) {
#pragma unroll
    for (int r = 0; r < 4; ++r) {
      int q = mt * 16 + quad * 4 + r;
      Qrel[bh * 264192 + q * 258 + col] = f2bf(acc[r]);
    }
  }
}

// Banded attention v9 (third submission; rounds 7-8 died to container/infra
// failures with no compile or correctness diagnostic; kernel audited clean
// for barrier divergence, OOB, gl2lds contract, LDS budget, waitcnt order):
// block-cooperative LDS staging. 64-q blocks, grid 512, 4 waves = qt (q
// 32-tile) x kh (key 32-half). Per 64-key tile, K[64][128] (16 KB) and
// V=Vt[128][64] (16 KB) staged ONCE per block via gl2lds (coalesced 1 KB/
// instr; replaces per-wave scattered 256B/2KB-stride register gathers that
// were request-rate/vmcnt-chain bound), consumed by both qt waves.
// XOR-swizzle via pre-swizzled GLOBAL source (LDS dest linear for gl2lds):
// K slot (r,s) holds unit s^(r&15) -> conflict-free ds_read_b128; V slot
// (d,s) holds unit s^(d&7) -> 4-way (cheap). Single-buffered T3-minimum:
// {ds_read frags; barrier; stage next; compute; barrier}. In-register
// softmax (swapped QK^T), exp2 folding, head-major O2, XCD-grouped bh.
__global__ __launch_bounds__(256, 2) void attn_k(const short* __restrict__ Qp,
                                                 const short* __restrict__ Kp,
                                                 const short* __restrict__ Vt,
                                                 const short* __restrict__ Qrel,
                                                 const unsigned char* __restrict__ kpm,
                                                 short* __restrict__ O2) {
  __shared__ __align__(16) short pool[32896];      // 65792 B
  short* qlds = pool;                              // 64 x 258 shorts
  short* Kbuf = pool + 16512;                      // [64 k][128 d] swizzled
  short* Vbuf = pool + 16512 + 8192;               // [128 d][64 k] swizzled
  float* obuf = (float*)(pool + 16512);            // epilogue alias (32 KB)
  float* lbuf = (float*)pool;                      // epilogue alias (256 B)
  int tid = threadIdx.x;
  int lane = tid & 63, wid = tid >> 6;
  int qt = wid & 1, kh = wid >> 1;
  int bid = blockIdx.x;
  // XCD-grouping: bid%8 fixes a group of 4 bh; all 16 q-blocks of those bh
  // run on one XCD -> K+V working set 2 MB, L2-resident.
  int bh = ((bid & 7) << 2) | ((bid >> 3) & 3);
  int qsb = bid >> 5;                              // 0..15
  int Q0 = qsb * 64;
  int q0 = Q0 + qt * 32;
  int l31 = lane & 31, hl = lane >> 5;
  int b = bh >> 3;

  int klo = Q0 - 256; if (klo < 0) klo = 0;        // 64-aligned
  int khi = Q0 + 320; if (khi > 1024) khi = 1024;  // 64-aligned

  const short* kgbase = Kp + (long)bh * 131072;
  const short* vgbase = Vt + (long)bh * 131072;
  const unsigned char* pmrow = kpm + b * 1024;

  // staging decomposition (per wave):
  // K: 4 calls x 4 rows: lane covers row wid*16+c*4+(lane>>4), slot lane&15,
  //    global unit = slot ^ (c*4 + (lane>>4))
  int ksr = lane >> 4, ksu = lane & 15;
  // V: 4 calls x 8 rows: lane covers d-row wid*32+c*8+(lane>>3), slot lane&7,
  //    global unit = (lane&7) ^ (lane>>3)   (c*8, wid*32 == 0 mod 8)
  int vsr = lane >> 3, vsu = (lane & 7) ^ (lane >> 3);

#define STAGE_KV(KT)                                                          \
  {                                                                           \
    int _k0 = (KT);                                                           \
    _Pragma("unroll")                                                         \
    for (int c = 0; c < 4; ++c) {                                             \
      int rl = wid * 16 + c * 4 + ksr;                                        \
      gl2lds(kgbase + (long)(_k0 + rl) * 128 + ((ksu ^ (c * 4 + ksr)) * 8),   \
             Kbuf + (wid * 16 + c * 4) * 128);                                \
    }                                                                         \
    _Pragma("unroll")                                                         \
    for (int c = 0; c < 4; ++c) {                                             \
      int rl = wid * 32 + c * 8 + vsr;                                        \
      gl2lds(vgbase + (long)rl * 1024 + _k0 + vsu * 8,                        \
             Vbuf + (wid * 32 + c * 8) * 64);                                 \
    }                                                                         \
  }

  // prologue: Qrel -> qlds, Q frags, stage tile 0, first pad-mask bytes
  {
    const short8* src = (const short8*)(Qrel + bh * 264192 + Q0 * 258);
    short8* dst = (short8*)qlds;
    for (int i = tid; i < 2064; i += 256) dst[i] = src[i];
  }
  short8 aq[8];
  const short* qrow = Qp + bh * 131072 + (q0 + l31) * 128 + hl * 8;
#pragma unroll
  for (int s = 0; s < 8; ++s) aq[s] = *(const short8*)(qrow + s * 16);
  STAGE_KV(klo);
  unsigned char pmb = pmrow[klo + kh * 32 + l31];
  __syncthreads();                       // drains qlds writes + stage vmcnt
  unsigned pm32 = (unsigned)__ballot(pmb != 0);

  float16a O[4];
#pragma unroll
  for (int d = 0; d < 4; ++d)
#pragma unroll
    for (int i = 0; i < 16; ++i) O[d][i] = 0.f;
  float lsum = 0.f;

  int qv = q0 + l31;                     // this lane's q-row
  int rowb = (qt * 32 + l31) * 258;
  int r15 = l31 & 15;                    // K read swizzle (kh*32 == 0 mod 16)
  int d7 = l31 & 7;                      // V read swizzle

  for (int k0 = klo; k0 < khi; k0 += 64) {
    int kw = k0 + kh * 32;               // this wave's 32-key base
    // ---- LDS -> register fragments (before buffer is overwritten) ----
    short8 kf[8];
    const short* Kr = Kbuf + (kh * 32 + l31) * 128;
#pragma unroll
    for (int s = 0; s < 8; ++s)
      kf[s] = *(const short8*)&Kr[(((2 * s + hl) ^ r15) * 8)];
    short8 vf0[4], vf1[4];
#pragma unroll
    for (int dblk = 0; dblk < 4; ++dblk) {
      const short* Vr = Vbuf + (dblk * 32 + l31) * 64;
      vf0[dblk] = *(const short8*)&Vr[(((kh * 4 + hl) ^ d7) * 8)];
      vf1[dblk] = *(const short8*)&Vr[(((kh * 4 + 2 + hl) ^ d7) * 8)];
    }
    __syncthreads();                     // all waves done reading the buffer

    // ---- stage next tile (hides under compute below) ----
    int k1 = k0 + 64;
    unsigned char pmn = 0;
    if (k1 < khi) {
      STAGE_KV(k1);
      pmn = pmrow[k1 + kh * 32 + l31];
    }
    unsigned pmc = pm32;

    // ---- S = K^T x Q : col(lane)=q, row(reg,hl)=key offset ----
    float16a S;
#pragma unroll
    for (int i = 0; i < 16; ++i) S[i] = 0.f;
#pragma unroll
    for (int s = 0; s < 8; ++s) S = MFMA32(kf[s], aq[s], S);

    // ---- softmax: per-lane q-row, 16 key-offsets in regs ----
    int dq = kw - qv;
    bool edge = (kw - q0 < -224) | (kw - q0 > 224) | (pmc != 0);
    if (!edge) {
      int rb = dq + 4 * hl + 128;
#pragma unroll
      for (int i = 0; i < 16; ++i) {
        int rr = rb + (i & 3) + 8 * (i >> 2);
        rr = rr < 0 ? 0 : (rr > 256 ? 256 : rr);
        float pe = __builtin_amdgcn_exp2f(S[i] + bf2f(qlds[rowb + rr]));
        S[i] = pe;
        lsum += pe;
      }
    } else {
#pragma unroll
      for (int i = 0; i < 16; ++i) {
        int koff = (i & 3) + 8 * (i >> 2) + 4 * hl;
        int dd = dq + koff;
        int rr = dd < -128 ? 0 : (dd > 128 ? 256 : dd + 128);
        float rel = bf2f(qlds[rowb + rr]);
        int msk = (dd < -256) | (dd > 256) | (int)((pmc >> koff) & 1u);
        float pe = msk ? 0.f : __builtin_amdgcn_exp2f(S[i] + rel);
        S[i] = pe;
        lsum += pe;
      }
    }

    // ---- P (f32 C-layout) -> bf16 A-frags: 8 cvt_pk + 4 permlane32_swap ----
    short8 ap0, ap1;
    {
      unsigned x0, y0, z0, w0;
      asm("v_cvt_pk_bf16_f32 %0, %1, %2" : "=v"(x0) : "v"(S[0]), "v"(S[1]));
      asm("v_cvt_pk_bf16_f32 %0, %1, %2" : "=v"(y0) : "v"(S[2]), "v"(S[3]));
      asm("v_cvt_pk_bf16_f32 %0, %1, %2" : "=v"(z0) : "v"(S[4]), "v"(S[5]));
      asm("v_cvt_pk_bf16_f32 %0, %1, %2" : "=v"(w0) : "v"(S[6]), "v"(S[7]));
      asm("v_permlane32_swap_b32 %0, %1" : "+v"(x0), "+v"(z0));
      asm("v_permlane32_swap_b32 %0, %1" : "+v"(y0), "+v"(w0));
      uint4v u0 = {x0, y0, z0, w0};
      ap0 = __builtin_bit_cast(short8, u0);
      unsigned x1, y1, z1, w1;
      asm("v_cvt_pk_bf16_f32 %0, %1, %2" : "=v"(x1) : "v"(S[8]), "v"(S[9]));
      asm("v_cvt_pk_bf16_f32 %0, %1, %2" : "=v"(y1) : "v"(S[10]), "v"(S[11]));
      asm("v_cvt_pk_bf16_f32 %0, %1, %2" : "=v"(z1) : "v"(S[12]), "v"(S[13]));
      asm("v_cvt_pk_bf16_f32 %0, %1, %2" : "=v"(w1) : "v"(S[14]), "v"(S[15]));
      asm("v_permlane32_swap_b32 %0, %1" : "+v"(x1), "+v"(z1));
      asm("v_permlane32_swap_b32 %0, %1" : "+v"(y1), "+v"(w1));
      uint4v u1 = {x1, y1, z1, w1};
      ap1 = __builtin_bit_cast(short8, u1);
    }

    // ---- PV ----
#pragma unroll
    for (int dblk = 0; dblk < 4; ++dblk) {
      O[dblk] = MFMA32(ap0, vf0[dblk], O[dblk]);
      O[dblk] = MFMA32(ap1, vf1[dblk], O[dblk]);
    }

    __syncthreads();                     // drains staging -> buffer ready
    pm32 = (unsigned)__ballot(pmn != 0);
  }
#undef STAGE_KV

  // ---- two-phase combine across the 2 key-halves (no atomics) ----
  lsum += __shfl_xor(lsum, 32);          // hl-pair partial denominators
  __syncthreads();                       // k-loop LDS dead; aliases now safe
  if (kh == 1) {
    if (hl == 0) lbuf[qt * 32 + l31] = lsum;
#pragma unroll
    for (int dblk = 0; dblk < 4; ++dblk)
#pragma unroll
      for (int i = 0; i < 16; ++i) {
        int qoff = (i & 3) + 8 * (i >> 2) + 4 * hl;
        obuf[(qt * 32 + qoff) * 128 + dblk * 32 + l31] = O[dblk][i];
      }
  }
  __syncthreads();
  if (kh == 0) {
    if (hl == 0) {
      float inv = __builtin_amdgcn_rcpf(lsum + lbuf[qt * 32 + l31]);
      lbuf[qt * 32 + l31] = inv;
    }
#pragma unroll
    for (int dblk = 0; dblk < 4; ++dblk)
#pragma unroll
      for (int i = 0; i < 16; ++i) {
        int qoff = (i & 3) + 8 * (i >> 2) + 4 * hl;
        obuf[(qt * 32 + qoff) * 128 + dblk * 32 + l31] += O[dblk][i];
      }
  }
  __syncthreads();

  // head-major contiguous epilogue: 16 KB line-aligned run per block
#pragma unroll
  for (int it = 0; it < 4; ++it) {
    int idx = tid + it * 256;
    int q = idx >> 4, d = (idx & 15) * 8;
    float inv = lbuf[q];
    const float* ob = &obuf[q * 128 + d];
    short8 v;
#pragma unroll
    for (int j = 0; j < 8; ++j) v[j] = f2bf(ob[j] * inv);
    *(short8*)&O2[(long)bh * 131072 + (long)(Q0 + q) * 128 + d] = v;
  }
}

extern "C" void kernel_launch(void* const* d_in, const int* in_sizes, int n_in,
                              void* d_out, int out_size, void* d_ws, size_t ws_size,
                              hipStream_t stream) {
  const float* Q   = (const float*)d_in[0];
  const float* K   = (const float*)d_in[1];
  const float* V   = (const float*)d_in[2];
  const unsigned char* kpm = (const unsigned char*)d_in[4];
  const float* Wq  = (const float*)d_in[5];
  const float* Wk  = (const float*)d_in[6];
  const float* Wv  = (const float*)d_in[7];
  const float* Wo  = (const float*)d_in[8];
  const float* rel = (const float*)d_in[9];
  float* out = (float*)d_out;

  short* ws = (short*)d_ws;
  short* Qb   = ws;
  short* Kb   = Qb + 4194304;
  short* Vb   = Kb + 4194304;
  short* Wqb  = Vb + 4194304;
  short* Wkb  = Wqb + 1048576;
  short* Wvb  = Wkb + 1048576;
  short* Wob  = Wvb + 1048576;
  short* relb = Wob + 1048576;
  short* Qp   = relb + 263168;
  short* Kp   = Qp + 4194304;
  short* Vt   = Kp + 4194304;
  short* O2   = Vt + 4194304;
  // Qrel (32*1024*258 shorts) aliases Qb/Kb/Vb head: those are dead once
  // gemm_qkv has run, and qrel_k/attn_k are stream-ordered after it.
  short* Qrel = Qb;

  Cvt8 ca;
  ca.in[0] = Q;  ca.out[0] = Qb;
  ca.in[1] = K;  ca.out[1] = Kb;
  ca.in[2] = V;  ca.out[2] = Vb;
  ca.in[3] = Wq; ca.out[3] = Wqb;
  ca.in[4] = Wk; ca.out[4] = Wkb;
  ca.in[5] = Wv; ca.out[5] = Wvb;
  ca.in[6] = Wo; ca.out[6] = Wob;
  ca.in[7] = rel; ca.out[7] = relb;
  cvt8_k<<<dim3(16641), dim3(256), 0, stream>>>(ca);

  gemm_qkv<<<dim3(768), dim3(256), 0, stream>>>(Qb, Kb, Vb, Wqb, Wkb, Wvb, Qp, Kp, Vt);
  qrel_k<<<dim3(8704), dim3(256), 0, stream>>>(Qp, relb, Qrel);
  attn_k<<<dim3(512), dim3(256), 0, stream>>>(Qp, Kp, Vt, Qrel, kpm, O2);
  gemm_o<<<dim3(512), dim3(256), 0, stream>>>(O2, Wob, out);
}

// Round 10
// 210.903 us; speedup vs baseline: 1.8150x; 1.0455x over previous
//
#include <hip/hip_runtime.h>

typedef __attribute__((ext_vector_type(8))) short short8;
typedef __attribute__((ext_vector_type(4))) short short4v;
typedef __attribute__((ext_vector_type(4))) float float4a;
typedef __attribute__((ext_vector_type(16))) float float16a;
typedef __attribute__((ext_vector_type(4))) unsigned int uint4v;

#define MFMA16(a, b, c) __builtin_amdgcn_mfma_f32_16x16x32_bf16(a, b, c, 0, 0, 0)
#define MFMA32(a, b, c) __builtin_amdgcn_mfma_f32_32x32x16_bf16(a, b, c, 0, 0, 0)

static __device__ __forceinline__ short f2bf(float f) {
  unsigned u = __builtin_bit_cast(unsigned, f);
  u += 0x7fff + ((u >> 16) & 1);   // RNE
  return (short)(u >> 16);
}
static __device__ __forceinline__ float bf2f(short s) {
  unsigned u = ((unsigned)(unsigned short)s) << 16;
  return __builtin_bit_cast(float, u);
}

// async global->LDS, 16 B per lane. LDS dest = wave-uniform base + lane*16.
static __device__ __forceinline__ void gl2lds(const short* g, short* l) {
  __builtin_amdgcn_global_load_lds(
      (const __attribute__((address_space(1))) void*)g,
      (__attribute__((address_space(3))) void*)l,
      16, 0, 0);
}

// ---- fused f32->bf16 conversion for all 8 tensors ----
// seg 6 (Wo) additionally permutes columns: WoP[n][h*128+d] = Wo[n][d*8+h],
// so gemm_o can consume head-major O2 with contiguous rows.
struct Cvt8 { const float* in[8]; short* out[8]; };
__global__ __launch_bounds__(256) void cvt8_k(Cvt8 a) {
  int b = blockIdx.x, seg, rb;
  if (b < 12288)      { seg = b >> 12;                 rb = b & 4095; }
  else if (b < 16384) { seg = 3 + ((b - 12288) >> 10); rb = (b - 12288) & 1023; }
  else                { seg = 7;                       rb = b - 16384; }
  int i = rb * 256 + threadIdx.x;
  if (seg == 6) {
    int o = i * 4;                       // 4 consecutive permuted outputs
    int n = o >> 10, kp = o & 1023;
    int h = kp >> 7, d0 = kp & 127;      // d0 multiple of 4, h fixed for all 4
    const float* src = a.in[6] + n * 1024 + h;
    short4v s;
    s.x = f2bf(src[d0 * 8]);
    s.y = f2bf(src[d0 * 8 + 8]);
    s.z = f2bf(src[d0 * 8 + 16]);
    s.w = f2bf(src[d0 * 8 + 24]);
    ((short4v*)a.out[6])[i] = s;
    return;
  }
  float4a v = ((const float4a*)a.in[seg])[i];
  short4v o;
  o.x = f2bf(v.x); o.y = f2bf(v.y); o.z = f2bf(v.z); o.w = f2bf(v.w);
  ((short4v*)a.out[seg])[i] = o;
}

// ---- fused Q/K/V projection GEMM: 2-phase LDS double-buffer + 2D XCD
// swizzle (verified round 6: 62 -> <42 us). ----
__global__ __launch_bounds__(256) void gemm_qkv(
    const short* __restrict__ Qb, const short* __restrict__ Kb, const short* __restrict__ Vb,
    const short* __restrict__ Wq, const short* __restrict__ Wk, const short* __restrict__ Wv,
    short* __restrict__ Qp, short* __restrict__ Kp, short* __restrict__ Vt) {
  __shared__ short pool[32768];        // 2 stages x (As 8192 | Bs 8192)
  int bid = blockIdx.x;
  int xcd = bid & 7, slot = bid >> 3;  // 768 = 8 XCD x 96
  int seg = slot >> 5, r = slot & 31;
  int mt = ((xcd >> 1) << 3) | (r >> 2);   // 32 mt in 4 groups of 8
  int nt = ((xcd & 1) << 2) | (r & 3);     // 8 nt in 2 groups of 4
  const short* A = seg == 0 ? Qb : (seg == 1 ? Kb : Vb);
  const short* W = seg == 0 ? Wq : (seg == 1 ? Wk : Wv);
  int m0 = mt * 128, n0 = nt * 128;
  int tid = threadIdx.x;
  int lane = tid & 63, wid = tid >> 6;
  int l15 = lane & 15, quad = lane >> 4;
  int wm = wid & 1, wn = wid >> 1;

  int srow = lane >> 3, sunit = (lane & 7) ^ (lane >> 3);
  const short* gA = A + (m0 + wid * 32 + srow) * 1024 + sunit * 8;
  const short* gB = W + (n0 + wid * 32 + srow) * 1024 + sunit * 8;
  int stoff = (wid * 32) * 64;         // per-wave stage offset
  int sw = l15 & 7;

  float4a acc[4][4];
#pragma unroll
  for (int i = 0; i < 4; ++i)
#pragma unroll
    for (int j = 0; j < 4; ++j) acc[i][j] = (float4a){0, 0, 0, 0};

  // prologue: stage tile 0 into buffer 0
#pragma unroll
  for (int t = 0; t < 4; ++t) {
    gl2lds(gA + t * 8192, pool + stoff + t * 512);
    gl2lds(gB + t * 8192, pool + 8192 + stoff + t * 512);
  }
  __syncthreads();                     // implicit vmcnt(0) drains the stage

  int cur = 0;
  for (int kc = 0; kc < 1024; kc += 64) {
    if (kc < 960) {                    // stage next tile into other buffer
      short* nxt = pool + ((cur ^ 1) << 14);
#pragma unroll
      for (int t = 0; t < 4; ++t) {
        gl2lds(gA + kc + 64 + t * 8192, nxt + stoff + t * 512);
        gl2lds(gB + kc + 64 + t * 8192, nxt + 8192 + stoff + t * 512);
      }
    }
    const short* As = pool + (cur << 14);
    const short* Bs = As + 8192;
#pragma unroll
    for (int ks = 0; ks < 2; ++ks) {
      short8 af[4], bfr[4];
#pragma unroll
      for (int i = 0; i < 4; ++i)
        af[i] = *(const short8*)&As[(wm * 64 + i * 16 + l15) * 64 +
                                    (((ks * 4 + quad) ^ sw) * 8)];
#pragma unroll
      for (int j = 0; j < 4; ++j)
        bfr[j] = *(const short8*)&Bs[(wn * 64 + j * 16 + l15) * 64 +
                                     (((ks * 4 + quad) ^ sw) * 8)];
#pragma unroll
      for (int i = 0; i < 4; ++i)
#pragma unroll
        for (int j = 0; j < 4; ++j) acc[i][j] = MFMA16(af[i], bfr[j], acc[i][j]);
    }
    __syncthreads();                   // drains next-stage loads (covered)
    cur ^= 1;
  }

  if (seg < 2) {
    // Qp/Kp: n = h*128+d, d consecutive across lanes -> direct stores
    float scl = (seg == 0) ? 0.12752745707470575f : 1.0f;  // sc * log2(e) for Q
#pragma unroll
    for (int i = 0; i < 4; ++i)
#pragma unroll
      for (int j = 0; j < 4; ++j)
#pragma unroll
        for (int r2 = 0; r2 < 4; ++r2) {
          int m = m0 + wm * 64 + i * 16 + quad * 4 + r2;
          int n = n0 + wn * 64 + j * 16 + l15;
          int bb = m >> 10, s = m & 1023, hh = n >> 7, d = n & 127;
          short v = f2bf(acc[i][j][r2] * scl);
          if (seg == 0) Qp[(((bb * 8 + hh) * 1024) + s) * 128 + d] = v;
          else          Kp[(((bb * 8 + hh) * 1024) + s) * 128 + d] = v;
        }
  } else {
    // Vt: transpose through LDS, then coalesced 256B-row stores.
    short* T = pool;                   // 64 x 132 shorts (reuses stage pool)
    int b2 = m0 >> 10, s0 = m0 & 1023;
    long vb2 = (long)(b2 * 8 + nt) * 131072;
#pragma unroll
    for (int hd = 0; hd < 2; ++hd) {
      __syncthreads();
      if (wn == hd) {
#pragma unroll
        for (int j = 0; j < 4; ++j)
#pragma unroll
          for (int i = 0; i < 4; ++i)
#pragma unroll
            for (int r2 = 0; r2 < 4; ++r2)
              T[(j * 16 + l15) * 132 + wm * 64 + i * 16 + quad * 4 + r2] =
                  f2bf(acc[i][j][r2]);
      }
      __syncthreads();
#pragma unroll
      for (int rr = 0; rr < 4; ++rr) {
        int d = rr * 16 + (tid >> 4);
        short8 v = *(const short8*)&T[d * 132 + (tid & 15) * 8];
        *(short8*)&Vt[vb2 + (hd * 64 + d) * 1024 + s0 + (tid & 15) * 8] = v;
      }
    }
  }
}

// ---- output projection: out(f32) = O2h @ WoP^T, head-major A. 2-phase dbuf
// + 2D XCD swizzle (verified round 6). ----
__global__ __launch_bounds__(256) void gemm_o(const short* __restrict__ A,
                                              const short* __restrict__ W,
                                              float* __restrict__ C) {
  __shared__ short pool[24576];        // 2 stages x (As 8192 | Bs 4096)
  int bid = blockIdx.x;
  int xcd = bid & 7, slot = bid >> 3;  // 512 = 8 XCD x 64
  int mt = ((xcd >> 1) << 3) | (slot >> 3);  // 32 mt in 4 groups of 8
  int nt = ((xcd & 1) << 3) | (slot & 7);    // 16 nt in 2 groups of 8
  int m0 = mt * 128, n0 = nt * 64;
  int lane = threadIdx.x & 63, wid = threadIdx.x >> 6;
  int l15 = lane & 15, quad = lane >> 4;
  int wm = wid & 1, wn = wid >> 1;

  int srow = lane >> 3, sunit = (lane & 7) ^ (lane >> 3);
  int bb = m0 >> 10, q0t = m0 & 1023;
  const short* gA = A + bb * 1048576 + (q0t + wid * 32 + srow) * 128 + sunit * 8;
  const short* gB = W + (n0 + wid * 16 + srow) * 1024 + sunit * 8;
  int saoff = (wid * 32) * 64;
  int sboff = (wid * 16) * 64;
  int sw = l15 & 7;

  float4a acc[4][2];
#pragma unroll
  for (int i = 0; i < 4; ++i)
#pragma unroll
    for (int j = 0; j < 2; ++j) acc[i][j] = (float4a){0, 0, 0, 0};

  // prologue: stage tile 0 (kc=0 -> koff=0)
#pragma unroll
  for (int t = 0; t < 4; ++t) gl2lds(gA + t * 1024, pool + saoff + t * 512);
#pragma unroll
  for (int t = 0; t < 2; ++t) gl2lds(gB + t * 8192, pool + 8192 + sboff + t * 512);
  __syncthreads();

  int cur = 0;
  for (int kc = 0; kc < 1024; kc += 64) {
    if (kc < 960) {
      int kn = kc + 64;
      int koff = (kn >> 7) * 131072 + (kn & 64);   // head block + half-row
      short* nxt = pool + ((cur ^ 1) * 12288);
#pragma unroll
      for (int t = 0; t < 4; ++t) gl2lds(gA + koff + t * 1024, nxt + saoff + t * 512);
#pragma unroll
      for (int t = 0; t < 2; ++t) gl2lds(gB + kn + t * 8192, nxt + 8192 + sboff + t * 512);
    }
    const short* As = pool + cur * 12288;
    const short* Bs = As + 8192;
#pragma unroll
    for (int ks = 0; ks < 2; ++ks) {
      short8 af[4], bfr[2];
#pragma unroll
      for (int i = 0; i < 4; ++i)
        af[i] = *(const short8*)&As[(wm * 64 + i * 16 + l15) * 64 +
                                    (((ks * 4 + quad) ^ sw) * 8)];
#pragma unroll
      for (int j = 0; j < 2; ++j)
        bfr[j] = *(const short8*)&Bs[(wn * 32 + j * 16 + l15) * 64 +
                                     (((ks * 4 + quad) ^ sw) * 8)];
#pragma unroll
      for (int i = 0; i < 4; ++i)
#pragma unroll
        for (int j = 0; j < 2; ++j) acc[i][j] = MFMA16(af[i], bfr[j], acc[i][j]);
    }
    __syncthreads();
    cur ^= 1;
  }

#pragma unroll
  for (int i = 0; i < 4; ++i)
#pragma unroll
    for (int j = 0; j < 2; ++j)
#pragma unroll
      for (int r2 = 0; r2 < 4; ++r2) {
        int m = m0 + wm * 64 + i * 16 + quad * 4 + r2;
        int n = n0 + wn * 32 + j * 16 + l15;
        C[m * 1024 + n] = acc[i][j][r2];
      }
}

// Qrel[bh, q, r] = sum_d Qp[bh,q,d] * rel[h,r,d]  (bf16, 258-padded rows)
// v2: block = (bh, group of 4 mt16-tiles), one tile-row per wave; the wave's
// A-fragment (K=128) is loaded ONCE and reused across all 17 nt tiles (was:
// one 16x16 tile per wave, Qp re-read 17x, 8704 blocks -> ~278 MB of 4KB-
// granularity L2 requests). Grid 512; XCD grouping (bid%8 fixes 4 bh) keeps
// Qp (1 MB) + rel (264 KB) L2-resident per XCD. Fragment layout, clamp-at-
// 256, and store guard identical to the verified version.
__global__ __launch_bounds__(256) void qrel_k(const short* __restrict__ Qp,
                                              const short* __restrict__ rel,
                                              short* __restrict__ Qrel) {
  int lane = threadIdx.x & 63, wid = threadIdx.x >> 6;
  int bid = blockIdx.x;
  int xcd = bid & 7, slot = bid >> 3;       // 512 = 8 XCD x 64
  int bh = (xcd << 2) | (slot & 3);         // 4 bh per XCD
  int mtg = slot >> 2;                      // 16 groups of 4 mt-tiles
  int mt = mtg * 4 + wid;
  int l15 = lane & 15, quad = lane >> 4;
  int h = bh & 7;

  const short* arow = Qp + bh * 131072 + (mt * 16 + l15) * 128 + quad * 8;
  short8 a[4];
#pragma unroll
  for (int t = 0; t < 4; ++t) a[t] = *(const short8*)(arow + t * 32);

  const short* rbase = rel + h * 32896 + quad * 8;   // h*257*128
  for (int nt = 0; nt < 17; ++nt) {
    int col = nt * 16 + l15;
    int colc = col > 256 ? 256 : col;
    const short* brow = rbase + colc * 128;
    float4a acc = {0, 0, 0, 0};
#pragma unroll
    for (int t = 0; t < 4; ++t) {
      short8 b = *(const short8*)(brow + t * 32);
      acc = MFMA16(a[t], b, acc);
    }
    if (col < 257) {
#pragma unroll
      for (int r = 0; r < 4; ++r) {
        int q = mt * 16 + quad * 4 + r;
        Qrel[bh * 264192 + q * 258 + col] = f2bf(acc[r]);
      }
    }
  }
}

// Banded attention v9 (verified round 9: attn ~20 us, total 220.5):
// block-cooperative LDS staging. 64-q blocks, grid 512, 4 waves = qt (q
// 32-tile) x kh (key 32-half). Per 64-key tile, K[64][128] (16 KB) and
// V=Vt[128][64] (16 KB) staged ONCE per block via gl2lds (coalesced 1 KB/
// instr), consumed by both qt waves. XOR-swizzle via pre-swizzled GLOBAL
// source (LDS dest linear for gl2lds): K slot (r,s) holds unit s^(r&15) ->
// conflict-free ds_read_b128; V slot (d,s) holds unit s^(d&7) -> 4-way
// (cheap). Single-buffered T3-minimum: {ds_read frags; barrier; stage next;
// compute; barrier}. In-register softmax (swapped QK^T), exp2 folding,
// head-major O2, XCD-grouped bh.
__global__ __launch_bounds__(256, 2) void attn_k(const short* __restrict__ Qp,
                                                 const short* __restrict__ Kp,
                                                 const short* __restrict__ Vt,
                                                 const short* __restrict__ Qrel,
                                                 const unsigned char* __restrict__ kpm,
                                                 short* __restrict__ O2) {
  __shared__ __align__(16) short pool[32896];      // 65792 B
  short* qlds = pool;                              // 64 x 258 shorts
  short* Kbuf = pool + 16512;                      // [64 k][128 d] swizzled
  short* Vbuf = pool + 16512 + 8192;               // [128 d][64 k] swizzled
  float* obuf = (float*)(pool + 16512);            // epilogue alias (32 KB)
  float* lbuf = (float*)pool;                      // epilogue alias (256 B)
  int tid = threadIdx.x;
  int lane = tid & 63, wid = tid >> 6;
  int qt = wid & 1, kh = wid >> 1;
  int bid = blockIdx.x;
  // XCD-grouping: bid%8 fixes a group of 4 bh; all 16 q-blocks of those bh
  // run on one XCD -> K+V working set 2 MB, L2-resident.
  int bh = ((bid & 7) << 2) | ((bid >> 3) & 3);
  int qsb = bid >> 5;                              // 0..15
  int Q0 = qsb * 64;
  int q0 = Q0 + qt * 32;
  int l31 = lane & 31, hl = lane >> 5;
  int b = bh >> 3;

  int klo = Q0 - 256; if (klo < 0) klo = 0;        // 64-aligned
  int khi = Q0 + 320; if (khi > 1024) khi = 1024;  // 64-aligned

  const short* kgbase = Kp + (long)bh * 131072;
  const short* vgbase = Vt + (long)bh * 131072;
  const unsigned char* pmrow = kpm + b * 1024;

  // staging decomposition (per wave):
  // K: 4 calls x 4 rows: lane covers row wid*16+c*4+(lane>>4), slot lane&15,
  //    global unit = slot ^ (c*4 + (lane>>4))
  int ksr = lane >> 4, ksu = lane & 15;
  // V: 4 calls x 8 rows: lane covers d-row wid*32+c*8+(lane>>3), slot lane&7,
  //    global unit = (lane&7) ^ (lane>>3)   (c*8, wid*32 == 0 mod 8)
  int vsr = lane >> 3, vsu = (lane & 7) ^ (lane >> 3);

#define STAGE_KV(KT)                                                          \
  {                                                                           \
    int _k0 = (KT);                                                           \
    _Pragma("unroll")                                                         \
    for (int c = 0; c < 4; ++c) {                                             \
      int rl = wid * 16 + c * 4 + ksr;                                        \
      gl2lds(kgbase + (long)(_k0 + rl) * 128 + ((ksu ^ (c * 4 + ksr)) * 8),   \
             Kbuf + (wid * 16 + c * 4) * 128);                                \
    }                                                                         \
    _Pragma("unroll")                                                         \
    for (int c = 0; c < 4; ++c) {                                             \
      int rl = wid * 32 + c * 8 + vsr;                                        \
      gl2lds(vgbase + (long)rl * 1024 + _k0 + vsu * 8,                        \
             Vbuf + (wid * 32 + c * 8) * 64);                                 \
    }                                                                         \
  }

  // prologue: Qrel -> qlds, Q frags, stage tile 0, first pad-mask bytes
  {
    const short8* src = (const short8*)(Qrel + bh * 264192 + Q0 * 258);
    short8* dst = (short8*)qlds;
    for (int i = tid; i < 2064; i += 256) dst[i] = src[i];
  }
  short8 aq[8];
  const short* qrow = Qp + bh * 131072 + (q0 + l31) * 128 + hl * 8;
#pragma unroll
  for (int s = 0; s < 8; ++s) aq[s] = *(const short8*)(qrow + s * 16);
  STAGE_KV(klo);
  unsigned char pmb = pmrow[klo + kh * 32 + l31];
  __syncthreads();                       // drains qlds writes + stage vmcnt
  unsigned pm32 = (unsigned)__ballot(pmb != 0);

  float16a O[4];
#pragma unroll
  for (int d = 0; d < 4; ++d)
#pragma unroll
    for (int i = 0; i < 16; ++i) O[d][i] = 0.f;
  float lsum = 0.f;

  int qv = q0 + l31;                     // this lane's q-row
  int rowb = (qt * 32 + l31) * 258;
  int r15 = l31 & 15;                    // K read swizzle (kh*32 == 0 mod 16)
  int d7 = l31 & 7;                      // V read swizzle

  for (int k0 = klo; k0 < khi; k0 += 64) {
    int kw = k0 + kh * 32;               // this wave's 32-key base
    // ---- LDS -> register fragments (before buffer is overwritten) ----
    short8 kf[8];
    const short* Kr = Kbuf + (kh * 32 + l31) * 128;
#pragma unroll
    for (int s = 0; s < 8; ++s)
      kf[s] = *(const short8*)&Kr[(((2 * s + hl) ^ r15) * 8)];
    short8 vf0[4], vf1[4];
#pragma unroll
    for (int dblk = 0; dblk < 4; ++dblk) {
      const short* Vr = Vbuf + (dblk * 32 + l31) * 64;
      vf0[dblk] = *(const short8*)&Vr[(((kh * 4 + hl) ^ d7) * 8)];
      vf1[dblk] = *(const short8*)&Vr[(((kh * 4 + 2 + hl) ^ d7) * 8)];
    }
    __syncthreads();                     // all waves done reading the buffer

    // ---- stage next tile (hides under compute below) ----
    int k1 = k0 + 64;
    unsigned char pmn = 0;
    if (k1 < khi) {
      STAGE_KV(k1);
      pmn = pmrow[k1 + kh * 32 + l31];
    }
    unsigned pmc = pm32;

    // ---- S = K^T x Q : col(lane)=q, row(reg,hl)=key offset ----
    float16a S;
#pragma unroll
    for (int i = 0; i < 16; ++i) S[i] = 0.f;
#pragma unroll
    for (int s = 0; s < 8; ++s) S = MFMA32(kf[s], aq[s], S);

    // ---- softmax: per-lane q-row, 16 key-offsets in regs ----
    int dq = kw - qv;
    bool edge = (kw - q0 < -224) | (kw - q0 > 224) | (pmc != 0);
    if (!edge) {
      int rb = dq + 4 * hl + 128;
#pragma unroll
      for (int i = 0; i < 16; ++i) {
        int rr = rb + (i & 3) + 8 * (i >> 2);
        rr = rr < 0 ? 0 : (rr > 256 ? 256 : rr);
        float pe = __builtin_amdgcn_exp2f(S[i] + bf2f(qlds[rowb + rr]));
        S[i] = pe;
        lsum += pe;
      }
    } else {
#pragma unroll
      for (int i = 0; i < 16; ++i) {
        int koff = (i & 3) + 8 * (i >> 2) + 4 * hl;
        int dd = dq + koff;
        int rr = dd < -128 ? 0 : (dd > 128 ? 256 : dd + 128);
        float rel = bf2f(qlds[rowb + rr]);
        int msk = (dd < -256) | (dd > 256) | (int)((pmc >> koff) & 1u);
        float pe = msk ? 0.f : __builtin_amdgcn_exp2f(S[i] + rel);
        S[i] = pe;
        lsum += pe;
      }
    }

    // ---- P (f32 C-layout) -> bf16 A-frags: 8 cvt_pk + 4 permlane32_swap ----
    short8 ap0, ap1;
    {
      unsigned x0, y0, z0, w0;
      asm("v_cvt_pk_bf16_f32 %0, %1, %2" : "=v"(x0) : "v"(S[0]), "v"(S[1]));
      asm("v_cvt_pk_bf16_f32 %0, %1, %2" : "=v"(y0) : "v"(S[2]), "v"(S[3]));
      asm("v_cvt_pk_bf16_f32 %0, %1, %2" : "=v"(z0) : "v"(S[4]), "v"(S[5]));
      asm("v_cvt_pk_bf16_f32 %0, %1, %2" : "=v"(w0) : "v"(S[6]), "v"(S[7]));
      asm("v_permlane32_swap_b32 %0, %1" : "+v"(x0), "+v"(z0));
      asm("v_permlane32_swap_b32 %0, %1" : "+v"(y0), "+v"(w0));
      uint4v u0 = {x0, y0, z0, w0};
      ap0 = __builtin_bit_cast(short8, u0);
      unsigned x1, y1, z1, w1;
      asm("v_cvt_pk_bf16_f32 %0, %1, %2" : "=v"(x1) : "v"(S[8]), "v"(S[9]));
      asm("v_cvt_pk_bf16_f32 %0, %1, %2" : "=v"(y1) : "v"(S[10]), "v"(S[11]));
      asm("v_cvt_pk_bf16_f32 %0, %1, %2" : "=v"(z1) : "v"(S[12]), "v"(S[13]));
      asm("v_cvt_pk_bf16_f32 %0, %1, %2" : "=v"(w1) : "v"(S[14]), "v"(S[15]));
      asm("v_permlane32_swap_b32 %0, %1" : "+v"(x1), "+v"(z1));
      asm("v_permlane32_swap_b32 %0, %1" : "+v"(y1), "+v"(w1));
      uint4v u1 = {x1, y1, z1, w1};
      ap1 = __builtin_bit_cast(short8, u1);
    }

    // ---- PV ----
#pragma unroll
    for (int dblk = 0; dblk < 4; ++dblk) {
      O[dblk] = MFMA32(ap0, vf0[dblk], O[dblk]);
      O[dblk] = MFMA32(ap1, vf1[dblk], O[dblk]);
    }

    __syncthreads();                     // drains staging -> buffer ready
    pm32 = (unsigned)__ballot(pmn != 0);
  }
#undef STAGE_KV

  // ---- two-phase combine across the 2 key-halves (no atomics) ----
  lsum += __shfl_xor(lsum, 32);          // hl-pair partial denominators
  __syncthreads();                       // k-loop LDS dead; aliases now safe
  if (kh == 1) {
    if (hl == 0) lbuf[qt * 32 + l31] = lsum;
#pragma unroll
    for (int dblk = 0; dblk < 4; ++dblk)
#pragma unroll
      for (int i = 0; i < 16; ++i) {
        int qoff = (i & 3) + 8 * (i >> 2) + 4 * hl;
        obuf[(qt * 32 + qoff) * 128 + dblk * 32 + l31] = O[dblk][i];
      }
  }
  __syncthreads();
  if (kh == 0) {
    if (hl == 0) {
      float inv = __builtin_amdgcn_rcpf(lsum + lbuf[qt * 32 + l31]);
      lbuf[qt * 32 + l31] = inv;
    }
#pragma unroll
    for (int dblk = 0; dblk < 4; ++dblk)
#pragma unroll
      for (int i = 0; i < 16; ++i) {
        int qoff = (i & 3) + 8 * (i >> 2) + 4 * hl;
        obuf[(qt * 32 + qoff) * 128 + dblk * 32 + l31] += O[dblk][i];
      }
  }
  __syncthreads();

  // head-major contiguous epilogue: 16 KB line-aligned run per block
#pragma unroll
  for (int it = 0; it < 4; ++it) {
    int idx = tid + it * 256;
    int q = idx >> 4, d = (idx & 15) * 8;
    float inv = lbuf[q];
    const float* ob = &obuf[q * 128 + d];
    short8 v;
#pragma unroll
    for (int j = 0; j < 8; ++j) v[j] = f2bf(ob[j] * inv);
    *(short8*)&O2[(long)bh * 131072 + (long)(Q0 + q) * 128 + d] = v;
  }
}

extern "C" void kernel_launch(void* const* d_in, const int* in_sizes, int n_in,
                              void* d_out, int out_size, void* d_ws, size_t ws_size,
                              hipStream_t stream) {
  const float* Q   = (const float*)d_in[0];
  const float* K   = (const float*)d_in[1];
  const float* V   = (const float*)d_in[2];
  const unsigned char* kpm = (const unsigned char*)d_in[4];
  const float* Wq  = (const float*)d_in[5];
  const float* Wk  = (const float*)d_in[6];
  const float* Wv  = (const float*)d_in[7];
  const float* Wo  = (const float*)d_in[8];
  const float* rel = (const float*)d_in[9];
  float* out = (float*)d_out;

  short* ws = (short*)d_ws;
  short* Qb   = ws;
  short* Kb   = Qb + 4194304;
  short* Vb   = Kb + 4194304;
  short* Wqb  = Vb + 4194304;
  short* Wkb  = Wqb + 1048576;
  short* Wvb  = Wkb + 1048576;
  short* Wob  = Wvb + 1048576;
  short* relb = Wob + 1048576;
  short* Qp   = relb + 263168;
  short* Kp   = Qp + 4194304;
  short* Vt   = Kp + 4194304;
  short* O2   = Vt + 4194304;
  // Qrel (32*1024*258 shorts) aliases Qb/Kb/Vb head: those are dead once
  // gemm_qkv has run, and qrel_k/attn_k are stream-ordered after it.
  short* Qrel = Qb;

  Cvt8 ca;
  ca.in[0] = Q;  ca.out[0] = Qb;
  ca.in[1] = K;  ca.out[1] = Kb;
  ca.in[2] = V;  ca.out[2] = Vb;
  ca.in[3] = Wq; ca.out[3] = Wqb;
  ca.in[4] = Wk; ca.out[4] = Wkb;
  ca.in[5] = Wv; ca.out[5] = Wvb;
  ca.in[6] = Wo; ca.out[6] = Wob;
  ca.in[7] = rel; ca.out[7] = relb;
  cvt8_k<<<dim3(16641), dim3(256), 0, stream>>>(ca);

  gemm_qkv<<<dim3(768), dim3(256), 0, stream>>>(Qb, Kb, Vb, Wqb, Wkb, Wvb, Qp, Kp, Vt);
  qrel_k<<<dim3(512), dim3(256), 0, stream>>>(Qp, relb, Qrel);
  attn_k<<<dim3(512), dim3(256), 0, stream>>>(Qp, Kp, Vt, Qrel, kpm, O2);
  gemm_o<<<dim3(512), dim3(256), 0, stream>>>(O2, Wob, out);
}

// Round 11
// 202.579 us; speedup vs baseline: 1.8896x; 1.0411x over previous
//
#include <hip/hip_runtime.h>

typedef __attribute__((ext_vector_type(8))) short short8;
typedef __attribute__((ext_vector_type(4))) short short4v;
typedef __attribute__((ext_vector_type(4))) float float4a;
typedef __attribute__((ext_vector_type(16))) float float16a;
typedef __attribute__((ext_vector_type(4))) unsigned int uint4v;

#define MFMA16(a, b, c) __builtin_amdgcn_mfma_f32_16x16x32_bf16(a, b, c, 0, 0, 0)
#define MFMA32(a, b, c) __builtin_amdgcn_mfma_f32_32x32x16_bf16(a, b, c, 0, 0, 0)

static __device__ __forceinline__ short f2bf(float f) {
  unsigned u = __builtin_bit_cast(unsigned, f);
  u += 0x7fff + ((u >> 16) & 1);   // RNE
  return (short)(u >> 16);
}
static __device__ __forceinline__ float bf2f(short s) {
  unsigned u = ((unsigned)(unsigned short)s) << 16;
  return __builtin_bit_cast(float, u);
}

// async global->LDS, 16 B per lane. LDS dest = wave-uniform base + lane*16.
static __device__ __forceinline__ void gl2lds(const short* g, short* l) {
  __builtin_amdgcn_global_load_lds(
      (const __attribute__((address_space(1))) void*)g,
      (__attribute__((address_space(3))) void*)l,
      16, 0, 0);
}

// ---- fused f32->bf16 conversion for all 8 tensors ----
// seg 6 (Wo) additionally permutes columns: WoP[n][h*128+d] = Wo[n][d*8+h],
// so gemm_o can consume head-major O2 with contiguous rows.
struct Cvt8 { const float* in[8]; short* out[8]; };
__global__ __launch_bounds__(256) void cvt8_k(Cvt8 a) {
  int b = blockIdx.x, seg, rb;
  if (b < 12288)      { seg = b >> 12;                 rb = b & 4095; }
  else if (b < 16384) { seg = 3 + ((b - 12288) >> 10); rb = (b - 12288) & 1023; }
  else                { seg = 7;                       rb = b - 16384; }
  int i = rb * 256 + threadIdx.x;
  if (seg == 6) {
    int o = i * 4;                       // 4 consecutive permuted outputs
    int n = o >> 10, kp = o & 1023;
    int h = kp >> 7, d0 = kp & 127;      // d0 multiple of 4, h fixed for all 4
    const float* src = a.in[6] + n * 1024 + h;
    short4v s;
    s.x = f2bf(src[d0 * 8]);
    s.y = f2bf(src[d0 * 8 + 8]);
    s.z = f2bf(src[d0 * 8 + 16]);
    s.w = f2bf(src[d0 * 8 + 24]);
    ((short4v*)a.out[6])[i] = s;
    return;
  }
  float4a v = ((const float4a*)a.in[seg])[i];
  short4v o;
  o.x = f2bf(v.x); o.y = f2bf(v.y); o.z = f2bf(v.z); o.w = f2bf(v.w);
  ((short4v*)a.out[seg])[i] = o;
}

// ---- fused Q/K/V projection GEMM: 2-phase LDS double-buffer + 2D XCD
// swizzle (verified round 6: 62 -> <42 us). Seg-0 blocks additionally fuse
// the Qrel mini-GEMM into their epilogue: the block's Qp tile (128 q x
// 128 d for one (b,h)) is already in acc registers -> transpose through a
// 128x132 LDS tile (same pattern as the verified Vt epilogue), then run
// qrel_k-v2's exact per-tile loop (A-frags from LDS, B-frags from global
// rel[h], identical MFMA/clamp/guard/store). Eliminates the qrel_k launch
// and its 8 MB Qp re-read. NOTE: Qrel must NOT alias Qb/Kb (writes now
// overlap gemm_qkv's own A reads) - relocated after O2 in the workspace.
__global__ __launch_bounds__(256) void gemm_qkv(
    const short* __restrict__ Qb, const short* __restrict__ Kb, const short* __restrict__ Vb,
    const short* __restrict__ Wq, const short* __restrict__ Wk, const short* __restrict__ Wv,
    const short* __restrict__ Rel, short* __restrict__ Qrel,
    short* __restrict__ Qp, short* __restrict__ Kp, short* __restrict__ Vt) {
  __shared__ short pool[32768];        // 2 stages x (As 8192 | Bs 8192)
  int bid = blockIdx.x;
  int xcd = bid & 7, slot = bid >> 3;  // 768 = 8 XCD x 96
  int seg = slot >> 5, r = slot & 31;
  int mt = ((xcd >> 1) << 3) | (r >> 2);   // 32 mt in 4 groups of 8
  int nt = ((xcd & 1) << 2) | (r & 3);     // 8 nt in 2 groups of 4
  const short* A = seg == 0 ? Qb : (seg == 1 ? Kb : Vb);
  const short* W = seg == 0 ? Wq : (seg == 1 ? Wk : Wv);
  int m0 = mt * 128, n0 = nt * 128;
  int tid = threadIdx.x;
  int lane = tid & 63, wid = tid >> 6;
  int l15 = lane & 15, quad = lane >> 4;
  int wm = wid & 1, wn = wid >> 1;

  int srow = lane >> 3, sunit = (lane & 7) ^ (lane >> 3);
  const short* gA = A + (m0 + wid * 32 + srow) * 1024 + sunit * 8;
  const short* gB = W + (n0 + wid * 32 + srow) * 1024 + sunit * 8;
  int stoff = (wid * 32) * 64;         // per-wave stage offset
  int sw = l15 & 7;

  float4a acc[4][4];
#pragma unroll
  for (int i = 0; i < 4; ++i)
#pragma unroll
    for (int j = 0; j < 4; ++j) acc[i][j] = (float4a){0, 0, 0, 0};

  // prologue: stage tile 0 into buffer 0
#pragma unroll
  for (int t = 0; t < 4; ++t) {
    gl2lds(gA + t * 8192, pool + stoff + t * 512);
    gl2lds(gB + t * 8192, pool + 8192 + stoff + t * 512);
  }
  __syncthreads();                     // implicit vmcnt(0) drains the stage

  int cur = 0;
  for (int kc = 0; kc < 1024; kc += 64) {
    if (kc < 960) {                    // stage next tile into other buffer
      short* nxt = pool + ((cur ^ 1) << 14);
#pragma unroll
      for (int t = 0; t < 4; ++t) {
        gl2lds(gA + kc + 64 + t * 8192, nxt + stoff + t * 512);
        gl2lds(gB + kc + 64 + t * 8192, nxt + 8192 + stoff + t * 512);
      }
    }
    const short* As = pool + (cur << 14);
    const short* Bs = As + 8192;
#pragma unroll
    for (int ks = 0; ks < 2; ++ks) {
      short8 af[4], bfr[4];
#pragma unroll
      for (int i = 0; i < 4; ++i)
        af[i] = *(const short8*)&As[(wm * 64 + i * 16 + l15) * 64 +
                                    (((ks * 4 + quad) ^ sw) * 8)];
#pragma unroll
      for (int j = 0; j < 4; ++j)
        bfr[j] = *(const short8*)&Bs[(wn * 64 + j * 16 + l15) * 64 +
                                     (((ks * 4 + quad) ^ sw) * 8)];
#pragma unroll
      for (int i = 0; i < 4; ++i)
#pragma unroll
        for (int j = 0; j < 4; ++j) acc[i][j] = MFMA16(af[i], bfr[j], acc[i][j]);
    }
    __syncthreads();                   // drains next-stage loads (covered)
    cur ^= 1;
  }

  if (seg < 2) {
    // Qp/Kp: n = h*128+d, d consecutive across lanes -> direct stores
    float scl = (seg == 0) ? 0.12752745707470575f : 1.0f;  // sc * log2(e) for Q
#pragma unroll
    for (int i = 0; i < 4; ++i)
#pragma unroll
      for (int j = 0; j < 4; ++j)
#pragma unroll
        for (int r2 = 0; r2 < 4; ++r2) {
          int m = m0 + wm * 64 + i * 16 + quad * 4 + r2;
          int n = n0 + wn * 64 + j * 16 + l15;
          int bb = m >> 10, s = m & 1023, hh = n >> 7, d = n & 127;
          short v = f2bf(acc[i][j][r2] * scl);
          if (seg == 0) Qp[(((bb * 8 + hh) * 1024) + s) * 128 + d] = v;
          else          Kp[(((bb * 8 + hh) * 1024) + s) * 128 + d] = v;
        }
    if (seg == 0) {
      // ---- fused Qrel: Qp-tile (in acc) @ rel[h]^T -> Qrel rows s0..s0+127
      short* T2 = pool;                // 128 x 132 shorts (stage pool is dead)
#pragma unroll
      for (int i = 0; i < 4; ++i)
#pragma unroll
        for (int j = 0; j < 4; ++j)
#pragma unroll
          for (int r2 = 0; r2 < 4; ++r2)
            T2[(wm * 64 + i * 16 + quad * 4 + r2) * 132 + wn * 64 + j * 16 + l15] =
                f2bf(acc[i][j][r2] * scl);
      __syncthreads();
      int h = nt;
      int b3 = m0 >> 10, s0 = m0 & 1023;
      long qbase = (long)(b3 * 8 + h) * 264192;
      const short* rbase = Rel + h * 32896 + quad * 8;   // h*257*128
#pragma unroll
      for (int half = 0; half < 2; ++half) {
        int w8 = wid + half * 4;       // q-subtile 0..7
        const short* arow2 = T2 + (w8 * 16 + l15) * 132 + quad * 8;
        short8 a2[4];
#pragma unroll
        for (int t = 0; t < 4; ++t) a2[t] = *(const short8*)(arow2 + t * 32);
        for (int ntc = 0; ntc < 17; ++ntc) {
          int col = ntc * 16 + l15;
          int colc = col > 256 ? 256 : col;
          const short* brow = rbase + colc * 128;
          float4a acq = {0, 0, 0, 0};
#pragma unroll
          for (int t = 0; t < 4; ++t) {
            short8 bq = *(const short8*)(brow + t * 32);
            acq = MFMA16(a2[t], bq, acq);
          }
          if (col < 257) {
#pragma unroll
            for (int r2 = 0; r2 < 4; ++r2)
              Qrel[qbase + (long)(s0 + w8 * 16 + quad * 4 + r2) * 258 + col] =
                  f2bf(acq[r2]);
          }
        }
      }
    }
  } else {
    // Vt: transpose through LDS, then coalesced 256B-row stores.
    short* T = pool;                   // 64 x 132 shorts (reuses stage pool)
    int b2 = m0 >> 10, s0 = m0 & 1023;
    long vb2 = (long)(b2 * 8 + nt) * 131072;
#pragma unroll
    for (int hd = 0; hd < 2; ++hd) {
      __syncthreads();
      if (wn == hd) {
#pragma unroll
        for (int j = 0; j < 4; ++j)
#pragma unroll
          for (int i = 0; i < 4; ++i)
#pragma unroll
            for (int r2 = 0; r2 < 4; ++r2)
              T[(j * 16 + l15) * 132 + wm * 64 + i * 16 + quad * 4 + r2] =
                  f2bf(acc[i][j][r2]);
      }
      __syncthreads();
#pragma unroll
      for (int rr = 0; rr < 4; ++rr) {
        int d = rr * 16 + (tid >> 4);
        short8 v = *(const short8*)&T[d * 132 + (tid & 15) * 8];
        *(short8*)&Vt[vb2 + (hd * 64 + d) * 1024 + s0 + (tid & 15) * 8] = v;
      }
    }
  }
}

// ---- output projection: out(f32) = O2h @ WoP^T, head-major A. 2-phase dbuf
// + 2D XCD swizzle (verified round 6). ----
__global__ __launch_bounds__(256) void gemm_o(const short* __restrict__ A,
                                              const short* __restrict__ W,
                                              float* __restrict__ C) {
  __shared__ short pool[24576];        // 2 stages x (As 8192 | Bs 4096)
  int bid = blockIdx.x;
  int xcd = bid & 7, slot = bid >> 3;  // 512 = 8 XCD x 64
  int mt = ((xcd >> 1) << 3) | (slot >> 3);  // 32 mt in 4 groups of 8
  int nt = ((xcd & 1) << 3) | (slot & 7);    // 16 nt in 2 groups of 8
  int m0 = mt * 128, n0 = nt * 64;
  int lane = threadIdx.x & 63, wid = threadIdx.x >> 6;
  int l15 = lane & 15, quad = lane >> 4;
  int wm = wid & 1, wn = wid >> 1;

  int srow = lane >> 3, sunit = (lane & 7) ^ (lane >> 3);
  int bb = m0 >> 10, q0t = m0 & 1023;
  const short* gA = A + bb * 1048576 + (q0t + wid * 32 + srow) * 128 + sunit * 8;
  const short* gB = W + (n0 + wid * 16 + srow) * 1024 + sunit * 8;
  int saoff = (wid * 32) * 64;
  int sboff = (wid * 16) * 64;
  int sw = l15 & 7;

  float4a acc[4][2];
#pragma unroll
  for (int i = 0; i < 4; ++i)
#pragma unroll
    for (int j = 0; j < 2; ++j) acc[i][j] = (float4a){0, 0, 0, 0};

  // prologue: stage tile 0 (kc=0 -> koff=0)
#pragma unroll
  for (int t = 0; t < 4; ++t) gl2lds(gA + t * 1024, pool + saoff + t * 512);
#pragma unroll
  for (int t = 0; t < 2; ++t) gl2lds(gB + t * 8192, pool + 8192 + sboff + t * 512);
  __syncthreads();

  int cur = 0;
  for (int kc = 0; kc < 1024; kc += 64) {
    if (kc < 960) {
      int kn = kc + 64;
      int koff = (kn >> 7) * 131072 + (kn & 64);   // head block + half-row
      short* nxt = pool + ((cur ^ 1) * 12288);
#pragma unroll
      for (int t = 0; t < 4; ++t) gl2lds(gA + koff + t * 1024, nxt + saoff + t * 512);
#pragma unroll
      for (int t = 0; t < 2; ++t) gl2lds(gB + kn + t * 8192, nxt + 8192 + sboff + t * 512);
    }
    const short* As = pool + cur * 12288;
    const short* Bs = As + 8192;
#pragma unroll
    for (int ks = 0; ks < 2; ++ks) {
      short8 af[4], bfr[2];
#pragma unroll
      for (int i = 0; i < 4; ++i)
        af[i] = *(const short8*)&As[(wm * 64 + i * 16 + l15) * 64 +
                                    (((ks * 4 + quad) ^ sw) * 8)];
#pragma unroll
      for (int j = 0; j < 2; ++j)
        bfr[j] = *(const short8*)&Bs[(wn * 32 + j * 16 + l15) * 64 +
                                     (((ks * 4 + quad) ^ sw) * 8)];
#pragma unroll
      for (int i = 0; i < 4; ++i)
#pragma unroll
        for (int j = 0; j < 2; ++j) acc[i][j] = MFMA16(af[i], bfr[j], acc[i][j]);
    }
    __syncthreads();
    cur ^= 1;
  }

#pragma unroll
  for (int i = 0; i < 4; ++i)
#pragma unroll
    for (int j = 0; j < 2; ++j)
#pragma unroll
      for (int r2 = 0; r2 < 4; ++r2) {
        int m = m0 + wm * 64 + i * 16 + quad * 4 + r2;
        int n = n0 + wn * 32 + j * 16 + l15;
        C[m * 1024 + n] = acc[i][j][r2];
      }
}

// Banded attention v9 (verified round 9/10): block-cooperative LDS staging.
// 64-q blocks, grid 512, 4 waves = qt (q 32-tile) x kh (key 32-half). Per
// 64-key tile, K[64][128] (16 KB) and V=Vt[128][64] (16 KB) staged ONCE per
// block via gl2lds, consumed by both qt waves. XOR-swizzle via pre-swizzled
// GLOBAL source (LDS dest linear for gl2lds). Single-buffered T3-minimum:
// {ds_read frags; barrier; stage next; compute; barrier}. In-register
// softmax (swapped QK^T), exp2 folding, head-major O2, XCD-grouped bh.
__global__ __launch_bounds__(256, 2) void attn_k(const short* __restrict__ Qp,
                                                 const short* __restrict__ Kp,
                                                 const short* __restrict__ Vt,
                                                 const short* __restrict__ Qrel,
                                                 const unsigned char* __restrict__ kpm,
                                                 short* __restrict__ O2) {
  __shared__ __align__(16) short pool[32896];      // 65792 B
  short* qlds = pool;                              // 64 x 258 shorts
  short* Kbuf = pool + 16512;                      // [64 k][128 d] swizzled
  short* Vbuf = pool + 16512 + 8192;               // [128 d][64 k] swizzled
  float* obuf = (float*)(pool + 16512);            // epilogue alias (32 KB)
  float* lbuf = (float*)pool;                      // epilogue alias (256 B)
  int tid = threadIdx.x;
  int lane = tid & 63, wid = tid >> 6;
  int qt = wid & 1, kh = wid >> 1;
  int bid = blockIdx.x;
  // XCD-grouping: bid%8 fixes a group of 4 bh; all 16 q-blocks of those bh
  // run on one XCD -> K+V working set 2 MB, L2-resident.
  int bh = ((bid & 7) << 2) | ((bid >> 3) & 3);
  int qsb = bid >> 5;                              // 0..15
  int Q0 = qsb * 64;
  int q0 = Q0 + qt * 32;
  int l31 = lane & 31, hl = lane >> 5;
  int b = bh >> 3;

  int klo = Q0 - 256; if (klo < 0) klo = 0;        // 64-aligned
  int khi = Q0 + 320; if (khi > 1024) khi = 1024;  // 64-aligned

  const short* kgbase = Kp + (long)bh * 131072;
  const short* vgbase = Vt + (long)bh * 131072;
  const unsigned char* pmrow = kpm + b * 1024;

  // staging decomposition (per wave):
  // K: 4 calls x 4 rows: lane covers row wid*16+c*4+(lane>>4), slot lane&15,
  //    global unit = slot ^ (c*4 + (lane>>4))
  int ksr = lane >> 4, ksu = lane & 15;
  // V: 4 calls x 8 rows: lane covers d-row wid*32+c*8+(lane>>3), slot lane&7,
  //    global unit = (lane&7) ^ (lane>>3)   (c*8, wid*32 == 0 mod 8)
  int vsr = lane >> 3, vsu = (lane & 7) ^ (lane >> 3);

#define STAGE_KV(KT)                                                          \
  {                                                                           \
    int _k0 = (KT);                                                           \
    _Pragma("unroll")                                                         \
    for (int c = 0; c < 4; ++c) {                                             \
      int rl = wid * 16 + c * 4 + ksr;                                        \
      gl2lds(kgbase + (long)(_k0 + rl) * 128 + ((ksu ^ (c * 4 + ksr)) * 8),   \
             Kbuf + (wid * 16 + c * 4) * 128);                                \
    }                                                                         \
    _Pragma("unroll")                                                         \
    for (int c = 0; c < 4; ++c) {                                             \
      int rl = wid * 32 + c * 8 + vsr;                                        \
      gl2lds(vgbase + (long)rl * 1024 + _k0 + vsu * 8,                        \
             Vbuf + (wid * 32 + c * 8) * 64);                                 \
    }                                                                         \
  }

  // prologue: Qrel -> qlds, Q frags, stage tile 0, first pad-mask bytes
  {
    const short8* src = (const short8*)(Qrel + (long)bh * 264192 + Q0 * 258);
    short8* dst = (short8*)qlds;
    for (int i = tid; i < 2064; i += 256) dst[i] = src[i];
  }
  short8 aq[8];
  const short* qrow = Qp + bh * 131072 + (q0 + l31) * 128 + hl * 8;
#pragma unroll
  for (int s = 0; s < 8; ++s) aq[s] = *(const short8*)(qrow + s * 16);
  STAGE_KV(klo);
  unsigned char pmb = pmrow[klo + kh * 32 + l31];
  __syncthreads();                       // drains qlds writes + stage vmcnt
  unsigned pm32 = (unsigned)__ballot(pmb != 0);

  float16a O[4];
#pragma unroll
  for (int d = 0; d < 4; ++d)
#pragma unroll
    for (int i = 0; i < 16; ++i) O[d][i] = 0.f;
  float lsum = 0.f;

  int qv = q0 + l31;                     // this lane's q-row
  int rowb = (qt * 32 + l31) * 258;
  int r15 = l31 & 15;                    // K read swizzle (kh*32 == 0 mod 16)
  int d7 = l31 & 7;                      // V read swizzle

  for (int k0 = klo; k0 < khi; k0 += 64) {
    int kw = k0 + kh * 32;               // this wave's 32-key base
    // ---- LDS -> register fragments (before buffer is overwritten) ----
    short8 kf[8];
    const short* Kr = Kbuf + (kh * 32 + l31) * 128;
#pragma unroll
    for (int s = 0; s < 8; ++s)
      kf[s] = *(const short8*)&Kr[(((2 * s + hl) ^ r15) * 8)];
    short8 vf0[4], vf1[4];
#pragma unroll
    for (int dblk = 0; dblk < 4; ++dblk) {
      const short* Vr = Vbuf + (dblk * 32 + l31) * 64;
      vf0[dblk] = *(const short8*)&Vr[(((kh * 4 + hl) ^ d7) * 8)];
      vf1[dblk] = *(const short8*)&Vr[(((kh * 4 + 2 + hl) ^ d7) * 8)];
    }
    __syncthreads();                     // all waves done reading the buffer

    // ---- stage next tile (hides under compute below) ----
    int k1 = k0 + 64;
    unsigned char pmn = 0;
    if (k1 < khi) {
      STAGE_KV(k1);
      pmn = pmrow[k1 + kh * 32 + l31];
    }
    unsigned pmc = pm32;

    // ---- S = K^T x Q : col(lane)=q, row(reg,hl)=key offset ----
    float16a S;
#pragma unroll
    for (int i = 0; i < 16; ++i) S[i] = 0.f;
#pragma unroll
    for (int s = 0; s < 8; ++s) S = MFMA32(kf[s], aq[s], S);

    // ---- softmax: per-lane q-row, 16 key-offsets in regs ----
    int dq = kw - qv;
    bool edge = (kw - q0 < -224) | (kw - q0 > 224) | (pmc != 0);
    if (!edge) {
      int rb = dq + 4 * hl + 128;
#pragma unroll
      for (int i = 0; i < 16; ++i) {
        int rr = rb + (i & 3) + 8 * (i >> 2);
        rr = rr < 0 ? 0 : (rr > 256 ? 256 : rr);
        float pe = __builtin_amdgcn_exp2f(S[i] + bf2f(qlds[rowb + rr]));
        S[i] = pe;
        lsum += pe;
      }
    } else {
#pragma unroll
      for (int i = 0; i < 16; ++i) {
        int koff = (i & 3) + 8 * (i >> 2) + 4 * hl;
        int dd = dq + koff;
        int rr = dd < -128 ? 0 : (dd > 128 ? 256 : dd + 128);
        float rel = bf2f(qlds[rowb + rr]);
        int msk = (dd < -256) | (dd > 256) | (int)((pmc >> koff) & 1u);
        float pe = msk ? 0.f : __builtin_amdgcn_exp2f(S[i] + rel);
        S[i] = pe;
        lsum += pe;
      }
    }

    // ---- P (f32 C-layout) -> bf16 A-frags: 8 cvt_pk + 4 permlane32_swap ----
    short8 ap0, ap1;
    {
      unsigned x0, y0, z0, w0;
      asm("v_cvt_pk_bf16_f32 %0, %1, %2" : "=v"(x0) : "v"(S[0]), "v"(S[1]));
      asm("v_cvt_pk_bf16_f32 %0, %1, %2" : "=v"(y0) : "v"(S[2]), "v"(S[3]));
      asm("v_cvt_pk_bf16_f32 %0, %1, %2" : "=v"(z0) : "v"(S[4]), "v"(S[5]));
      asm("v_cvt_pk_bf16_f32 %0, %1, %2" : "=v"(w0) : "v"(S[6]), "v"(S[7]));
      asm("v_permlane32_swap_b32 %0, %1" : "+v"(x0), "+v"(z0));
      asm("v_permlane32_swap_b32 %0, %1" : "+v"(y0), "+v"(w0));
      uint4v u0 = {x0, y0, z0, w0};
      ap0 = __builtin_bit_cast(short8, u0);
      unsigned x1, y1, z1, w1;
      asm("v_cvt_pk_bf16_f32 %0, %1, %2" : "=v"(x1) : "v"(S[8]), "v"(S[9]));
      asm("v_cvt_pk_bf16_f32 %0, %1, %2" : "=v"(y1) : "v"(S[10]), "v"(S[11]));
      asm("v_cvt_pk_bf16_f32 %0, %1, %2" : "=v"(z1) : "v"(S[12]), "v"(S[13]));
      asm("v_cvt_pk_bf16_f32 %0, %1, %2" : "=v"(w1) : "v"(S[14]), "v"(S[15]));
      asm("v_permlane32_swap_b32 %0, %1" : "+v"(x1), "+v"(z1));
      asm("v_permlane32_swap_b32 %0, %1" : "+v"(y1), "+v"(w1));
      uint4v u1 = {x1, y1, z1, w1};
      ap1 = __builtin_bit_cast(short8, u1);
    }

    // ---- PV ----
#pragma unroll
    for (int dblk = 0; dblk < 4; ++dblk) {
      O[dblk] = MFMA32(ap0, vf0[dblk], O[dblk]);
      O[dblk] = MFMA32(ap1, vf1[dblk], O[dblk]);
    }

    __syncthreads();                     // drains staging -> buffer ready
    pm32 = (unsigned)__ballot(pmn != 0);
  }
#undef STAGE_KV

  // ---- two-phase combine across the 2 key-halves (no atomics) ----
  lsum += __shfl_xor(lsum, 32);          // hl-pair partial denominators
  __syncthreads();                       // k-loop LDS dead; aliases now safe
  if (kh == 1) {
    if (hl == 0) lbuf[qt * 32 + l31] = lsum;
#pragma unroll
    for (int dblk = 0; dblk < 4; ++dblk)
#pragma unroll
      for (int i = 0; i < 16; ++i) {
        int qoff = (i & 3) + 8 * (i >> 2) + 4 * hl;
        obuf[(qt * 32 + qoff) * 128 + dblk * 32 + l31] = O[dblk][i];
      }
  }
  __syncthreads();
  if (kh == 0) {
    if (hl == 0) {
      float inv = __builtin_amdgcn_rcpf(lsum + lbuf[qt * 32 + l31]);
      lbuf[qt * 32 + l31] = inv;
    }
#pragma unroll
    for (int dblk = 0; dblk < 4; ++dblk)
#pragma unroll
      for (int i = 0; i < 16; ++i) {
        int qoff = (i & 3) + 8 * (i >> 2) + 4 * hl;
        obuf[(qt * 32 + qoff) * 128 + dblk * 32 + l31] += O[dblk][i];
      }
  }
  __syncthreads();

  // head-major contiguous epilogue: 16 KB line-aligned run per block
#pragma unroll
  for (int it = 0; it < 4; ++it) {
    int idx = tid + it * 256;
    int q = idx >> 4, d = (idx & 15) * 8;
    float inv = lbuf[q];
    const float* ob = &obuf[q * 128 + d];
    short8 v;
#pragma unroll
    for (int j = 0; j < 8; ++j) v[j] = f2bf(ob[j] * inv);
    *(short8*)&O2[(long)bh * 131072 + (long)(Q0 + q) * 128 + d] = v;
  }
}

extern "C" void kernel_launch(void* const* d_in, const int* in_sizes, int n_in,
                              void* d_out, int out_size, void* d_ws, size_t ws_size,
                              hipStream_t stream) {
  const float* Q   = (const float*)d_in[0];
  const float* K   = (const float*)d_in[1];
  const float* V   = (const float*)d_in[2];
  const unsigned char* kpm = (const unsigned char*)d_in[4];
  const float* Wq  = (const float*)d_in[5];
  const float* Wk  = (const float*)d_in[6];
  const float* Wv  = (const float*)d_in[7];
  const float* Wo  = (const float*)d_in[8];
  const float* rel = (const float*)d_in[9];
  float* out = (float*)d_out;

  short* ws = (short*)d_ws;
  short* Qb   = ws;
  short* Kb   = Qb + 4194304;
  short* Vb   = Kb + 4194304;
  short* Wqb  = Vb + 4194304;
  short* Wkb  = Wqb + 1048576;
  short* Wvb  = Wkb + 1048576;
  short* Wob  = Wvb + 1048576;
  short* relb = Wob + 1048576;
  short* Qp   = relb + 263168;
  short* Kp   = Qp + 4194304;
  short* Vt   = Kp + 4194304;
  short* O2   = Vt + 4194304;
  // Qrel no longer aliases Qb/Kb: gemm_qkv now WRITES it while other blocks
  // still READ Qb/Kb/Vb. Fresh region after O2 (usage ~76 MB << ws_size).
  short* Qrel = O2 + 4194304;

  Cvt8 ca;
  ca.in[0] = Q;  ca.out[0] = Qb;
  ca.in[1] = K;  ca.out[1] = Kb;
  ca.in[2] = V;  ca.out[2] = Vb;
  ca.in[3] = Wq; ca.out[3] = Wqb;
  ca.in[4] = Wk; ca.out[4] = Wkb;
  ca.in[5] = Wv; ca.out[5] = Wvb;
  ca.in[6] = Wo; ca.out[6] = Wob;
  ca.in[7] = rel; ca.out[7] = relb;
  cvt8_k<<<dim3(16641), dim3(256), 0, stream>>>(ca);

  gemm_qkv<<<dim3(768), dim3(256), 0, stream>>>(Qb, Kb, Vb, Wqb, Wkb, Wvb,
                                                relb, Qrel, Qp, Kp, Vt);
  attn_k<<<dim3(512), dim3(256), 0, stream>>>(Qp, Kp, Vt, Qrel, kpm, O2);
  gemm_o<<<dim3(512), dim3(256), 0, stream>>>(O2, Wob, out);
}